// Round 2
// baseline (9058.739 us; speedup 1.0000x reference)
//
#include <hip/hip_runtime.h>

#define F_DIM 1024
#define W_DIM 512
#define NB 4
#define NC 4

// ---------------- conv 3x3, SAME zero padding, single batch ----------------
__global__ __launch_bounds__(256) void conv3x3_kernel(
    const float* __restrict__ x, const float* __restrict__ w,
    const float* __restrict__ bias, float* __restrict__ out,
    int Cin, int Cout, int H, int W)
{
  int idx = blockIdx.x * 256 + threadIdx.x;   // co*H*W + i*W + j
  int j = idx % W;
  int t = idx / W;
  int i = t % H;
  int co = t / H;
  float acc = bias[co];
  for (int ci = 0; ci < Cin; ++ci) {
    const float* xp = x + (size_t)ci * H * W;
    const float* wp = w + (size_t)(co * Cin + ci) * 9;
#pragma unroll
    for (int dy = 0; dy < 3; ++dy) {
      int iy = i + dy - 1;
      if (iy < 0 || iy >= H) continue;
#pragma unroll
      for (int dx = 0; dx < 3; ++dx) {
        int jx = j + dx - 1;
        if (jx < 0 || jx >= W) continue;
        acc += wp[dy * 3 + dx] * xp[(size_t)iy * W + jx];
      }
    }
  }
  out[idx] = acc;
}

// ---------------- generic batched tiled fp32 GEMM ----------------
// C[m,n] = alpha * sum_k A[m,k]*B[k,n] (+ C[m,n] if beta)
// AT: A[m,k] = Asrc[k*lda + m] ;  BT: B[k,n] = Bsrc[n*ldb + k]
template <int AT, int BT>
__global__ __launch_bounds__(256) void gemm_kernel(
    const float* __restrict__ A, const float* __restrict__ B,
    float* __restrict__ C,
    int M, int N, int K, int lda, int ldb, int ldc,
    long long aStride, long long bStride, long long cStride,
    float alpha, int beta)
{
  int bz = blockIdx.z;
  A += (size_t)bz * aStride;
  B += (size_t)bz * bStride;
  C += (size_t)bz * cStride;
  int m0 = blockIdx.y * 64, n0 = blockIdx.x * 64;
  int tid = threadIdx.x;
  __shared__ float As[16][64];
  __shared__ float Bs[16][64];
  int ty = tid >> 4, tx = tid & 15;
  float acc[4][4] = {};
  for (int k0 = 0; k0 < K; k0 += 16) {
    if (AT) {
      int kr = tid >> 4, m4 = (tid & 15) * 4;
      float4 a4 = *(const float4*)&A[(size_t)(k0 + kr) * lda + m0 + m4];
      *(float4*)&As[kr][m4] = a4;
    } else {
      int mr = tid >> 2, k4 = (tid & 3) * 4;
      float4 a4 = *(const float4*)&A[(size_t)(m0 + mr) * lda + k0 + k4];
      As[k4 + 0][mr] = a4.x; As[k4 + 1][mr] = a4.y;
      As[k4 + 2][mr] = a4.z; As[k4 + 3][mr] = a4.w;
    }
    if (BT) {
      int nr = tid >> 2, k4 = (tid & 3) * 4;
      float4 b4 = *(const float4*)&B[(size_t)(n0 + nr) * ldb + k0 + k4];
      Bs[k4 + 0][nr] = b4.x; Bs[k4 + 1][nr] = b4.y;
      Bs[k4 + 2][nr] = b4.z; Bs[k4 + 3][nr] = b4.w;
    } else {
      int kr = tid >> 4, n4 = (tid & 15) * 4;
      *(float4*)&Bs[kr][n4] = *(const float4*)&B[(size_t)(k0 + kr) * ldb + n0 + n4];
    }
    __syncthreads();
#pragma unroll
    for (int k = 0; k < 16; ++k) {
      float4 av = *(const float4*)&As[k][ty * 4];
      float4 bv = *(const float4*)&Bs[k][tx * 4];
      float a_[4] = {av.x, av.y, av.z, av.w};
      float b_[4] = {bv.x, bv.y, bv.z, bv.w};
#pragma unroll
      for (int i = 0; i < 4; ++i)
#pragma unroll
        for (int jj = 0; jj < 4; ++jj) acc[i][jj] += a_[i] * b_[jj];
    }
    __syncthreads();
  }
#pragma unroll
  for (int i = 0; i < 4; ++i) {
    int row = m0 + ty * 4 + i;
    float* cp = &C[(size_t)row * ldc + n0 + tx * 4];
    float4 o;
    o.x = alpha * acc[i][0]; o.y = alpha * acc[i][1];
    o.z = alpha * acc[i][2]; o.w = alpha * acc[i][3];
    if (beta) {
      float4 c0 = *(const float4*)cp;
      o.x += c0.x; o.y += c0.y; o.z += c0.z; o.w += c0.w;
    }
    *(float4*)cp = o;
  }
}

// ---------------- layernorm over feature axis, single b (4 c-planes) ----------------
__global__ __launch_bounds__(256) void ln_kernel(
    const float* __restrict__ x, const float* __restrict__ g,
    const float* __restrict__ bt, float* __restrict__ out)
{
  int c = blockIdx.y;                 // 0..3
  int lane = threadIdx.x & 63;
  int seg = threadIdx.x >> 6;         // 0..3, each 256 features
  int w = blockIdx.x * 64 + lane;
  const float* xp = x + ((size_t)c << 19) + w;
  float sum = 0.f, sq = 0.f;
  for (int f = seg * 256; f < seg * 256 + 256; ++f) {
    float v = xp[(size_t)f << 9];
    sum += v; sq += v * v;
  }
  __shared__ float s1[4][64], s2[4][64];
  s1[seg][lane] = sum; s2[seg][lane] = sq;
  __syncthreads();
  float tot = s1[0][lane] + s1[1][lane] + s1[2][lane] + s1[3][lane];
  float tq  = s2[0][lane] + s2[1][lane] + s2[2][lane] + s2[3][lane];
  float mu = tot * (1.f / 1024.f);
  float var = tq * (1.f / 1024.f) - mu * mu;
  float rs = rsqrtf(var + 1e-5f);
  float* op = out + ((size_t)c << 19) + w;
  const float* gp = g + c * F_DIM;
  const float* bp = bt + c * F_DIM;
  for (int f = seg * 256; f < seg * 256 + 256; ++f) {
    float v = xp[(size_t)f << 9];
    op[(size_t)f << 9] = (v - mu) * rs * gp[f] + bp[f];
  }
}

// ---------------- RoPE in-place, single b (4 c-planes) ----------------
__global__ __launch_bounds__(256) void rope_kernel(float* __restrict__ q)
{
  int idx = blockIdx.x * 256 + threadIdx.x;  // pair idx, total 4*512*512
  int w = idx & 511;
  int fp = (idx >> 9) & 511;   // feature-pair within c-plane
  int c = idx >> 18;           // 0..3
  int j = fp & 63;             // pair within head (dh=128)
  float inv = expf(-(float)j * (9.210340371976184f / 64.f));
  float ang = (float)w * inv;
  float cs = cosf(ang), sn = sinf(ang);
  size_t base = ((size_t)c << 19) + ((size_t)(fp * 2) << 9) + w;
  float e = q[base];
  float o = q[base + 512];
  q[base] = e * cs - o * sn;
  q[base + 512] = o * cs + e * sn;
}

// ---------------- softmax over rows of 512 (in-place) ----------------
__device__ __forceinline__ float waveRedMax(float v) {
#pragma unroll
  for (int o = 32; o > 0; o >>= 1) v = fmaxf(v, __shfl_xor(v, o));
  return v;
}
__device__ __forceinline__ float waveRedSum(float v) {
#pragma unroll
  for (int o = 32; o > 0; o >>= 1) v += __shfl_xor(v, o);
  return v;
}
__global__ __launch_bounds__(256) void softmax512_kernel(float* __restrict__ S)
{
  float* p = S + (size_t)blockIdx.x * 512;
  int t = threadIdx.x;
  int lane = t & 63, wid = t >> 6;
  float v0 = p[t], v1 = p[t + 256];
  __shared__ float sm[4];
  float m = waveRedMax(fmaxf(v0, v1));
  if (lane == 0) sm[wid] = m;
  __syncthreads();
  float M = fmaxf(fmaxf(sm[0], sm[1]), fmaxf(sm[2], sm[3]));
  float e0 = expf(v0 - M), e1 = expf(v1 - M);
  __shared__ float ss[4];
  float s = waveRedSum(e0 + e1);
  if (lane == 0) ss[wid] = s;
  __syncthreads();
  float inv = 1.f / (ss[0] + ss[1] + ss[2] + ss[3]);
  p[t] = e0 * inv;
  p[t + 256] = e1 * inv;
}

// ---------------- squared relu in-place ----------------
__global__ __launch_bounds__(256) void sqrelu_kernel(float* __restrict__ y)
{
  int idx = blockIdx.x * 256 + threadIdx.x;
  float v = y[idx];
  v = fmaxf(v, 0.f);
  y[idx] = v * v;
}

// ---------------- concat for one b: out_b[0:8]=x_b, out_b[8:12]=h_b ----------------
__global__ __launch_bounds__(256) void concat_b_kernel(
    const float* __restrict__ x_b, const float* __restrict__ h_b, float* __restrict__ out_b)
{
  int idx = blockIdx.x * 256 + threadIdx.x;   // 12 * 2^19 total
  int inner = idx & ((1 << 19) - 1);
  int ch = idx >> 19;
  out_b[idx] = (ch < 8) ? x_b[((size_t)ch << 19) + inner]
                        : h_b[((size_t)(ch - 8) << 19) + inner];
}

extern "C" void kernel_launch(void* const* d_in, const int* in_sizes, int n_in,
                              void* d_out, int out_size, void* d_ws, size_t ws_size,
                              hipStream_t stream)
{
  const float* x        = (const float*)d_in[0];
  const float* embed_cw = (const float*)d_in[1];
  const float* embed_cb = (const float*)d_in[2];
  const float* embed_pw = (const float*)d_in[3];
  const float* n1g      = (const float*)d_in[4];
  const float* n1b      = (const float*)d_in[5];
  const float* q_cw     = (const float*)d_in[6];
  const float* q_cb     = (const float*)d_in[7];
  const float* q_pw     = (const float*)d_in[8];
  const float* k_cw     = (const float*)d_in[9];
  const float* k_cb     = (const float*)d_in[10];
  const float* k_pw     = (const float*)d_in[11];
  const float* v_cw     = (const float*)d_in[12];
  const float* v_cb     = (const float*)d_in[13];
  const float* v_pw     = (const float*)d_in[14];
  const float* o_cw     = (const float*)d_in[15];
  const float* o_cb     = (const float*)d_in[16];
  const float* o_pw     = (const float*)d_in[17];
  const float* n2g      = (const float*)d_in[18];
  const float* n2b      = (const float*)d_in[19];
  const float* f1_cw    = (const float*)d_in[20];
  const float* f1_cb    = (const float*)d_in[21];
  const float* f1_pw    = (const float*)d_in[22];
  const float* f2_cw    = (const float*)d_in[23];
  const float* f2_cb    = (const float*)d_in[24];
  const float* f2_pw    = (const float*)d_in[25];
  float* out = (float*)d_out;
  float* ws  = (float*)d_ws;

  // per-b workspace: 6 planes of 4c x 1024 x 512 = 2,097,152 floats each -> 48 MiB total
  const size_t PL = 2097152;          // per-buffer floats (4 c-planes)
  const size_t CP = 524288;           // one c-plane (1024*512)
  float* Hb  = ws;
  float* XN  = ws + PL;
  float* Qb  = ws + 2 * PL;
  float* Kb  = ws + 3 * PL;
  float* Vb  = ws + 4 * PL;
  float* TMP = ws + 5 * PL;
  float* MID = XN;                    // 8.4M floats spanning XN..Vb (FFN phase only)

  const long long PW_A = (long long)F_DIM * F_DIM;   // 1,048,576 per-c weight stride
  const long long CPs  = (long long)CP;

  for (int b = 0; b < NB; ++b) {
    const float* xb = x + (size_t)b * 8 * CP;

    // 1. embed: conv(8->4) -> TMP ; pw -> Hb
    conv3x3_kernel<<<8192, 256, 0, stream>>>(xb, embed_cw, embed_cb, TMP, 8, NC, F_DIM, W_DIM);
    gemm_kernel<0, 0><<<dim3(8, 16, 4), 256, 0, stream>>>(
        embed_pw, TMP, Hb, 1024, 512, 1024, 1024, 512, 512, PW_A, CPs, CPs, 1.f, 0);

    // 2. LN1 -> XN
    ln_kernel<<<dim3(8, 4), 256, 0, stream>>>(Hb, n1g, n1b, XN);

    // 3. q,k,v projections
    conv3x3_kernel<<<8192, 256, 0, stream>>>(XN, q_cw, q_cb, TMP, NC, NC, F_DIM, W_DIM);
    gemm_kernel<0, 0><<<dim3(8, 16, 4), 256, 0, stream>>>(
        q_pw, TMP, Qb, 1024, 512, 1024, 1024, 512, 512, PW_A, CPs, CPs, 1.f, 0);
    conv3x3_kernel<<<8192, 256, 0, stream>>>(XN, k_cw, k_cb, TMP, NC, NC, F_DIM, W_DIM);
    gemm_kernel<0, 0><<<dim3(8, 16, 4), 256, 0, stream>>>(
        k_pw, TMP, Kb, 1024, 512, 1024, 1024, 512, 512, PW_A, CPs, CPs, 1.f, 0);
    conv3x3_kernel<<<8192, 256, 0, stream>>>(XN, v_cw, v_cb, TMP, NC, NC, F_DIM, W_DIM);
    gemm_kernel<0, 0><<<dim3(8, 16, 4), 256, 0, stream>>>(
        v_pw, TMP, Vb, 1024, 512, 1024, 1024, 512, 512, PW_A, CPs, CPs, 1.f, 0);

    // 4. RoPE
    rope_kernel<<<4096, 256, 0, stream>>>(Qb);
    rope_kernel<<<4096, 256, 0, stream>>>(Kb);

    // 5-7. attention: 32 (c,h) batches, chunks of 8; S lives in TMP (8*512*512 = 2.1M)
    for (int ch = 0; ch < 4; ++ch) {
      size_t qoff = (size_t)ch * 8 * 65536;   // 8 head-batches of 128*512
      // S = Q^T K / 32
      gemm_kernel<1, 0><<<dim3(8, 8, 8), 256, 0, stream>>>(
          Qb + qoff, Kb + qoff, TMP, 512, 512, 128, 512, 512, 512,
          65536LL, 65536LL, 262144LL, 1.f / 32.f, 0);
      softmax512_kernel<<<4096, 256, 0, stream>>>(TMP);
      // att = V * P^T, stored (d,pos), overwrites Q region of this chunk
      gemm_kernel<0, 1><<<dim3(8, 2, 8), 256, 0, stream>>>(
          Vb + qoff, TMP, Qb + qoff, 128, 512, 512, 512, 512, 512,
          65536LL, 262144LL, 65536LL, 1.f, 0);
    }

    // 8. o-projection, accumulate into Hb
    conv3x3_kernel<<<8192, 256, 0, stream>>>(Qb, o_cw, o_cb, TMP, NC, NC, F_DIM, W_DIM);
    gemm_kernel<0, 0><<<dim3(8, 16, 4), 256, 0, stream>>>(
        o_pw, TMP, Hb, 1024, 512, 1024, 1024, 512, 512, PW_A, CPs, CPs, 1.f, 1);

    // 9. LN2 -> XN
    ln_kernel<<<dim3(8, 4), 256, 0, stream>>>(Hb, n2g, n2b, XN);

    // 10. ffn1: conv -> TMP ; pw (4096x1024) -> MID (overlays XN..Vb) ; sqrelu
    conv3x3_kernel<<<8192, 256, 0, stream>>>(XN, f1_cw, f1_cb, TMP, NC, NC, F_DIM, W_DIM);
    gemm_kernel<0, 0><<<dim3(8, 64, 4), 256, 0, stream>>>(
        f1_pw, TMP, MID, 4096, 512, 1024, 1024, 512, 512,
        (long long)4096 * 1024, CPs, (long long)4096 * 512, 1.f, 0);
    sqrelu_kernel<<<32768, 256, 0, stream>>>(MID);

    // 11. ffn2 per output channel: conv(4->1, H=4096) -> TMP ; pw accumulate Hb[c]
    for (int co = 0; co < NC; ++co) {
      conv3x3_kernel<<<8192, 256, 0, stream>>>(
          MID, f2_cw + (size_t)co * NC * 9, f2_cb + co, TMP, NC, 1, 4096, W_DIM);
      gemm_kernel<0, 0><<<dim3(8, 16, 1), 256, 0, stream>>>(
          f2_pw + (size_t)co * 1024 * 4096, TMP, Hb + (size_t)co * CP,
          1024, 512, 4096, 4096, 512, 512, 0LL, 0LL, 0LL, 1.f, 1);
    }

    // 12. concat this b
    concat_b_kernel<<<24576, 256, 0, stream>>>(xb, Hb, out + (size_t)b * 12 * CP);
  }
}

// Round 3
// 2818.849 us; speedup vs baseline: 3.2136x; 3.2136x over previous
//
#include <hip/hip_runtime.h>

typedef __attribute__((ext_vector_type(8))) short short8;
typedef __attribute__((ext_vector_type(4))) float f32x4;
typedef unsigned int uint;
typedef unsigned short ushort;

#define PLF 524288   // 1024*512 elements per activation plane

__device__ __forceinline__ ushort f2bf(float f) {
  uint u = __float_as_uint(f);
  u += 0x7FFF + ((u >> 16) & 1);   // RNE
  return (ushort)(u >> 16);
}
__device__ __forceinline__ float bf2f(ushort h) {
  return __uint_as_float(((uint)h) << 16);
}
__device__ __forceinline__ int swzf(int r) { return ((r & 3) ^ ((r >> 2) & 3)); }

#define GLOAD16(gp, lp)                                          \
  __builtin_amdgcn_global_load_lds(                              \
      (const __attribute__((address_space(1))) void*)(gp),       \
      (__attribute__((address_space(3))) void*)(lp), 16, 0, 0)

// ---------------------------------------------------------------------------
// Generic MFMA GEMM: C[m][n] = alpha * sum_k A[m][k] * B[n][k]  (both row-major-K)
// A/B: bf16 (CVT=0, staged via global_load_lds) or fp32 (CVT=1, reg-convert).
// CDT: 0 = fp32 C (optional BETA accumulate), 1 = bf16 C (optional RELU2).
// Per-z offsets: off = (z/Div)*S1 + (z%Div)*S2  (element units).
// ---------------------------------------------------------------------------
template <int ACVT, int BCVT, int CDT, int BETA, int RELU2>
__global__ __launch_bounds__(256) void mm_kernel(
    const void* __restrict__ Av, const void* __restrict__ Bv, void* __restrict__ Cv,
    int K, int lda, int ldb, int ldc,
    int aDiv, long long aS1, long long aS2,
    int bDiv, long long bS1, long long bS2,
    int cDiv, long long cS1, long long cS2, float alpha)
{
  __shared__ char lds[16384];   // A tile 8KB | B tile 8KB
  const int tid = threadIdx.x;
  const int z = blockIdx.z;
  const long long aOff = (long long)(z / aDiv) * aS1 + (long long)(z % aDiv) * aS2;
  const long long bOff = (long long)(z / bDiv) * bS1 + (long long)(z % bDiv) * bS2;
  const long long cOff = (long long)(z / cDiv) * cS1 + (long long)(z % cDiv) * cS2;
  const int m0 = blockIdx.y * 128, n0 = blockIdx.x * 128;
  const int lane = tid & 63, wid = tid >> 6;
  const int wr = wid >> 1, wc = wid & 1;
  const int u = lane & 15, g = lane >> 4;
  const int sr0 = tid >> 2, sslot = tid & 3;

  f32x4 acc[4][4];
#pragma unroll
  for (int i = 0; i < 4; ++i)
#pragma unroll
    for (int j = 0; j < 4; ++j) acc[i][j] = (f32x4){0.f, 0.f, 0.f, 0.f};

  for (int kt = 0; kt < K; kt += 32) {
    __syncthreads();
#pragma unroll
    for (int half = 0; half < 2; ++half) {
      const int r = sr0 + 64 * half;
      const int ss = sslot ^ swzf(r);
      if (ACVT == 0) {
        const ushort* src = (const ushort*)Av + aOff + (long long)(m0 + r) * lda + kt + ss * 8;
        GLOAD16(src, &lds[0] + wid * 1024 + half * 4096);
      } else {
        const float* src = (const float*)Av + aOff + (long long)(m0 + r) * lda + kt + ss * 8;
        float4 x0 = *(const float4*)src;
        float4 x1 = *(const float4*)(src + 4);
        short8 h;
        h[0] = (short)f2bf(x0.x); h[1] = (short)f2bf(x0.y);
        h[2] = (short)f2bf(x0.z); h[3] = (short)f2bf(x0.w);
        h[4] = (short)f2bf(x1.x); h[5] = (short)f2bf(x1.y);
        h[6] = (short)f2bf(x1.z); h[7] = (short)f2bf(x1.w);
        *(short8*)(&lds[0] + r * 64 + sslot * 16) = h;
      }
      if (BCVT == 0) {
        const ushort* src = (const ushort*)Bv + bOff + (long long)(n0 + r) * ldb + kt + ss * 8;
        GLOAD16(src, &lds[8192] + wid * 1024 + half * 4096);
      } else {
        const float* src = (const float*)Bv + bOff + (long long)(n0 + r) * ldb + kt + ss * 8;
        float4 x0 = *(const float4*)src;
        float4 x1 = *(const float4*)(src + 4);
        short8 h;
        h[0] = (short)f2bf(x0.x); h[1] = (short)f2bf(x0.y);
        h[2] = (short)f2bf(x0.z); h[3] = (short)f2bf(x0.w);
        h[4] = (short)f2bf(x1.x); h[5] = (short)f2bf(x1.y);
        h[6] = (short)f2bf(x1.z); h[7] = (short)f2bf(x1.w);
        *(short8*)(&lds[8192] + r * 64 + sslot * 16) = h;
      }
    }
    __syncthreads();
    short8 af[4], bfr[4];
#pragma unroll
    for (int mi = 0; mi < 4; ++mi) {
      const int r = wr * 64 + mi * 16 + u;
      af[mi] = *(const short8*)(&lds[0] + r * 64 + ((g ^ swzf(r)) * 16));
    }
#pragma unroll
    for (int ni = 0; ni < 4; ++ni) {
      const int r = wc * 64 + ni * 16 + u;
      bfr[ni] = *(const short8*)(&lds[8192] + r * 64 + ((g ^ swzf(r)) * 16));
    }
#pragma unroll
    for (int mi = 0; mi < 4; ++mi)
#pragma unroll
      for (int ni = 0; ni < 4; ++ni)
        acc[mi][ni] = __builtin_amdgcn_mfma_f32_16x16x32_bf16(af[mi], bfr[ni], acc[mi][ni], 0, 0, 0);
  }

#pragma unroll
  for (int mi = 0; mi < 4; ++mi)
#pragma unroll
    for (int ni = 0; ni < 4; ++ni)
#pragma unroll
      for (int q = 0; q < 4; ++q) {
        const int row = m0 + wr * 64 + mi * 16 + g * 4 + q;
        const int col = n0 + wc * 64 + ni * 16 + u;
        float v = acc[mi][ni][q] * alpha;
        if (CDT == 0) {
          float* cp = (float*)Cv + cOff + (long long)row * ldc + col;
          if (BETA) v += *cp;
          *cp = v;
        } else {
          if (RELU2) { v = fmaxf(v, 0.f); v = v * v; }
          ((ushort*)Cv)[cOff + (long long)row * ldc + col] = f2bf(v);
        }
      }
}

// ---------------------------------------------------------------------------
// conv 3x3 SAME on transposed planes [512 w][F f], bf16 in/out, fp32 weights.
// plane p = bb*4 + co; input base = (bb*Cin+ci) planes.
// ---------------------------------------------------------------------------
__global__ __launch_bounds__(256) void conv_kernel(
    const ushort* __restrict__ in, const float* __restrict__ wt,
    const float* __restrict__ bias, ushort* __restrict__ outp,
    int Cin, int log2F)
{
  const int idx = blockIdx.x * 256 + threadIdx.x;
  const int F = 1 << log2F;
  const int f = idx & (F - 1);
  const int wrow = (idx >> log2F) & 511;
  const int p = idx >> (log2F + 9);
  const int co = p & 3, bb = p >> 2;
  float acc = bias[co];
  const bool f0ok = f > 0, f1ok = f < F - 1;
  for (int ci = 0; ci < Cin; ++ci) {
    const ushort* base = in + (((size_t)(bb * Cin + ci)) << (log2F + 9));
    const float* wp = wt + (co * Cin + ci) * 9;
#pragma unroll
    for (int dx = 0; dx < 3; ++dx) {
      const int wr2 = wrow + dx - 1;
      if (wr2 < 0 || wr2 > 511) continue;
      const ushort* rp = base + ((size_t)wr2 << log2F) + f;
      if (f0ok) acc += wp[dx] * bf2f(rp[-1]);
      acc += wp[3 + dx] * bf2f(rp[0]);
      if (f1ok) acc += wp[6 + dx] * bf2f(rp[1]);
    }
  }
  outp[idx] = f2bf(acc);
}

// ---------------- layernorm over f (rows of 1024), H fp32 -> XN bf16 --------
__global__ __launch_bounds__(256) void ln_kernel(
    const float* __restrict__ H, const float* __restrict__ gam,
    const float* __restrict__ bet, ushort* __restrict__ XN)
{
  const int wid = threadIdx.x >> 6, lane = threadIdx.x & 63;
  const int row = blockIdx.x * 4 + wid;
  const int c = (row >> 9) & 3;
  const float* xp = H + (size_t)row * 1024;
  float4 v[4];
  float s = 0.f, q = 0.f;
#pragma unroll
  for (int p = 0; p < 4; ++p) {
    v[p] = *(const float4*)(xp + p * 256 + lane * 4);
    s += v[p].x + v[p].y + v[p].z + v[p].w;
    q += v[p].x * v[p].x + v[p].y * v[p].y + v[p].z * v[p].z + v[p].w * v[p].w;
  }
#pragma unroll
  for (int o = 32; o > 0; o >>= 1) { s += __shfl_xor(s, o); q += __shfl_xor(q, o); }
  const float mu = s * (1.f / 1024.f);
  const float var = q * (1.f / 1024.f) - mu * mu;
  const float rs = rsqrtf(var + 1e-5f);
  ushort* op = XN + (size_t)row * 1024;
  const float* gp = gam + c * 1024;
  const float* bp = bet + c * 1024;
#pragma unroll
  for (int p = 0; p < 4; ++p) {
    const int f = p * 256 + lane * 4;
    float4 g4 = *(const float4*)(gp + f);
    float4 b4 = *(const float4*)(bp + f);
    ushort4 o4;
    o4.x = f2bf((v[p].x - mu) * rs * g4.x + b4.x);
    o4.y = f2bf((v[p].y - mu) * rs * g4.y + b4.y);
    o4.z = f2bf((v[p].z - mu) * rs * g4.z + b4.z);
    o4.w = f2bf((v[p].w - mu) * rs * g4.w + b4.w);
    *(ushort4*)(op + f) = o4;
  }
}

// ---------------- softmax rows of 512: S fp32 -> P bf16 ---------------------
__global__ __launch_bounds__(256) void softmax_kernel(
    const float* __restrict__ S, ushort* __restrict__ P)
{
  const int wid = threadIdx.x >> 6, lane = threadIdx.x & 63;
  const size_t row = (size_t)blockIdx.x * 4 + wid;
  const float* sp = S + row * 512;
  float4 v0 = *(const float4*)(sp + lane * 4);
  float4 v1 = *(const float4*)(sp + 256 + lane * 4);
  float m = fmaxf(fmaxf(fmaxf(v0.x, v0.y), fmaxf(v0.z, v0.w)),
                  fmaxf(fmaxf(v1.x, v1.y), fmaxf(v1.z, v1.w)));
#pragma unroll
  for (int o = 32; o > 0; o >>= 1) m = fmaxf(m, __shfl_xor(m, o));
  float e0 = __expf(v0.x - m), e1 = __expf(v0.y - m), e2 = __expf(v0.z - m), e3 = __expf(v0.w - m);
  float e4 = __expf(v1.x - m), e5 = __expf(v1.y - m), e6 = __expf(v1.z - m), e7 = __expf(v1.w - m);
  float s = e0 + e1 + e2 + e3 + e4 + e5 + e6 + e7;
#pragma unroll
  for (int o = 32; o > 0; o >>= 1) s += __shfl_xor(s, o);
  const float inv = 1.f / s;
  ushort* pp = P + row * 512;
  ushort4 a, b;
  a.x = f2bf(e0 * inv); a.y = f2bf(e1 * inv); a.z = f2bf(e2 * inv); a.w = f2bf(e3 * inv);
  b.x = f2bf(e4 * inv); b.y = f2bf(e5 * inv); b.z = f2bf(e6 * inv); b.w = f2bf(e7 * inv);
  *(ushort4*)(pp + lane * 4) = a;
  *(ushort4*)(pp + 256 + lane * 4) = b;
}

// ---------------- RoPE in-place on bf16 [w][f] planes (pairs adjacent) ------
__global__ __launch_bounds__(256) void rope_kernel(uint* __restrict__ B)
{
  const int idx = blockIdx.x * 256 + threadIdx.x;
  const int fp = idx & 511;
  const int w = (idx >> 9) & 511;
  const int pl = idx >> 18;
  const int j = fp & 63;
  const float inv = __expf(-(float)j * (9.210340371976184f / 64.f));
  float sn, cs;
  sincosf((float)w * inv, &sn, &cs);
  uint* p = B + ((size_t)pl << 18) + ((size_t)w << 9) + fp;
  const uint pr = *p;
  const float e = bf2f((ushort)(pr & 0xFFFF));
  const float o = bf2f((ushort)(pr >> 16));
  const float ne = e * cs - o * sn;
  const float no = o * cs + e * sn;
  *p = ((uint)f2bf(no) << 16) | (uint)f2bf(ne);
}

// ---------------- transpose-in: x fp32 [f][w] -> XT bf16 [w][f] -------------
__global__ __launch_bounds__(256) void tin_kernel(
    const float* __restrict__ x, ushort* __restrict__ XT, int planeOff)
{
  __shared__ float t[32][33];
  const int f0 = blockIdx.x * 32, w0 = blockIdx.y * 32;
  const int z = blockIdx.z;
  const int tx = threadIdx.x & 31, ty = threadIdx.x >> 5;
  const float* src = x + (size_t)(planeOff + z) * PLF;
#pragma unroll
  for (int r = 0; r < 32; r += 8) t[r + ty][tx] = src[(size_t)(f0 + r + ty) * 512 + w0 + tx];
  __syncthreads();
  ushort* dst = XT + (size_t)z * PLF;
#pragma unroll
  for (int r = 0; r < 32; r += 8) dst[(size_t)(w0 + r + ty) * 1024 + f0 + tx] = f2bf(t[tx][r + ty]);
}

// ---------------- transpose-out: H fp32 [w][f] -> out[b][8+c][f][w] ---------
__global__ __launch_bounds__(256) void tout_kernel(
    const float* __restrict__ H, float* __restrict__ out, int b0)
{
  __shared__ float t[32][33];
  const int w0 = blockIdx.x * 32, f0 = blockIdx.y * 32;
  const int p = blockIdx.z;
  const int b = b0 + (p >> 2), c = p & 3;
  const int tx = threadIdx.x & 31, ty = threadIdx.x >> 5;
  const float* src = H + (size_t)p * PLF;
#pragma unroll
  for (int r = 0; r < 32; r += 8) t[r + ty][tx] = src[(size_t)(w0 + r + ty) * 1024 + f0 + tx];
  __syncthreads();
  float* dst = out + (size_t)(b * 12 + 8 + c) * PLF;
#pragma unroll
  for (int r = 0; r < 32; r += 8) dst[(size_t)(f0 + r + ty) * 512 + w0 + tx] = t[tx][r + ty];
}

// ---------------- copy x -> out channels 0..7 (fp32, float4) ---------------
__global__ __launch_bounds__(256) void copyx_kernel(
    const float4* __restrict__ x, float4* __restrict__ out)
{
  const int idx = blockIdx.x * 256 + threadIdx.x;   // 4,194,304 float4s
  const int pl = idx >> 17;                          // PLF/4 = 131072 per plane
  const int rem = idx & 131071;
  const int b = pl >> 3, ch = pl & 7;
  out[(size_t)(b * 12 + ch) * 131072 + rem] = x[idx];
}

// ---------------------------------------------------------------------------
extern "C" void kernel_launch(void* const* d_in, const int* in_sizes, int n_in,
                              void* d_out, int out_size, void* d_ws, size_t ws_size,
                              hipStream_t stream)
{
  const float* x        = (const float*)d_in[0];
  const float* embed_cw = (const float*)d_in[1];
  const float* embed_cb = (const float*)d_in[2];
  const float* embed_pw = (const float*)d_in[3];
  const float* n1g      = (const float*)d_in[4];
  const float* n1b      = (const float*)d_in[5];
  const float* q_cw     = (const float*)d_in[6];
  const float* q_cb     = (const float*)d_in[7];
  const float* q_pw     = (const float*)d_in[8];
  const float* k_cw     = (const float*)d_in[9];
  const float* k_cb     = (const float*)d_in[10];
  const float* k_pw     = (const float*)d_in[11];
  const float* v_cw     = (const float*)d_in[12];
  const float* v_cb     = (const float*)d_in[13];
  const float* v_pw     = (const float*)d_in[14];
  const float* o_cw     = (const float*)d_in[15];
  const float* o_cb     = (const float*)d_in[16];
  const float* o_pw     = (const float*)d_in[17];
  const float* n2g      = (const float*)d_in[18];
  const float* n2b      = (const float*)d_in[19];
  const float* f1_cw    = (const float*)d_in[20];
  const float* f1_cb    = (const float*)d_in[21];
  const float* f1_pw    = (const float*)d_in[22];
  const float* f2_cw    = (const float*)d_in[23];
  const float* f2_cb    = (const float*)d_in[24];
  const float* f2_pw    = (const float*)d_in[25];
  float* out = (float*)d_out;

  const size_t perB = 50331648ull;   // bytes per batch of chunk
  const int N = (ws_size >= 4 * perB) ? 4 : (ws_size >= 2 * perB) ? 2 : 1;
  const int nP = 4 * N;

  char* base = (char*)d_ws;
  float*  Hf = (float*)base;                                    // N*8388608 B
  ushort* XT = (ushort*)(base + (size_t)N * 8388608);           // N*8388608 B
  ushort* XN = (ushort*)((char*)XT + (size_t)N * 8388608);      // N*4194304 B
  ushort* Qb = (ushort*)((char*)XN + (size_t)N * 4194304);
  ushort* CT = (ushort*)((char*)Qb + (size_t)N * 4194304);
  ushort* Kb = (ushort*)((char*)CT + (size_t)N * 4194304);
  ushort* Vb = (ushort*)((char*)Kb + (size_t)N * 4194304);
  float*  Sf = (float*)((char*)Vb + (size_t)N * 4194304);       // N*8388608 B
  ushort* Pb = (ushort*)((char*)Sf + (size_t)N * 8388608);      // N*4194304 B
  ushort* MID = XT;   // overlays XT+XN+Qb  (N*16777216 B)
  ushort* F2C = Kb;   // overlays Kb+Vb+Sf  (N*16777216 B)

  const long long WS1 = 1048576;    // 1024*1024 per-channel pw weight stride
  const long long WS4 = 4194304;    // 4096*1024 ffn weight stride
  const int GCONV = nP * (PLF / 256);

  copyx_kernel<<<16384, 256, 0, stream>>>((const float4*)x, (float4*)out);

  for (int b0 = 0; b0 < 4; b0 += N) {
    // --- input transpose ---
    tin_kernel<<<dim3(32, 16, 8 * N), 256, 0, stream>>>(x, XT, b0 * 8);
    // --- embed ---
    conv_kernel<<<2 * GCONV, 256, 0, stream>>>(XT, embed_cw, embed_cb, CT, 8, 10);
    mm_kernel<0, 1, 0, 0, 0><<<dim3(8, 4, nP), 256, 0, stream>>>(
        CT, embed_pw, Hf, 1024, 1024, 1024, 1024,
        1, PLF, 0, 4, 0, WS1, 1, PLF, 0, 1.f);
    // --- LN1 ---
    ln_kernel<<<nP * 128, 256, 0, stream>>>(Hf, n1g, n1b, XN);
    // --- q/k/v projections ---
    conv_kernel<<<GCONV, 256, 0, stream>>>(XN, q_cw, q_cb, CT, 4, 10);
    mm_kernel<0, 1, 1, 0, 0><<<dim3(8, 4, nP), 256, 0, stream>>>(
        CT, q_pw, Qb, 1024, 1024, 1024, 1024,
        1, PLF, 0, 4, 0, WS1, 1, PLF, 0, 1.f);
    conv_kernel<<<GCONV, 256, 0, stream>>>(XN, k_cw, k_cb, CT, 4, 10);
    mm_kernel<0, 1, 1, 0, 0><<<dim3(8, 4, nP), 256, 0, stream>>>(
        CT, k_pw, Kb, 1024, 1024, 1024, 1024,
        1, PLF, 0, 4, 0, WS1, 1, PLF, 0, 1.f);
    conv_kernel<<<GCONV, 256, 0, stream>>>(XN, v_cw, v_cb, CT, 4, 10);
    mm_kernel<1, 0, 1, 0, 0><<<dim3(4, 8, nP), 256, 0, stream>>>(
        v_pw, CT, Vb, 1024, 1024, 1024, 512,
        4, 0, WS1, 1, PLF, 0, 1, PLF, 0, 1.f);          // V stored [f][w]
    // --- RoPE ---
    rope_kernel<<<nP * 1024, 256, 0, stream>>>((uint*)Qb);
    rope_kernel<<<nP * 1024, 256, 0, stream>>>((uint*)Kb);
    // --- attention, 4 chunks of 8N head-batches ---
    for (int sc = 0; sc < 4; ++sc) {
      const size_t po = (size_t)sc * N * PLF;
      mm_kernel<0, 0, 0, 0, 0><<<dim3(4, 4, 8 * N), 256, 0, stream>>>(
          Qb + po, Kb + po, Sf, 128, 1024, 1024, 512,
          8, PLF, 128, 8, PLF, 128, 1, 262144, 0, 1.f / 32.f);
      softmax_kernel<<<N * 1024, 256, 0, stream>>>(Sf, Pb);
      mm_kernel<0, 0, 1, 0, 0><<<dim3(1, 4, 8 * N), 256, 0, stream>>>(
          Pb, Vb + po, Qb + po, 512, 512, 512, 1024,
          1, 262144, 0, 8, PLF, 65536, 8, PLF, 128, 1.f);
    }
    // --- o projection (accumulate into H) ---
    conv_kernel<<<GCONV, 256, 0, stream>>>(Qb, o_cw, o_cb, CT, 4, 10);
    mm_kernel<0, 1, 0, 1, 0><<<dim3(8, 4, nP), 256, 0, stream>>>(
        CT, o_pw, Hf, 1024, 1024, 1024, 1024,
        1, PLF, 0, 4, 0, WS1, 1, PLF, 0, 1.f);
    // --- LN2 ---
    ln_kernel<<<nP * 128, 256, 0, stream>>>(Hf, n2g, n2b, XN);
    // --- ffn1 (+fused squared relu) ---
    conv_kernel<<<GCONV, 256, 0, stream>>>(XN, f1_cw, f1_cb, CT, 4, 10);
    mm_kernel<0, 1, 1, 0, 1><<<dim3(32, 4, nP), 256, 0, stream>>>(
        CT, f1_pw, MID, 1024, 1024, 1024, 4096,
        1, PLF, 0, 4, 0, WS4, 1, 2097152, 0, 1.f);
    // --- ffn2 conv (F=4096) then pw accumulate into H ---
    conv_kernel<<<8 * GCONV, 256, 0, stream>>>(MID, f2_cw, f2_cb, F2C, 4, 12);
    mm_kernel<0, 1, 0, 1, 0><<<dim3(8, 4, nP), 256, 0, stream>>>(
        F2C, f2_pw, Hf, 4096, 4096, 4096, 1024,
        1, 2097152, 0, 4, 0, WS4, 1, PLF, 0, 1.f);
    // --- output transpose ---
    tout_kernel<<<dim3(16, 32, nP), 256, 0, stream>>>(Hf, out, b0);
  }
}

// Round 4
// 1208.723 us; speedup vs baseline: 7.4945x; 2.3321x over previous
//
#include <hip/hip_runtime.h>

typedef __attribute__((ext_vector_type(8))) short short8;
typedef __attribute__((ext_vector_type(4))) float f32x4;
typedef unsigned int uint;
typedef unsigned short ushort;

#define PLF 524288   // 1024*512 elements per activation plane

__device__ __forceinline__ ushort f2bf(float f) {
  uint u = __float_as_uint(f);
  u += 0x7FFF + ((u >> 16) & 1);   // RNE
  return (ushort)(u >> 16);
}
__device__ __forceinline__ float bf2f(ushort h) {
  return __uint_as_float(((uint)h) << 16);
}
__device__ __forceinline__ int swzf(int r) { return ((r & 3) ^ ((r >> 2) & 3)); }

#define GLOAD16(gp, lp)                                          \
  __builtin_amdgcn_global_load_lds(                              \
      (const __attribute__((address_space(1))) void*)(gp),       \
      (__attribute__((address_space(3))) void*)(lp), 16, 0, 0)

// ---------------------------------------------------------------------------
// Generic MFMA GEMM: C[m][n] = alpha * sum_k A[m][k] * B[n][k]  (both row-major-K)
// A/B: bf16 (CVT=0, staged via global_load_lds) or fp32 (CVT=1, reg-convert).
// CDT: 0 = fp32 C (optional BETA accumulate), 1 = bf16 C (optional RELU2).
// Per-z offsets: off = (z/Div)*S1 + (z%Div)*S2  (element units).
// ---------------------------------------------------------------------------
template <int ACVT, int BCVT, int CDT, int BETA, int RELU2>
__global__ __launch_bounds__(256) void mm_kernel(
    const void* __restrict__ Av, const void* __restrict__ Bv, void* __restrict__ Cv,
    int K, int lda, int ldb, int ldc,
    int aDiv, long long aS1, long long aS2,
    int bDiv, long long bS1, long long bS2,
    int cDiv, long long cS1, long long cS2, float alpha)
{
  __shared__ char lds[16384];   // A tile 8KB | B tile 8KB
  const int tid = threadIdx.x;
  const int z = blockIdx.z;
  const long long aOff = (long long)(z / aDiv) * aS1 + (long long)(z % aDiv) * aS2;
  const long long bOff = (long long)(z / bDiv) * bS1 + (long long)(z % bDiv) * bS2;
  const long long cOff = (long long)(z / cDiv) * cS1 + (long long)(z % cDiv) * cS2;
  const int m0 = blockIdx.y * 128, n0 = blockIdx.x * 128;
  const int lane = tid & 63, wid = tid >> 6;
  const int wr = wid >> 1, wc = wid & 1;
  const int u = lane & 15, g = lane >> 4;
  const int sr0 = tid >> 2, sslot = tid & 3;

  f32x4 acc[4][4];
#pragma unroll
  for (int i = 0; i < 4; ++i)
#pragma unroll
    for (int j = 0; j < 4; ++j) acc[i][j] = (f32x4){0.f, 0.f, 0.f, 0.f};

  for (int kt = 0; kt < K; kt += 32) {
    __syncthreads();
#pragma unroll
    for (int half = 0; half < 2; ++half) {
      const int r = sr0 + 64 * half;
      const int ss = sslot ^ swzf(r);
      if (ACVT == 0) {
        const ushort* src = (const ushort*)Av + aOff + (long long)(m0 + r) * lda + kt + ss * 8;
        GLOAD16(src, &lds[0] + wid * 1024 + half * 4096);
      } else {
        const float* src = (const float*)Av + aOff + (long long)(m0 + r) * lda + kt + ss * 8;
        float4 x0 = *(const float4*)src;
        float4 x1 = *(const float4*)(src + 4);
        short8 h;
        h[0] = (short)f2bf(x0.x); h[1] = (short)f2bf(x0.y);
        h[2] = (short)f2bf(x0.z); h[3] = (short)f2bf(x0.w);
        h[4] = (short)f2bf(x1.x); h[5] = (short)f2bf(x1.y);
        h[6] = (short)f2bf(x1.z); h[7] = (short)f2bf(x1.w);
        *(short8*)(&lds[0] + r * 64 + sslot * 16) = h;
      }
      if (BCVT == 0) {
        const ushort* src = (const ushort*)Bv + bOff + (long long)(n0 + r) * ldb + kt + ss * 8;
        GLOAD16(src, &lds[8192] + wid * 1024 + half * 4096);
      } else {
        const float* src = (const float*)Bv + bOff + (long long)(n0 + r) * ldb + kt + ss * 8;
        float4 x0 = *(const float4*)src;
        float4 x1 = *(const float4*)(src + 4);
        short8 h;
        h[0] = (short)f2bf(x0.x); h[1] = (short)f2bf(x0.y);
        h[2] = (short)f2bf(x0.z); h[3] = (short)f2bf(x0.w);
        h[4] = (short)f2bf(x1.x); h[5] = (short)f2bf(x1.y);
        h[6] = (short)f2bf(x1.z); h[7] = (short)f2bf(x1.w);
        *(short8*)(&lds[8192] + r * 64 + sslot * 16) = h;
      }
    }
    __syncthreads();
    short8 af[4], bfr[4];
#pragma unroll
    for (int mi = 0; mi < 4; ++mi) {
      const int r = wr * 64 + mi * 16 + u;
      af[mi] = *(const short8*)(&lds[0] + r * 64 + ((g ^ swzf(r)) * 16));
    }
#pragma unroll
    for (int ni = 0; ni < 4; ++ni) {
      const int r = wc * 64 + ni * 16 + u;
      bfr[ni] = *(const short8*)(&lds[8192] + r * 64 + ((g ^ swzf(r)) * 16));
    }
#pragma unroll
    for (int mi = 0; mi < 4; ++mi)
#pragma unroll
      for (int ni = 0; ni < 4; ++ni)
        acc[mi][ni] = __builtin_amdgcn_mfma_f32_16x16x32_bf16(af[mi], bfr[ni], acc[mi][ni], 0, 0, 0);
  }

#pragma unroll
  for (int mi = 0; mi < 4; ++mi)
#pragma unroll
    for (int ni = 0; ni < 4; ++ni)
#pragma unroll
      for (int q = 0; q < 4; ++q) {
        const int row = m0 + wr * 64 + mi * 16 + g * 4 + q;
        const int col = n0 + wc * 64 + ni * 16 + u;
        float v = acc[mi][ni][q] * alpha;
        if (CDT == 0) {
          float* cp = (float*)Cv + cOff + (long long)row * ldc + col;
          if (BETA) v += *cp;
          *cp = v;
        } else {
          if (RELU2) { v = fmaxf(v, 0.f); v = v * v; }
          ((ushort*)Cv)[cOff + (long long)row * ldc + col] = f2bf(v);
        }
      }
}

// ---------------------------------------------------------------------------
// conv 3x3 SAME on transposed planes [512 w][F f], bf16 in/out, fp32 weights.
// 8 outputs per thread along f. plane p = bb*4 + co; input plane = bb*Cin+ci.
// ---------------------------------------------------------------------------
__global__ __launch_bounds__(256) void conv8_kernel(
    const ushort* __restrict__ in, const float* __restrict__ wt,
    const float* __restrict__ bias, ushort* __restrict__ outp,
    int Cin, int log2F)
{
  const int idx = blockIdx.x * 256 + threadIdx.x;
  const int F8m = (1 << (log2F - 3)) - 1;
  const int f8 = idx & F8m;
  const int w = (idx >> (log2F - 3)) & 511;
  const int p = idx >> (log2F + 6);
  const int co = p & 3, bb = p >> 2;
  const int f0 = f8 << 3;
  const float bv = bias[co];
  float acc[8];
#pragma unroll
  for (int j = 0; j < 8; ++j) acc[j] = bv;
  const bool lok = f8 > 0, rok = f8 < F8m;
  for (int ci = 0; ci < Cin; ++ci) {
    const ushort* base = in + (((size_t)(bb * Cin + ci)) << (log2F + 9));
    const float* wp = wt + (co * Cin + ci) * 9;
#pragma unroll
    for (int dxw = 0; dxw < 3; ++dxw) {
      const int w2 = w + dxw - 1;
      if (w2 < 0 || w2 > 511) continue;
      const ushort* rp = base + ((size_t)w2 << log2F) + f0;
      const short8 cen = *(const short8*)rp;
      float xv[10];
      xv[0] = lok ? bf2f(rp[-1]) : 0.f;
#pragma unroll
      for (int j = 0; j < 8; ++j) xv[j + 1] = bf2f((ushort)cen[j]);
      xv[9] = rok ? bf2f(rp[8]) : 0.f;
      const float k0 = wp[dxw], k1 = wp[3 + dxw], k2 = wp[6 + dxw];
#pragma unroll
      for (int j = 0; j < 8; ++j)
        acc[j] += k0 * xv[j] + k1 * xv[j + 1] + k2 * xv[j + 2];
    }
  }
  short8 o;
#pragma unroll
  for (int j = 0; j < 8; ++j) o[j] = (short)f2bf(acc[j]);
  *(short8*)(outp + (((size_t)p << 9) + w << log2F) + f0) = o;
}

// ---------------- layernorm over f (rows of 1024), H fp32 -> XN bf16 --------
__global__ __launch_bounds__(256) void ln_kernel(
    const float* __restrict__ H, const float* __restrict__ gam,
    const float* __restrict__ bet, ushort* __restrict__ XN)
{
  const int wid = threadIdx.x >> 6, lane = threadIdx.x & 63;
  const int row = blockIdx.x * 4 + wid;
  const int c = (row >> 9) & 3;
  const float* xp = H + (size_t)row * 1024;
  float4 v[4];
  float s = 0.f, q = 0.f;
#pragma unroll
  for (int p = 0; p < 4; ++p) {
    v[p] = *(const float4*)(xp + p * 256 + lane * 4);
    s += v[p].x + v[p].y + v[p].z + v[p].w;
    q += v[p].x * v[p].x + v[p].y * v[p].y + v[p].z * v[p].z + v[p].w * v[p].w;
  }
#pragma unroll
  for (int o = 32; o > 0; o >>= 1) { s += __shfl_xor(s, o); q += __shfl_xor(q, o); }
  const float mu = s * (1.f / 1024.f);
  const float var = q * (1.f / 1024.f) - mu * mu;
  const float rs = rsqrtf(var + 1e-5f);
  ushort* op = XN + (size_t)row * 1024;
  const float* gp = gam + c * 1024;
  const float* bp = bet + c * 1024;
#pragma unroll
  for (int p = 0; p < 4; ++p) {
    const int f = p * 256 + lane * 4;
    float4 g4 = *(const float4*)(gp + f);
    float4 b4 = *(const float4*)(bp + f);
    ushort4 o4;
    o4.x = f2bf((v[p].x - mu) * rs * g4.x + b4.x);
    o4.y = f2bf((v[p].y - mu) * rs * g4.y + b4.y);
    o4.z = f2bf((v[p].z - mu) * rs * g4.z + b4.z);
    o4.w = f2bf((v[p].w - mu) * rs * g4.w + b4.w);
    *(ushort4*)(op + f) = o4;
  }
}

// ---------------- softmax rows of 512: S fp32 -> P bf16 ---------------------
__global__ __launch_bounds__(256) void softmax_kernel(
    const float* __restrict__ S, ushort* __restrict__ P)
{
  const int wid = threadIdx.x >> 6, lane = threadIdx.x & 63;
  const size_t row = (size_t)blockIdx.x * 4 + wid;
  const float* sp = S + row * 512;
  float4 v0 = *(const float4*)(sp + lane * 4);
  float4 v1 = *(const float4*)(sp + 256 + lane * 4);
  float m = fmaxf(fmaxf(fmaxf(v0.x, v0.y), fmaxf(v0.z, v0.w)),
                  fmaxf(fmaxf(v1.x, v1.y), fmaxf(v1.z, v1.w)));
#pragma unroll
  for (int o = 32; o > 0; o >>= 1) m = fmaxf(m, __shfl_xor(m, o));
  float e0 = __expf(v0.x - m), e1 = __expf(v0.y - m), e2 = __expf(v0.z - m), e3 = __expf(v0.w - m);
  float e4 = __expf(v1.x - m), e5 = __expf(v1.y - m), e6 = __expf(v1.z - m), e7 = __expf(v1.w - m);
  float s = e0 + e1 + e2 + e3 + e4 + e5 + e6 + e7;
#pragma unroll
  for (int o = 32; o > 0; o >>= 1) s += __shfl_xor(s, o);
  const float inv = 1.f / s;
  ushort* pp = P + row * 512;
  ushort4 a, b;
  a.x = f2bf(e0 * inv); a.y = f2bf(e1 * inv); a.z = f2bf(e2 * inv); a.w = f2bf(e3 * inv);
  b.x = f2bf(e4 * inv); b.y = f2bf(e5 * inv); b.z = f2bf(e6 * inv); b.w = f2bf(e7 * inv);
  *(ushort4*)(pp + lane * 4) = a;
  *(ushort4*)(pp + 256 + lane * 4) = b;
}

// ---------------- RoPE in-place on bf16 [w][f] planes (pairs adjacent) ------
__global__ __launch_bounds__(256) void rope_kernel(uint* __restrict__ B)
{
  const int idx = blockIdx.x * 256 + threadIdx.x;
  const int fp = idx & 511;
  const int w = (idx >> 9) & 511;
  const int pl = idx >> 18;
  const int j = fp & 63;
  const float inv = __expf(-(float)j * (9.210340371976184f / 64.f));
  float sn, cs;
  sincosf((float)w * inv, &sn, &cs);
  uint* p = B + ((size_t)pl << 18) + ((size_t)w << 9) + fp;
  const uint pr = *p;
  const float e = bf2f((ushort)(pr & 0xFFFF));
  const float o = bf2f((ushort)(pr >> 16));
  const float ne = e * cs - o * sn;
  const float no = o * cs + e * sn;
  *p = ((uint)f2bf(no) << 16) | (uint)f2bf(ne);
}

// ---------------- transpose-in: x fp32 [f][w] -> XT bf16 [w][f] -------------
__global__ __launch_bounds__(256) void tin_kernel(
    const float* __restrict__ x, ushort* __restrict__ XT, int planeOff)
{
  __shared__ float t[32][33];
  const int f0 = blockIdx.x * 32, w0 = blockIdx.y * 32;
  const int z = blockIdx.z;
  const int tx = threadIdx.x & 31, ty = threadIdx.x >> 5;
  const float* src = x + (size_t)(planeOff + z) * PLF;
#pragma unroll
  for (int r = 0; r < 32; r += 8) t[r + ty][tx] = src[(size_t)(f0 + r + ty) * 512 + w0 + tx];
  __syncthreads();
  ushort* dst = XT + (size_t)z * PLF;
#pragma unroll
  for (int r = 0; r < 32; r += 8) dst[(size_t)(w0 + r + ty) * 1024 + f0 + tx] = f2bf(t[tx][r + ty]);
}

// ---------------- transpose-out: H fp32 [w][f] -> out[b][8+c][f][w] ---------
__global__ __launch_bounds__(256) void tout_kernel(
    const float* __restrict__ H, float* __restrict__ out, int b0)
{
  __shared__ float t[32][33];
  const int w0 = blockIdx.x * 32, f0 = blockIdx.y * 32;
  const int p = blockIdx.z;
  const int b = b0 + (p >> 2), c = p & 3;
  const int tx = threadIdx.x & 31, ty = threadIdx.x >> 5;
  const float* src = H + (size_t)p * PLF;
#pragma unroll
  for (int r = 0; r < 32; r += 8) t[r + ty][tx] = src[(size_t)(w0 + r + ty) * 1024 + f0 + tx];
  __syncthreads();
  float* dst = out + (size_t)(b * 12 + 8 + c) * PLF;
#pragma unroll
  for (int r = 0; r < 32; r += 8) dst[(size_t)(f0 + r + ty) * 512 + w0 + tx] = t[tx][r + ty];
}

// ---------------- copy x -> out channels 0..7 (fp32, float4) ---------------
__global__ __launch_bounds__(256) void copyx_kernel(
    const float4* __restrict__ x, float4* __restrict__ out)
{
  const int idx = blockIdx.x * 256 + threadIdx.x;   // 4,194,304 float4s
  const int pl = idx >> 17;                          // PLF/4 = 131072 per plane
  const int rem = idx & 131071;
  const int b = pl >> 3, ch = pl & 7;
  out[(size_t)(b * 12 + ch) * 131072 + rem] = x[idx];
}

// ---------------------------------------------------------------------------
extern "C" void kernel_launch(void* const* d_in, const int* in_sizes, int n_in,
                              void* d_out, int out_size, void* d_ws, size_t ws_size,
                              hipStream_t stream)
{
  const float* x        = (const float*)d_in[0];
  const float* embed_cw = (const float*)d_in[1];
  const float* embed_cb = (const float*)d_in[2];
  const float* embed_pw = (const float*)d_in[3];
  const float* n1g      = (const float*)d_in[4];
  const float* n1b      = (const float*)d_in[5];
  const float* q_cw     = (const float*)d_in[6];
  const float* q_cb     = (const float*)d_in[7];
  const float* q_pw     = (const float*)d_in[8];
  const float* k_cw     = (const float*)d_in[9];
  const float* k_cb     = (const float*)d_in[10];
  const float* k_pw     = (const float*)d_in[11];
  const float* v_cw     = (const float*)d_in[12];
  const float* v_cb     = (const float*)d_in[13];
  const float* v_pw     = (const float*)d_in[14];
  const float* o_cw     = (const float*)d_in[15];
  const float* o_cb     = (const float*)d_in[16];
  const float* o_pw     = (const float*)d_in[17];
  const float* n2g      = (const float*)d_in[18];
  const float* n2b      = (const float*)d_in[19];
  const float* f1_cw    = (const float*)d_in[20];
  const float* f1_cb    = (const float*)d_in[21];
  const float* f1_pw    = (const float*)d_in[22];
  const float* f2_cw    = (const float*)d_in[23];
  const float* f2_cb    = (const float*)d_in[24];
  const float* f2_pw    = (const float*)d_in[25];
  float* out = (float*)d_out;

  const size_t perB = 50331648ull;
  const int N = (ws_size >= 4 * perB) ? 4 : (ws_size >= 2 * perB) ? 2 : 1;
  const int nP = 4 * N;

  char* base = (char*)d_ws;
  float*  Hf = (float*)base;                                    // N*8388608 B
  ushort* XT = (ushort*)(base + (size_t)N * 8388608);           // N*8388608 B
  ushort* XN = (ushort*)((char*)XT + (size_t)N * 8388608);      // N*4194304 B
  ushort* Qb = (ushort*)((char*)XN + (size_t)N * 4194304);
  ushort* CT = (ushort*)((char*)Qb + (size_t)N * 4194304);
  ushort* Kb = (ushort*)((char*)CT + (size_t)N * 4194304);
  ushort* Vb = (ushort*)((char*)Kb + (size_t)N * 4194304);
  float*  Sf = (float*)((char*)Vb + (size_t)N * 4194304);       // N*8388608 B
  ushort* Pb = (ushort*)((char*)Sf + (size_t)N * 8388608);      // N*4194304 B
  ushort* MID = XT;   // overlays XT+XN+Qb  (N*16777216 B)
  ushort* F2C = Kb;   // overlays Kb+Vb+Sf  (N*16777216 B)

  const long long WS1 = 1048576;    // 1024*1024 per-channel pw weight stride
  const long long WS4 = 4194304;    // 4096*1024 ffn weight stride
  const int GC1 = nP * 256;         // conv blocks at F=1024 (nP*512*128/256)
  const int GC4 = nP * 1024;        // conv blocks at F=4096

  copyx_kernel<<<16384, 256, 0, stream>>>((const float4*)x, (float4*)out);

  for (int b0 = 0; b0 < 4; b0 += N) {
    // --- input transpose ---
    tin_kernel<<<dim3(32, 16, 8 * N), 256, 0, stream>>>(x, XT, b0 * 8);
    // --- embed ---
    conv8_kernel<<<GC1, 256, 0, stream>>>(XT, embed_cw, embed_cb, CT, 8, 10);
    mm_kernel<0, 1, 0, 0, 0><<<dim3(8, 4, nP), 256, 0, stream>>>(
        CT, embed_pw, Hf, 1024, 1024, 1024, 1024,
        1, PLF, 0, 4, 0, WS1, 1, PLF, 0, 1.f);
    // --- LN1 ---
    ln_kernel<<<nP * 128, 256, 0, stream>>>(Hf, n1g, n1b, XN);
    // --- q/k/v projections ---
    conv8_kernel<<<GC1, 256, 0, stream>>>(XN, q_cw, q_cb, CT, 4, 10);
    mm_kernel<0, 1, 1, 0, 0><<<dim3(8, 4, nP), 256, 0, stream>>>(
        CT, q_pw, Qb, 1024, 1024, 1024, 1024,
        1, PLF, 0, 4, 0, WS1, 1, PLF, 0, 1.f);
    conv8_kernel<<<GC1, 256, 0, stream>>>(XN, k_cw, k_cb, CT, 4, 10);
    mm_kernel<0, 1, 1, 0, 0><<<dim3(8, 4, nP), 256, 0, stream>>>(
        CT, k_pw, Kb, 1024, 1024, 1024, 1024,
        1, PLF, 0, 4, 0, WS1, 1, PLF, 0, 1.f);
    conv8_kernel<<<GC1, 256, 0, stream>>>(XN, v_cw, v_cb, CT, 4, 10);
    mm_kernel<1, 0, 1, 0, 0><<<dim3(4, 8, nP), 256, 0, stream>>>(
        v_pw, CT, Vb, 1024, 1024, 1024, 512,
        4, 0, WS1, 1, PLF, 0, 1, PLF, 0, 1.f);          // V stored [f][w]
    // --- RoPE ---
    rope_kernel<<<nP * 1024, 256, 0, stream>>>((uint*)Qb);
    rope_kernel<<<nP * 1024, 256, 0, stream>>>((uint*)Kb);
    // --- attention, 4 chunks of 8N head-batches ---
    for (int sc = 0; sc < 4; ++sc) {
      const size_t po = (size_t)sc * N * PLF;
      mm_kernel<0, 0, 0, 0, 0><<<dim3(4, 4, 8 * N), 256, 0, stream>>>(
          Qb + po, Kb + po, Sf, 128, 1024, 1024, 512,
          8, PLF, 128, 8, PLF, 128, 1, 262144, 0, 1.f / 32.f);
      softmax_kernel<<<N * 1024, 256, 0, stream>>>(Sf, Pb);
      mm_kernel<0, 0, 1, 0, 0><<<dim3(1, 4, 8 * N), 256, 0, stream>>>(
          Pb, Vb + po, Qb + po, 512, 512, 512, 1024,
          1, 262144, 0, 8, PLF, 65536, 8, PLF, 128, 1.f);
    }
    // --- o projection (accumulate into H) ---
    conv8_kernel<<<GC1, 256, 0, stream>>>(Qb, o_cw, o_cb, CT, 4, 10);
    mm_kernel<0, 1, 0, 1, 0><<<dim3(8, 4, nP), 256, 0, stream>>>(
        CT, o_pw, Hf, 1024, 1024, 1024, 1024,
        1, PLF, 0, 4, 0, WS1, 1, PLF, 0, 1.f);
    // --- LN2 ---
    ln_kernel<<<nP * 128, 256, 0, stream>>>(Hf, n2g, n2b, XN);
    // --- ffn1 (+fused squared relu) ---
    conv8_kernel<<<GC1, 256, 0, stream>>>(XN, f1_cw, f1_cb, CT, 4, 10);
    mm_kernel<0, 1, 1, 0, 1><<<dim3(32, 4, nP), 256, 0, stream>>>(
        CT, f1_pw, MID, 1024, 1024, 1024, 4096,
        1, PLF, 0, 4, 0, WS4, 1, 2097152, 0, 1.f);
    // --- ffn2 conv (F=4096) then pw accumulate into H ---
    conv8_kernel<<<GC4, 256, 0, stream>>>(MID, f2_cw, f2_cb, F2C, 4, 12);
    mm_kernel<0, 1, 0, 1, 0><<<dim3(8, 4, nP), 256, 0, stream>>>(
        F2C, f2_pw, Hf, 4096, 4096, 4096, 1024,
        1, 2097152, 0, 4, 0, WS4, 1, PLF, 0, 1.f);
    // --- output transpose ---
    tout_kernel<<<dim3(16, 32, nP), 256, 0, stream>>>(Hf, out, b0);
  }
}

// Round 5
// 971.209 us; speedup vs baseline: 9.3273x; 1.2446x over previous
//
#include <hip/hip_runtime.h>

typedef __attribute__((ext_vector_type(8))) short short8;
typedef __attribute__((ext_vector_type(4))) float f32x4;
typedef unsigned int uint;
typedef unsigned short ushort;

#define PLF 524288   // 1024*512 elements per activation plane

__device__ __forceinline__ ushort f2bf(float f) {
  uint u = __float_as_uint(f);
  u += 0x7FFF + ((u >> 16) & 1);   // RNE
  return (ushort)(u >> 16);
}
__device__ __forceinline__ float bf2f(ushort h) {
  return __uint_as_float(((uint)h) << 16);
}
__device__ __forceinline__ int swzf(int r) { return ((r & 3) ^ ((r >> 2) & 3)); }

#define GLOAD16(gp, lp)                                          \
  __builtin_amdgcn_global_load_lds(                              \
      (const __attribute__((address_space(1))) void*)(gp),       \
      (__attribute__((address_space(3))) void*)(lp), 16, 0, 0)

// ---------------------------------------------------------------------------
// MFMA GEMM: C[m][n] = alpha * sum_k A[m][k] * B[n][k]  (both row-major-K)
// A always bf16 (global_load_lds). B bf16 (BCVT=0) or fp32 reg-convert (BCVT=1).
// CDT: 0 = fp32 C (+BETA accumulate), 1 = bf16 C (+RELU2 squared-relu).
// MFAST: block-decomposition m-fastest (for wide-N grids).
// Per-z offsets: off = (z/Div)*S1 + (z%Div)*S2 (element units).
// XCD-chunked bijective block swizzle; double-buffered K loop.
// ---------------------------------------------------------------------------
template <int CDT, int BETA, int RELU2, int MFAST, int BCVT>
__global__ __launch_bounds__(256) void mm_kernel(
    const void* __restrict__ Av, const void* __restrict__ Bv, void* __restrict__ Cv,
    int K, int lda, int ldb, int ldc,
    int aDiv, long long aS1, long long aS2,
    int bDiv, long long bS1, long long bS2,
    int cDiv, long long cS1, long long cS2, float alpha)
{
  __shared__ char lds[32768];   // 2 bufs x (A 8KB | B 8KB)
  const int nx = gridDim.x, ny = gridDim.y;
  const int nwg = nx * ny * (int)gridDim.z;
  const int o = ((int)blockIdx.z * ny + blockIdx.y) * nx + blockIdx.x;
  const int qd = nwg >> 3, rm = nwg & 7, xcd = o & 7, rot = o >> 3;
  const int wflat = (xcd < rm ? xcd * (qd + 1) : rm * (qd + 1) + (xcd - rm) * qd) + rot;
  int bx, by, bz;
  if (MFAST) { by = wflat % ny; int t2 = wflat / ny; bx = t2 % nx; bz = t2 / nx; }
  else       { bx = wflat % nx; int t2 = wflat / nx; by = t2 % ny; bz = t2 / ny; }
  const int tid = threadIdx.x;
  const long long aOff = (long long)(bz / aDiv) * aS1 + (long long)(bz % aDiv) * aS2;
  const long long bOff = (long long)(bz / bDiv) * bS1 + (long long)(bz % bDiv) * bS2;
  const long long cOff = (long long)(bz / cDiv) * cS1 + (long long)(bz % cDiv) * cS2;
  const int m0 = by * 128, n0 = bx * 128;
  const int lane = tid & 63, wid = tid >> 6;
  const int wr = wid >> 1, wc = wid & 1;
  const int u = lane & 15, g = lane >> 4;
  const int sr0 = tid >> 2, sslot = tid & 3;
  const ushort* Ap = (const ushort*)Av + aOff;
  const ushort* Bp = (const ushort*)Bv + bOff;
  const float*  Bf = (const float*)Bv + bOff;

#define STAGE(buf, kt)                                                         \
  {                                                                            \
    _Pragma("unroll")                                                          \
    for (int half = 0; half < 2; ++half) {                                     \
      const int r = sr0 + 64 * half;                                           \
      const int ss = sslot ^ swzf(r);                                          \
      GLOAD16(Ap + (long long)(m0 + r) * lda + (kt) + ss * 8,                  \
              &lds[(buf) * 16384] + wid * 1024 + half * 4096);                 \
      if (BCVT == 0) {                                                         \
        GLOAD16(Bp + (long long)(n0 + r) * ldb + (kt) + ss * 8,                \
                &lds[(buf) * 16384 + 8192] + wid * 1024 + half * 4096);        \
      } else {                                                                 \
        const float* srcB = Bf + (long long)(n0 + r) * ldb + (kt) + ss * 8;    \
        float4 x0 = *(const float4*)srcB;                                      \
        float4 x1 = *(const float4*)(srcB + 4);                                \
        short8 h;                                                              \
        h[0] = (short)f2bf(x0.x); h[1] = (short)f2bf(x0.y);                    \
        h[2] = (short)f2bf(x0.z); h[3] = (short)f2bf(x0.w);                    \
        h[4] = (short)f2bf(x1.x); h[5] = (short)f2bf(x1.y);                    \
        h[6] = (short)f2bf(x1.z); h[7] = (short)f2bf(x1.w);                    \
        *(short8*)(&lds[(buf) * 16384 + 8192] + r * 64 + sslot * 16) = h;      \
      }                                                                        \
    }                                                                          \
  }

  f32x4 acc[4][4];
#pragma unroll
  for (int i = 0; i < 4; ++i)
#pragma unroll
    for (int j = 0; j < 4; ++j) acc[i][j] = (f32x4){0.f, 0.f, 0.f, 0.f};

  STAGE(0, 0);
  asm volatile("s_waitcnt vmcnt(0) lgkmcnt(0)" ::: "memory");
  __builtin_amdgcn_s_barrier();
  int cur = 0;
  for (int kt = 0; kt < K; kt += 32) {
    if (kt + 32 < K) STAGE(cur ^ 1, kt + 32);
    short8 af[4], bfr[4];
#pragma unroll
    for (int mi = 0; mi < 4; ++mi) {
      const int r = wr * 64 + mi * 16 + u;
      af[mi] = *(const short8*)(&lds[cur * 16384] + r * 64 + ((g ^ swzf(r)) * 16));
    }
#pragma unroll
    for (int ni = 0; ni < 4; ++ni) {
      const int r = wc * 64 + ni * 16 + u;
      bfr[ni] = *(const short8*)(&lds[cur * 16384 + 8192] + r * 64 + ((g ^ swzf(r)) * 16));
    }
#pragma unroll
    for (int mi = 0; mi < 4; ++mi)
#pragma unroll
      for (int ni = 0; ni < 4; ++ni)
        acc[mi][ni] = __builtin_amdgcn_mfma_f32_16x16x32_bf16(af[mi], bfr[ni], acc[mi][ni], 0, 0, 0);
    asm volatile("s_waitcnt vmcnt(0) lgkmcnt(0)" ::: "memory");
    __builtin_amdgcn_s_barrier();
    cur ^= 1;
  }
#undef STAGE

#pragma unroll
  for (int mi = 0; mi < 4; ++mi)
#pragma unroll
    for (int ni = 0; ni < 4; ++ni)
#pragma unroll
      for (int q = 0; q < 4; ++q) {
        const int row = m0 + wr * 64 + mi * 16 + g * 4 + q;
        const int col = n0 + wc * 64 + ni * 16 + u;
        float v = acc[mi][ni][q] * alpha;
        if (CDT == 0) {
          float* cp = (float*)Cv + cOff + (long long)row * ldc + col;
          if (BETA) v += *cp;
          *cp = v;
        } else {
          if (RELU2) { v = fmaxf(v, 0.f); v = v * v; }
          ((ushort*)Cv)[cOff + (long long)row * ldc + col] = f2bf(v);
        }
      }
}

// ---------------- fp32 -> bf16 weight conversion (8 elem/thread) ------------
__global__ __launch_bounds__(256) void cvt_kernel(
    const float4* __restrict__ s, short8* __restrict__ d)
{
  const int i = blockIdx.x * 256 + threadIdx.x;
  const float4 a = s[2 * i], b = s[2 * i + 1];
  short8 h;
  h[0] = (short)f2bf(a.x); h[1] = (short)f2bf(a.y);
  h[2] = (short)f2bf(a.z); h[3] = (short)f2bf(a.w);
  h[4] = (short)f2bf(b.x); h[5] = (short)f2bf(b.y);
  h[6] = (short)f2bf(b.z); h[7] = (short)f2bf(b.w);
  d[i] = h;
}

// ---------------------------------------------------------------------------
// conv 3x3 SAME on transposed planes [512 w][F f], bf16 in/out, fp32 weights.
// 8 outputs per thread along f. plane p = bb*4 + co; input plane = bb*Cin+ci.
// ---------------------------------------------------------------------------
__global__ __launch_bounds__(256) void conv8_kernel(
    const ushort* __restrict__ in, const float* __restrict__ wt,
    const float* __restrict__ bias, ushort* __restrict__ outp,
    int Cin, int log2F)
{
  const int idx = blockIdx.x * 256 + threadIdx.x;
  const int F8m = (1 << (log2F - 3)) - 1;
  const int f8 = idx & F8m;
  const int w = (idx >> (log2F - 3)) & 511;
  const int p = idx >> (log2F + 6);
  const int co = p & 3, bb = p >> 2;
  const int f0 = f8 << 3;
  const float bv = bias[co];
  float acc[8];
#pragma unroll
  for (int j = 0; j < 8; ++j) acc[j] = bv;
  const bool lok = f8 > 0, rok = f8 < F8m;
  for (int ci = 0; ci < Cin; ++ci) {
    const ushort* base = in + (((size_t)(bb * Cin + ci)) << (log2F + 9));
    const float* wp = wt + (co * Cin + ci) * 9;
#pragma unroll
    for (int dxw = 0; dxw < 3; ++dxw) {
      const int w2 = w + dxw - 1;
      if (w2 < 0 || w2 > 511) continue;
      const ushort* rp = base + ((size_t)w2 << log2F) + f0;
      const short8 cen = *(const short8*)rp;
      float xv[10];
      xv[0] = lok ? bf2f(rp[-1]) : 0.f;
#pragma unroll
      for (int j = 0; j < 8; ++j) xv[j + 1] = bf2f((ushort)cen[j]);
      xv[9] = rok ? bf2f(rp[8]) : 0.f;
      const float k0 = wp[dxw], k1 = wp[3 + dxw], k2 = wp[6 + dxw];
#pragma unroll
      for (int j = 0; j < 8; ++j)
        acc[j] += k0 * xv[j] + k1 * xv[j + 1] + k2 * xv[j + 2];
    }
  }
  short8 o;
#pragma unroll
  for (int j = 0; j < 8; ++j) o[j] = (short)f2bf(acc[j]);
  *(short8*)(outp + (((size_t)p << 9) + w << log2F) + f0) = o;
}

// ---------------- layernorm over f (rows of 1024), H fp32 -> XN bf16 --------
__global__ __launch_bounds__(256) void ln_kernel(
    const float* __restrict__ H, const float* __restrict__ gam,
    const float* __restrict__ bet, ushort* __restrict__ XN)
{
  const int wid = threadIdx.x >> 6, lane = threadIdx.x & 63;
  const int row = blockIdx.x * 4 + wid;
  const int c = (row >> 9) & 3;
  const float* xp = H + (size_t)row * 1024;
  float4 v[4];
  float s = 0.f, q = 0.f;
#pragma unroll
  for (int p = 0; p < 4; ++p) {
    v[p] = *(const float4*)(xp + p * 256 + lane * 4);
    s += v[p].x + v[p].y + v[p].z + v[p].w;
    q += v[p].x * v[p].x + v[p].y * v[p].y + v[p].z * v[p].z + v[p].w * v[p].w;
  }
#pragma unroll
  for (int o = 32; o > 0; o >>= 1) { s += __shfl_xor(s, o); q += __shfl_xor(q, o); }
  const float mu = s * (1.f / 1024.f);
  const float var = q * (1.f / 1024.f) - mu * mu;
  const float rs = rsqrtf(var + 1e-5f);
  ushort* op = XN + (size_t)row * 1024;
  const float* gp = gam + c * 1024;
  const float* bp = bet + c * 1024;
#pragma unroll
  for (int p = 0; p < 4; ++p) {
    const int f = p * 256 + lane * 4;
    float4 g4 = *(const float4*)(gp + f);
    float4 b4 = *(const float4*)(bp + f);
    ushort4 o4;
    o4.x = f2bf((v[p].x - mu) * rs * g4.x + b4.x);
    o4.y = f2bf((v[p].y - mu) * rs * g4.y + b4.y);
    o4.z = f2bf((v[p].z - mu) * rs * g4.z + b4.z);
    o4.w = f2bf((v[p].w - mu) * rs * g4.w + b4.w);
    *(ushort4*)(op + f) = o4;
  }
}

// ---------------- softmax rows of 512: S fp32 -> P bf16 ---------------------
__global__ __launch_bounds__(256) void softmax_kernel(
    const float* __restrict__ S, ushort* __restrict__ P)
{
  const int wid = threadIdx.x >> 6, lane = threadIdx.x & 63;
  const size_t row = (size_t)blockIdx.x * 4 + wid;
  const float* sp = S + row * 512;
  float4 v0 = *(const float4*)(sp + lane * 4);
  float4 v1 = *(const float4*)(sp + 256 + lane * 4);
  float m = fmaxf(fmaxf(fmaxf(v0.x, v0.y), fmaxf(v0.z, v0.w)),
                  fmaxf(fmaxf(v1.x, v1.y), fmaxf(v1.z, v1.w)));
#pragma unroll
  for (int o = 32; o > 0; o >>= 1) m = fmaxf(m, __shfl_xor(m, o));
  float e0 = __expf(v0.x - m), e1 = __expf(v0.y - m), e2 = __expf(v0.z - m), e3 = __expf(v0.w - m);
  float e4 = __expf(v1.x - m), e5 = __expf(v1.y - m), e6 = __expf(v1.z - m), e7 = __expf(v1.w - m);
  float s = e0 + e1 + e2 + e3 + e4 + e5 + e6 + e7;
#pragma unroll
  for (int o = 32; o > 0; o >>= 1) s += __shfl_xor(s, o);
  const float inv = 1.f / s;
  ushort* pp = P + row * 512;
  ushort4 a, b;
  a.x = f2bf(e0 * inv); a.y = f2bf(e1 * inv); a.z = f2bf(e2 * inv); a.w = f2bf(e3 * inv);
  b.x = f2bf(e4 * inv); b.y = f2bf(e5 * inv); b.z = f2bf(e6 * inv); b.w = f2bf(e7 * inv);
  *(ushort4*)(pp + lane * 4) = a;
  *(ushort4*)(pp + 256 + lane * 4) = b;
}

// ---------------- RoPE in-place on bf16 [w][f] planes (pairs adjacent) ------
__global__ __launch_bounds__(256) void rope_kernel(uint* __restrict__ B)
{
  const int idx = blockIdx.x * 256 + threadIdx.x;
  const int fp = idx & 511;
  const int w = (idx >> 9) & 511;
  const int pl = idx >> 18;
  const int j = fp & 63;
  const float inv = __expf(-(float)j * (9.210340371976184f / 64.f));
  float sn, cs;
  sincosf((float)w * inv, &sn, &cs);
  uint* p = B + ((size_t)pl << 18) + ((size_t)w << 9) + fp;
  const uint pr = *p;
  const float e = bf2f((ushort)(pr & 0xFFFF));
  const float o = bf2f((ushort)(pr >> 16));
  const float ne = e * cs - o * sn;
  const float no = o * cs + e * sn;
  *p = ((uint)f2bf(no) << 16) | (uint)f2bf(ne);
}

// ---------------- transpose-in: x fp32 [f][w] -> XT bf16 [w][f] -------------
__global__ __launch_bounds__(256) void tin_kernel(
    const float* __restrict__ x, ushort* __restrict__ XT, int planeOff)
{
  __shared__ float t[32][33];
  const int f0 = blockIdx.x * 32, w0 = blockIdx.y * 32;
  const int z = blockIdx.z;
  const int tx = threadIdx.x & 31, ty = threadIdx.x >> 5;
  const float* src = x + (size_t)(planeOff + z) * PLF;
#pragma unroll
  for (int r = 0; r < 32; r += 8) t[r + ty][tx] = src[(size_t)(f0 + r + ty) * 512 + w0 + tx];
  __syncthreads();
  ushort* dst = XT + (size_t)z * PLF;
#pragma unroll
  for (int r = 0; r < 32; r += 8) dst[(size_t)(w0 + r + ty) * 1024 + f0 + tx] = f2bf(t[tx][r + ty]);
}

// ---------------- transpose-out: H fp32 [w][f] -> out[b][8+c][f][w] ---------
__global__ __launch_bounds__(256) void tout_kernel(
    const float* __restrict__ H, float* __restrict__ out, int b0)
{
  __shared__ float t[32][33];
  const int w0 = blockIdx.x * 32, f0 = blockIdx.y * 32;
  const int p = blockIdx.z;
  const int b = b0 + (p >> 2), c = p & 3;
  const int tx = threadIdx.x & 31, ty = threadIdx.x >> 5;
  const float* src = H + (size_t)p * PLF;
#pragma unroll
  for (int r = 0; r < 32; r += 8) t[r + ty][tx] = src[(size_t)(w0 + r + ty) * 1024 + f0 + tx];
  __syncthreads();
  float* dst = out + (size_t)(b * 12 + 8 + c) * PLF;
#pragma unroll
  for (int r = 0; r < 32; r += 8) dst[(size_t)(f0 + r + ty) * 512 + w0 + tx] = t[tx][r + ty];
}

// ---------------- copy x -> out channels 0..7 (fp32, float4) ---------------
__global__ __launch_bounds__(256) void copyx_kernel(
    const float4* __restrict__ x, float4* __restrict__ out)
{
  const int idx = blockIdx.x * 256 + threadIdx.x;   // 4,194,304 float4s
  const int pl = idx >> 17;                          // PLF/4 = 131072 per plane
  const int rem = idx & 131071;
  const int b = pl >> 3, ch = pl & 7;
  out[(size_t)(b * 12 + ch) * 131072 + rem] = x[idx];
}

// ---------------------------------------------------------------------------
extern "C" void kernel_launch(void* const* d_in, const int* in_sizes, int n_in,
                              void* d_out, int out_size, void* d_ws, size_t ws_size,
                              hipStream_t stream)
{
  const float* x        = (const float*)d_in[0];
  const float* embed_cw = (const float*)d_in[1];
  const float* embed_cb = (const float*)d_in[2];
  const float* embed_pw = (const float*)d_in[3];
  const float* n1g      = (const float*)d_in[4];
  const float* n1b      = (const float*)d_in[5];
  const float* q_cw     = (const float*)d_in[6];
  const float* q_cb     = (const float*)d_in[7];
  const float* q_pw     = (const float*)d_in[8];
  const float* k_cw     = (const float*)d_in[9];
  const float* k_cb     = (const float*)d_in[10];
  const float* k_pw     = (const float*)d_in[11];
  const float* v_cw     = (const float*)d_in[12];
  const float* v_cb     = (const float*)d_in[13];
  const float* v_pw     = (const float*)d_in[14];
  const float* o_cw     = (const float*)d_in[15];
  const float* o_cb     = (const float*)d_in[16];
  const float* o_pw     = (const float*)d_in[17];
  const float* n2g      = (const float*)d_in[18];
  const float* n2b      = (const float*)d_in[19];
  const float* f1_cw    = (const float*)d_in[20];
  const float* f1_cb    = (const float*)d_in[21];
  const float* f1_pw    = (const float*)d_in[22];
  const float* f2_cw    = (const float*)d_in[23];
  const float* f2_cb    = (const float*)d_in[24];
  const float* f2_pw    = (const float*)d_in[25];
  float* out = (float*)d_out;

  const size_t perB = 50331648ull;
  const int N = (ws_size >= 4 * perB) ? 4 : (ws_size >= 2 * perB) ? 2 : 1;
  const int nP = 4 * N;

  char* base = (char*)d_ws;
  float*  Hf = (float*)base;                                    // N*8388608 B
  ushort* XT = (ushort*)(base + (size_t)N * 8388608);           // N*8388608 B
  ushort* XN = (ushort*)((char*)XT + (size_t)N * 8388608);      // N*4194304 B
  ushort* Qb = (ushort*)((char*)XN + (size_t)N * 4194304);
  ushort* CT = (ushort*)((char*)Qb + (size_t)N * 4194304);
  ushort* Kb = (ushort*)((char*)CT + (size_t)N * 4194304);
  ushort* Vb = (ushort*)((char*)Kb + (size_t)N * 4194304);
  float*  Sf = (float*)((char*)Vb + (size_t)N * 4194304);       // N*8388608 B
  ushort* Pb = (ushort*)((char*)Sf + (size_t)N * 8388608);      // N*4194304 B
  ushort* MID = XT;                    // overlays XT+XN+Qb
  ushort* F2C = Kb;                    // overlays Kb+Vb+Sf
  ushort* W8  = (N == 1) ? (ushort*)Sf : Pb;   // 8.4MB slot for small bf16 weights
  ushort* f1w = Kb;                    // 33.5MB span (N>=2 only)
  ushort* f2w = XT;                    // 33.5MB span (N>=2 only)

  const long long W1 = 1048576;     // per-channel 1024x1024 weight, elements
  const long long W4 = 4194304;     // 4096x1024 / 1024x4096 weight, elements
  const long long P4 = 4LL * PLF;
  const long long M1 = 2097152;     // 4096*512 plane, elements
  const int GC1 = nP * 256;
  const int GC4 = nP * 1024;

  copyx_kernel<<<16384, 256, 0, stream>>>((const float4*)x, (float4*)out);

  for (int b0 = 0; b0 < 4; b0 += N) {
    // --- input transpose ---
    tin_kernel<<<dim3(32, 16, 8 * N), 256, 0, stream>>>(x, XT, b0 * 8);
    // --- embed ---
    conv8_kernel<<<GC1, 256, 0, stream>>>(XT, embed_cw, embed_cb, CT, 8, 10);
    cvt_kernel<<<2048, 256, 0, stream>>>((const float4*)embed_pw, (short8*)W8);
    mm_kernel<0, 0, 0, 0, 0><<<dim3(8, 4, nP), 256, 0, stream>>>(
        CT, W8, Hf, 1024, 1024, 1024, 1024,
        N, PLF, P4, N, W1, 0, N, PLF, P4, 1.f);
    // --- LN1 ---
    ln_kernel<<<nP * 128, 256, 0, stream>>>(Hf, n1g, n1b, XN);
    // --- q/k/v projections ---
    conv8_kernel<<<GC1, 256, 0, stream>>>(XN, q_cw, q_cb, CT, 4, 10);
    cvt_kernel<<<2048, 256, 0, stream>>>((const float4*)q_pw, (short8*)W8);
    mm_kernel<1, 0, 0, 0, 0><<<dim3(8, 4, nP), 256, 0, stream>>>(
        CT, W8, Qb, 1024, 1024, 1024, 1024,
        N, PLF, P4, N, W1, 0, N, PLF, P4, 1.f);
    conv8_kernel<<<GC1, 256, 0, stream>>>(XN, k_cw, k_cb, CT, 4, 10);
    cvt_kernel<<<2048, 256, 0, stream>>>((const float4*)k_pw, (short8*)W8);
    mm_kernel<1, 0, 0, 0, 0><<<dim3(8, 4, nP), 256, 0, stream>>>(
        CT, W8, Kb, 1024, 1024, 1024, 1024,
        N, PLF, P4, N, W1, 0, N, PLF, P4, 1.f);
    conv8_kernel<<<GC1, 256, 0, stream>>>(XN, v_cw, v_cb, CT, 4, 10);
    cvt_kernel<<<2048, 256, 0, stream>>>((const float4*)v_pw, (short8*)W8);
    mm_kernel<1, 0, 0, 0, 0><<<dim3(4, 8, nP), 256, 0, stream>>>(
        W8, CT, Vb, 1024, 1024, 1024, 512,
        N, W1, 0, N, PLF, P4, N, PLF, P4, 1.f);        // V stored [f][w]
    // --- RoPE ---
    rope_kernel<<<nP * 1024, 256, 0, stream>>>((uint*)Qb);
    rope_kernel<<<nP * 1024, 256, 0, stream>>>((uint*)Kb);
    // --- attention, 4 chunks of 8N head-batches ---
    for (int sc = 0; sc < 4; ++sc) {
      const size_t po = (size_t)sc * N * PLF;
      mm_kernel<0, 0, 0, 0, 0><<<dim3(4, 4, 8 * N), 256, 0, stream>>>(
          Qb + po, Kb + po, Sf, 128, 1024, 1024, 512,
          8, PLF, 128, 8, PLF, 128, 1, 262144, 0, 1.f / 32.f);
      softmax_kernel<<<N * 1024, 256, 0, stream>>>(Sf, Pb);
      mm_kernel<1, 0, 0, 0, 0><<<dim3(1, 4, 8 * N), 256, 0, stream>>>(
          Pb, Vb + po, Qb + po, 512, 512, 512, 1024,
          1, 262144, 0, 8, PLF, 65536, 8, PLF, 128, 1.f);
    }
    // --- o projection (accumulate into H) ---
    conv8_kernel<<<GC1, 256, 0, stream>>>(Qb, o_cw, o_cb, CT, 4, 10);
    cvt_kernel<<<2048, 256, 0, stream>>>((const float4*)o_pw, (short8*)W8);
    mm_kernel<0, 1, 0, 0, 0><<<dim3(8, 4, nP), 256, 0, stream>>>(
        CT, W8, Hf, 1024, 1024, 1024, 1024,
        N, PLF, P4, N, W1, 0, N, PLF, P4, 1.f);
    // --- LN2 ---
    ln_kernel<<<nP * 128, 256, 0, stream>>>(Hf, n2g, n2b, XN);
    // --- ffn1 (+fused squared relu) ---
    conv8_kernel<<<GC1, 256, 0, stream>>>(XN, f1_cw, f1_cb, CT, 4, 10);
    if (N >= 2) {
      cvt_kernel<<<8192, 256, 0, stream>>>((const float4*)f1_pw, (short8*)f1w);
      mm_kernel<1, 0, 1, 1, 0><<<dim3(32, 4, nP), 256, 0, stream>>>(
          CT, f1w, MID, 1024, 1024, 1024, 4096,
          N, PLF, P4, N, W4, 0, N, M1, 4 * M1, 1.f);
    } else {
      mm_kernel<1, 0, 1, 1, 1><<<dim3(32, 4, nP), 256, 0, stream>>>(
          CT, f1_pw, MID, 1024, 1024, 1024, 4096,
          N, PLF, P4, N, W4, 0, N, M1, 4 * M1, 1.f);
    }
    // --- ffn2 conv (F=4096) then pw accumulate into H ---
    conv8_kernel<<<GC4, 256, 0, stream>>>(MID, f2_cw, f2_cb, F2C, 4, 12);
    if (N >= 2) {
      cvt_kernel<<<8192, 256, 0, stream>>>((const float4*)f2_pw, (short8*)f2w);
      mm_kernel<0, 1, 0, 0, 0><<<dim3(8, 4, nP), 256, 0, stream>>>(
          F2C, f2w, Hf, 4096, 4096, 4096, 1024,
          N, M1, 4 * M1, N, W4, 0, N, PLF, P4, 1.f);
    } else {
      mm_kernel<0, 1, 0, 0, 1><<<dim3(8, 4, nP), 256, 0, stream>>>(
          F2C, f2_pw, Hf, 4096, 4096, 4096, 1024,
          N, M1, 4 * M1, N, W4, 0, N, PLF, P4, 1.f);
    }
    // --- output transpose ---
    tout_kernel<<<dim3(16, 32, nP), 256, 0, stream>>>(Hf, out, b0);
  }
}

// Round 6
// 773.263 us; speedup vs baseline: 11.7150x; 1.2560x over previous
//
#include <hip/hip_runtime.h>

typedef __attribute__((ext_vector_type(8))) short short8;
typedef __attribute__((ext_vector_type(4))) float f32x4;
typedef unsigned int uint;
typedef unsigned short ushort;

#define PLF 524288   // 1024*512 elements per activation plane

__device__ __forceinline__ ushort f2bf(float f) {
  uint u = __float_as_uint(f);
  u += 0x7FFF + ((u >> 16) & 1);   // RNE
  return (ushort)(u >> 16);
}
__device__ __forceinline__ float bf2f(ushort h) {
  return __uint_as_float(((uint)h) << 16);
}
__device__ __forceinline__ int swzf(int r) { return ((r & 3) ^ ((r >> 2) & 3)); }

#define GLOAD16(gp, lp)                                          \
  __builtin_amdgcn_global_load_lds(                              \
      (const __attribute__((address_space(1))) void*)(gp),       \
      (__attribute__((address_space(3))) void*)(lp), 16, 0, 0)

// ---------------------------------------------------------------------------
// MFMA GEMM: C[m][n] = alpha * sum_k A[m][k] * B[n][k]  (both row-major-K)
// A always bf16 (global_load_lds). B bf16 (BCVT=0) or fp32 reg-convert (BCVT=1).
// CDT: 0 = fp32 C (+BETA accumulate), 1 = bf16 C (+RELU2 squared-relu).
// MFAST: block-decomposition m-fastest (for wide-N grids).
// Per-z offsets: off = (z/Div)*S1 + (z%Div)*S2 (element units).
// XCD-chunked bijective block swizzle; double-buffered K loop.
// ---------------------------------------------------------------------------
template <int CDT, int BETA, int RELU2, int MFAST, int BCVT>
__global__ __launch_bounds__(256) void mm_kernel(
    const void* __restrict__ Av, const void* __restrict__ Bv, void* __restrict__ Cv,
    int K, int lda, int ldb, int ldc,
    int aDiv, long long aS1, long long aS2,
    int bDiv, long long bS1, long long bS2,
    int cDiv, long long cS1, long long cS2, float alpha)
{
  __shared__ char lds[32768];   // 2 bufs x (A 8KB | B 8KB)
  const int nx = gridDim.x, ny = gridDim.y;
  const int nwg = nx * ny * (int)gridDim.z;
  const int o = ((int)blockIdx.z * ny + blockIdx.y) * nx + blockIdx.x;
  const int qd = nwg >> 3, rm = nwg & 7, xcd = o & 7, rot = o >> 3;
  const int wflat = (xcd < rm ? xcd * (qd + 1) : rm * (qd + 1) + (xcd - rm) * qd) + rot;
  int bx, by, bz;
  if (MFAST) { by = wflat % ny; int t2 = wflat / ny; bx = t2 % nx; bz = t2 / nx; }
  else       { bx = wflat % nx; int t2 = wflat / nx; by = t2 % ny; bz = t2 / ny; }
  const int tid = threadIdx.x;
  const long long aOff = (long long)(bz / aDiv) * aS1 + (long long)(bz % aDiv) * aS2;
  const long long bOff = (long long)(bz / bDiv) * bS1 + (long long)(bz % bDiv) * bS2;
  const long long cOff = (long long)(bz / cDiv) * cS1 + (long long)(bz % cDiv) * cS2;
  const int m0 = by * 128, n0 = bx * 128;
  const int lane = tid & 63, wid = tid >> 6;
  const int wr = wid >> 1, wc = wid & 1;
  const int u = lane & 15, g = lane >> 4;
  const int sr0 = tid >> 2, sslot = tid & 3;
  const ushort* Ap = (const ushort*)Av + aOff;
  const ushort* Bp = (const ushort*)Bv + bOff;
  const float*  Bf = (const float*)Bv + bOff;

#define STAGE(buf, kt)                                                         \
  {                                                                            \
    _Pragma("unroll")                                                          \
    for (int half = 0; half < 2; ++half) {                                     \
      const int r = sr0 + 64 * half;                                           \
      const int ss = sslot ^ swzf(r);                                          \
      GLOAD16(Ap + (long long)(m0 + r) * lda + (kt) + ss * 8,                  \
              &lds[(buf) * 16384] + wid * 1024 + half * 4096);                 \
      if (BCVT == 0) {                                                         \
        GLOAD16(Bp + (long long)(n0 + r) * ldb + (kt) + ss * 8,                \
                &lds[(buf) * 16384 + 8192] + wid * 1024 + half * 4096);        \
      } else {                                                                 \
        const float* srcB = Bf + (long long)(n0 + r) * ldb + (kt) + ss * 8;    \
        float4 x0 = *(const float4*)srcB;                                      \
        float4 x1 = *(const float4*)(srcB + 4);                                \
        short8 h;                                                              \
        h[0] = (short)f2bf(x0.x); h[1] = (short)f2bf(x0.y);                    \
        h[2] = (short)f2bf(x0.z); h[3] = (short)f2bf(x0.w);                    \
        h[4] = (short)f2bf(x1.x); h[5] = (short)f2bf(x1.y);                    \
        h[6] = (short)f2bf(x1.z); h[7] = (short)f2bf(x1.w);                    \
        *(short8*)(&lds[(buf) * 16384 + 8192] + r * 64 + sslot * 16) = h;      \
      }                                                                        \
    }                                                                          \
  }

  f32x4 acc[4][4];
#pragma unroll
  for (int i = 0; i < 4; ++i)
#pragma unroll
    for (int j = 0; j < 4; ++j) acc[i][j] = (f32x4){0.f, 0.f, 0.f, 0.f};

  STAGE(0, 0);
  asm volatile("s_waitcnt vmcnt(0) lgkmcnt(0)" ::: "memory");
  __builtin_amdgcn_s_barrier();
  int cur = 0;
  for (int kt = 0; kt < K; kt += 32) {
    if (kt + 32 < K) STAGE(cur ^ 1, kt + 32);
    short8 af[4], bfr[4];
#pragma unroll
    for (int mi = 0; mi < 4; ++mi) {
      const int r = wr * 64 + mi * 16 + u;
      af[mi] = *(const short8*)(&lds[cur * 16384] + r * 64 + ((g ^ swzf(r)) * 16));
    }
#pragma unroll
    for (int ni = 0; ni < 4; ++ni) {
      const int r = wc * 64 + ni * 16 + u;
      bfr[ni] = *(const short8*)(&lds[cur * 16384 + 8192] + r * 64 + ((g ^ swzf(r)) * 16));
    }
#pragma unroll
    for (int mi = 0; mi < 4; ++mi)
#pragma unroll
      for (int ni = 0; ni < 4; ++ni)
        acc[mi][ni] = __builtin_amdgcn_mfma_f32_16x16x32_bf16(af[mi], bfr[ni], acc[mi][ni], 0, 0, 0);
    asm volatile("s_waitcnt vmcnt(0) lgkmcnt(0)" ::: "memory");
    __builtin_amdgcn_s_barrier();
    cur ^= 1;
  }
#undef STAGE

#pragma unroll
  for (int mi = 0; mi < 4; ++mi)
#pragma unroll
    for (int ni = 0; ni < 4; ++ni)
#pragma unroll
      for (int q = 0; q < 4; ++q) {
        const int row = m0 + wr * 64 + mi * 16 + g * 4 + q;
        const int col = n0 + wc * 64 + ni * 16 + u;
        float v = acc[mi][ni][q] * alpha;
        if (CDT == 0) {
          float* cp = (float*)Cv + cOff + (long long)row * ldc + col;
          if (BETA) v += *cp;
          *cp = v;
        } else {
          if (RELU2) { v = fmaxf(v, 0.f); v = v * v; }
          ((ushort*)Cv)[cOff + (long long)row * ldc + col] = f2bf(v);
        }
      }
}

// ---------------- fp32 -> bf16 weight conversion (8 elem/thread) ------------
__global__ __launch_bounds__(256) void cvt_kernel(
    const float4* __restrict__ s, short8* __restrict__ d)
{
  const int i = blockIdx.x * 256 + threadIdx.x;
  const float4 a = s[2 * i], b = s[2 * i + 1];
  short8 h;
  h[0] = (short)f2bf(a.x); h[1] = (short)f2bf(a.y);
  h[2] = (short)f2bf(a.z); h[3] = (short)f2bf(a.w);
  h[4] = (short)f2bf(b.x); h[5] = (short)f2bf(b.y);
  h[6] = (short)f2bf(b.z); h[7] = (short)f2bf(b.w);
  d[i] = h;
}

// ---------------------------------------------------------------------------
// conv 3x3 SAME on transposed planes [512 w][F f], bf16 in/out, fp32 weights.
// Each thread: 8 f-outputs x ALL 4 output channels (input read once, used 4x).
// bb = batch-chunk plane group; input planes bb*CIN+ci, output planes bb*4+co.
// ---------------------------------------------------------------------------
template <int CIN>
__global__ __launch_bounds__(256) void conv4c_kernel(
    const ushort* __restrict__ in, const float* __restrict__ wt,
    const float* __restrict__ bias, ushort* __restrict__ outp, int log2F)
{
  const int idx = blockIdx.x * 256 + threadIdx.x;
  const int F8m = (1 << (log2F - 3)) - 1;
  const int f8 = idx & F8m;
  const int w = (idx >> (log2F - 3)) & 511;
  const int bb = idx >> (log2F + 6);
  const int f0 = f8 << 3;
  float acc[4][8];
#pragma unroll
  for (int co = 0; co < 4; ++co) {
    const float bv = bias[co];
#pragma unroll
    for (int j = 0; j < 8; ++j) acc[co][j] = bv;
  }
  const bool lok = f8 > 0, rok = f8 < F8m;
#pragma unroll
  for (int ci = 0; ci < CIN; ++ci) {
    const ushort* base = in + (((size_t)(bb * CIN + ci)) << (log2F + 9));
#pragma unroll
    for (int dxw = 0; dxw < 3; ++dxw) {
      const int w2 = w + dxw - 1;
      if (w2 < 0 || w2 > 511) continue;
      const ushort* rp = base + ((size_t)w2 << log2F) + f0;
      const short8 cen = *(const short8*)rp;
      float xv[10];
      xv[0] = lok ? bf2f(rp[-1]) : 0.f;
#pragma unroll
      for (int j = 0; j < 8; ++j) xv[j + 1] = bf2f((ushort)cen[j]);
      xv[9] = rok ? bf2f(rp[8]) : 0.f;
#pragma unroll
      for (int co = 0; co < 4; ++co) {
        const float* wp = wt + (co * CIN + ci) * 9;
        const float k0 = wp[dxw], k1 = wp[3 + dxw], k2 = wp[6 + dxw];
#pragma unroll
        for (int j = 0; j < 8; ++j)
          acc[co][j] += k0 * xv[j] + k1 * xv[j + 1] + k2 * xv[j + 2];
      }
    }
  }
#pragma unroll
  for (int co = 0; co < 4; ++co) {
    short8 o;
#pragma unroll
    for (int j = 0; j < 8; ++j) o[j] = (short)f2bf(acc[co][j]);
    *(short8*)(outp + (((size_t)(bb * 4 + co)) << (log2F + 9)) + ((size_t)w << log2F) + f0) = o;
  }
}

// ---------------- layernorm over f (rows of 1024), H fp32 -> XN bf16 --------
__global__ __launch_bounds__(256) void ln_kernel(
    const float* __restrict__ H, const float* __restrict__ gam,
    const float* __restrict__ bet, ushort* __restrict__ XN)
{
  const int wid = threadIdx.x >> 6, lane = threadIdx.x & 63;
  const int row = blockIdx.x * 4 + wid;
  const int c = (row >> 9) & 3;
  const float* xp = H + (size_t)row * 1024;
  float4 v[4];
  float s = 0.f, q = 0.f;
#pragma unroll
  for (int p = 0; p < 4; ++p) {
    v[p] = *(const float4*)(xp + p * 256 + lane * 4);
    s += v[p].x + v[p].y + v[p].z + v[p].w;
    q += v[p].x * v[p].x + v[p].y * v[p].y + v[p].z * v[p].z + v[p].w * v[p].w;
  }
#pragma unroll
  for (int o = 32; o > 0; o >>= 1) { s += __shfl_xor(s, o); q += __shfl_xor(q, o); }
  const float mu = s * (1.f / 1024.f);
  const float var = q * (1.f / 1024.f) - mu * mu;
  const float rs = rsqrtf(var + 1e-5f);
  ushort* op = XN + (size_t)row * 1024;
  const float* gp = gam + c * 1024;
  const float* bp = bet + c * 1024;
#pragma unroll
  for (int p = 0; p < 4; ++p) {
    const int f = p * 256 + lane * 4;
    float4 g4 = *(const float4*)(gp + f);
    float4 b4 = *(const float4*)(bp + f);
    ushort4 o4;
    o4.x = f2bf((v[p].x - mu) * rs * g4.x + b4.x);
    o4.y = f2bf((v[p].y - mu) * rs * g4.y + b4.y);
    o4.z = f2bf((v[p].z - mu) * rs * g4.z + b4.z);
    o4.w = f2bf((v[p].w - mu) * rs * g4.w + b4.w);
    *(ushort4*)(op + f) = o4;
  }
}

// ---------------- softmax rows of 512: S fp32 -> P bf16 ---------------------
__global__ __launch_bounds__(256) void softmax_kernel(
    const float* __restrict__ S, ushort* __restrict__ P)
{
  const int wid = threadIdx.x >> 6, lane = threadIdx.x & 63;
  const size_t row = (size_t)blockIdx.x * 4 + wid;
  const float* sp = S + row * 512;
  float4 v0 = *(const float4*)(sp + lane * 4);
  float4 v1 = *(const float4*)(sp + 256 + lane * 4);
  float m = fmaxf(fmaxf(fmaxf(v0.x, v0.y), fmaxf(v0.z, v0.w)),
                  fmaxf(fmaxf(v1.x, v1.y), fmaxf(v1.z, v1.w)));
#pragma unroll
  for (int o = 32; o > 0; o >>= 1) m = fmaxf(m, __shfl_xor(m, o));
  float e0 = __expf(v0.x - m), e1 = __expf(v0.y - m), e2 = __expf(v0.z - m), e3 = __expf(v0.w - m);
  float e4 = __expf(v1.x - m), e5 = __expf(v1.y - m), e6 = __expf(v1.z - m), e7 = __expf(v1.w - m);
  float s = e0 + e1 + e2 + e3 + e4 + e5 + e6 + e7;
#pragma unroll
  for (int o = 32; o > 0; o >>= 1) s += __shfl_xor(s, o);
  const float inv = 1.f / s;
  ushort* pp = P + row * 512;
  ushort4 a, b;
  a.x = f2bf(e0 * inv); a.y = f2bf(e1 * inv); a.z = f2bf(e2 * inv); a.w = f2bf(e3 * inv);
  b.x = f2bf(e4 * inv); b.y = f2bf(e5 * inv); b.z = f2bf(e6 * inv); b.w = f2bf(e7 * inv);
  *(ushort4*)(pp + lane * 4) = a;
  *(ushort4*)(pp + 256 + lane * 4) = b;
}

// ---------------- RoPE in-place on bf16 [w][f] planes (pairs adjacent) ------
__global__ __launch_bounds__(256) void rope_kernel(uint* __restrict__ B)
{
  const int idx = blockIdx.x * 256 + threadIdx.x;
  const int fp = idx & 511;
  const int w = (idx >> 9) & 511;
  const int pl = idx >> 18;
  const int j = fp & 63;
  const float inv = __expf(-(float)j * (9.210340371976184f / 64.f));
  float sn, cs;
  sincosf((float)w * inv, &sn, &cs);
  uint* p = B + ((size_t)pl << 18) + ((size_t)w << 9) + fp;
  const uint pr = *p;
  const float e = bf2f((ushort)(pr & 0xFFFF));
  const float o = bf2f((ushort)(pr >> 16));
  const float ne = e * cs - o * sn;
  const float no = o * cs + e * sn;
  *p = ((uint)f2bf(no) << 16) | (uint)f2bf(ne);
}

// ---------------- transpose-in: x fp32 [f][w] -> XT bf16 [w][f] -------------
__global__ __launch_bounds__(256) void tin_kernel(
    const float* __restrict__ x, ushort* __restrict__ XT, int planeOff)
{
  __shared__ float t[32][33];
  const int f0 = blockIdx.x * 32, w0 = blockIdx.y * 32;
  const int z = blockIdx.z;
  const int tx = threadIdx.x & 31, ty = threadIdx.x >> 5;
  const float* src = x + (size_t)(planeOff + z) * PLF;
#pragma unroll
  for (int r = 0; r < 32; r += 8) t[r + ty][tx] = src[(size_t)(f0 + r + ty) * 512 + w0 + tx];
  __syncthreads();
  ushort* dst = XT + (size_t)z * PLF;
#pragma unroll
  for (int r = 0; r < 32; r += 8) dst[(size_t)(w0 + r + ty) * 1024 + f0 + tx] = f2bf(t[tx][r + ty]);
}

// ---------------- transpose-out: H fp32 [w][f] -> out[b][8+c][f][w] ---------
__global__ __launch_bounds__(256) void tout_kernel(
    const float* __restrict__ H, float* __restrict__ out, int b0)
{
  __shared__ float t[32][33];
  const int w0 = blockIdx.x * 32, f0 = blockIdx.y * 32;
  const int p = blockIdx.z;
  const int b = b0 + (p >> 2), c = p & 3;
  const int tx = threadIdx.x & 31, ty = threadIdx.x >> 5;
  const float* src = H + (size_t)p * PLF;
#pragma unroll
  for (int r = 0; r < 32; r += 8) t[r + ty][tx] = src[(size_t)(w0 + r + ty) * 1024 + f0 + tx];
  __syncthreads();
  float* dst = out + (size_t)(b * 12 + 8 + c) * PLF;
#pragma unroll
  for (int r = 0; r < 32; r += 8) dst[(size_t)(f0 + r + ty) * 512 + w0 + tx] = t[tx][r + ty];
}

// ---------------- copy x -> out channels 0..7 (fp32, float4) ---------------
__global__ __launch_bounds__(256) void copyx_kernel(
    const float4* __restrict__ x, float4* __restrict__ out)
{
  const int idx = blockIdx.x * 256 + threadIdx.x;   // 4,194,304 float4s
  const int pl = idx >> 17;                          // PLF/4 = 131072 per plane
  const int rem = idx & 131071;
  const int b = pl >> 3, ch = pl & 7;
  out[(size_t)(b * 12 + ch) * 131072 + rem] = x[idx];
}

// ---------------------------------------------------------------------------
extern "C" void kernel_launch(void* const* d_in, const int* in_sizes, int n_in,
                              void* d_out, int out_size, void* d_ws, size_t ws_size,
                              hipStream_t stream)
{
  const float* x        = (const float*)d_in[0];
  const float* embed_cw = (const float*)d_in[1];
  const float* embed_cb = (const float*)d_in[2];
  const float* embed_pw = (const float*)d_in[3];
  const float* n1g      = (const float*)d_in[4];
  const float* n1b      = (const float*)d_in[5];
  const float* q_cw     = (const float*)d_in[6];
  const float* q_cb     = (const float*)d_in[7];
  const float* q_pw     = (const float*)d_in[8];
  const float* k_cw     = (const float*)d_in[9];
  const float* k_cb     = (const float*)d_in[10];
  const float* k_pw     = (const float*)d_in[11];
  const float* v_cw     = (const float*)d_in[12];
  const float* v_cb     = (const float*)d_in[13];
  const float* v_pw     = (const float*)d_in[14];
  const float* o_cw     = (const float*)d_in[15];
  const float* o_cb     = (const float*)d_in[16];
  const float* o_pw     = (const float*)d_in[17];
  const float* n2g      = (const float*)d_in[18];
  const float* n2b      = (const float*)d_in[19];
  const float* f1_cw    = (const float*)d_in[20];
  const float* f1_cb    = (const float*)d_in[21];
  const float* f1_pw    = (const float*)d_in[22];
  const float* f2_cw    = (const float*)d_in[23];
  const float* f2_cb    = (const float*)d_in[24];
  const float* f2_pw    = (const float*)d_in[25];
  float* out = (float*)d_out;

  const size_t perB = 50331648ull;
  const int N = (ws_size >= 4 * perB) ? 4 : (ws_size >= 2 * perB) ? 2 : 1;
  const int nP = 4 * N;

  char* base = (char*)d_ws;
  float*  Hf = (float*)base;                                    // N*8388608 B
  ushort* XT = (ushort*)(base + (size_t)N * 8388608);           // N*8388608 B
  ushort* XN = (ushort*)((char*)XT + (size_t)N * 8388608);      // N*4194304 B
  ushort* Qb = (ushort*)((char*)XN + (size_t)N * 4194304);
  ushort* CT = (ushort*)((char*)Qb + (size_t)N * 4194304);
  ushort* Kb = (ushort*)((char*)CT + (size_t)N * 4194304);
  ushort* Vb = (ushort*)((char*)Kb + (size_t)N * 4194304);
  float*  Sf = (float*)((char*)Vb + (size_t)N * 4194304);       // N*8388608 B
  ushort* Pb = (ushort*)((char*)Sf + (size_t)N * 8388608);      // N*4194304 B
  ushort* MID = XT;                    // overlays XT+XN+Qb
  ushort* F2C = Kb;                    // overlays Kb+Vb+Sf
  ushort* W8  = (N == 1) ? (ushort*)Sf : Pb;   // 8.4MB slot for small bf16 weights
  ushort* f1w = Kb;                    // 33.5MB span (N>=2 only)
  ushort* f2w = XT;                    // 33.5MB span (N>=2 only)

  const long long W1 = 1048576;     // per-channel 1024x1024 weight, elements
  const long long W4 = 4194304;     // 4096x1024 / 1024x4096 weight, elements
  const long long P4 = 4LL * PLF;
  const long long M1 = 2097152;     // 4096*512 plane, elements
  const int GCc1 = N * 256;         // conv4c blocks at F=1024
  const int GCc4 = N * 1024;        // conv4c blocks at F=4096

  copyx_kernel<<<16384, 256, 0, stream>>>((const float4*)x, (float4*)out);

  for (int b0 = 0; b0 < 4; b0 += N) {
    // --- input transpose ---
    tin_kernel<<<dim3(32, 16, 8 * N), 256, 0, stream>>>(x, XT, b0 * 8);
    // --- embed ---
    conv4c_kernel<8><<<GCc1, 256, 0, stream>>>(XT, embed_cw, embed_cb, CT, 10);
    cvt_kernel<<<2048, 256, 0, stream>>>((const float4*)embed_pw, (short8*)W8);
    mm_kernel<0, 0, 0, 0, 0><<<dim3(8, 4, nP), 256, 0, stream>>>(
        CT, W8, Hf, 1024, 1024, 1024, 1024,
        N, PLF, P4, N, W1, 0, N, PLF, P4, 1.f);
    // --- LN1 ---
    ln_kernel<<<nP * 128, 256, 0, stream>>>(Hf, n1g, n1b, XN);
    // --- q/k/v projections ---
    conv4c_kernel<4><<<GCc1, 256, 0, stream>>>(XN, q_cw, q_cb, CT, 10);
    cvt_kernel<<<2048, 256, 0, stream>>>((const float4*)q_pw, (short8*)W8);
    mm_kernel<1, 0, 0, 0, 0><<<dim3(8, 4, nP), 256, 0, stream>>>(
        CT, W8, Qb, 1024, 1024, 1024, 1024,
        N, PLF, P4, N, W1, 0, N, PLF, P4, 1.f);
    conv4c_kernel<4><<<GCc1, 256, 0, stream>>>(XN, k_cw, k_cb, CT, 10);
    cvt_kernel<<<2048, 256, 0, stream>>>((const float4*)k_pw, (short8*)W8);
    mm_kernel<1, 0, 0, 0, 0><<<dim3(8, 4, nP), 256, 0, stream>>>(
        CT, W8, Kb, 1024, 1024, 1024, 1024,
        N, PLF, P4, N, W1, 0, N, PLF, P4, 1.f);
    conv4c_kernel<4><<<GCc1, 256, 0, stream>>>(XN, v_cw, v_cb, CT, 10);
    cvt_kernel<<<2048, 256, 0, stream>>>((const float4*)v_pw, (short8*)W8);
    mm_kernel<1, 0, 0, 0, 0><<<dim3(4, 8, nP), 256, 0, stream>>>(
        W8, CT, Vb, 1024, 1024, 1024, 512,
        N, W1, 0, N, PLF, P4, N, PLF, P4, 1.f);        // V stored [f][w]
    // --- RoPE ---
    rope_kernel<<<nP * 1024, 256, 0, stream>>>((uint*)Qb);
    rope_kernel<<<nP * 1024, 256, 0, stream>>>((uint*)Kb);
    // --- attention, 4 chunks of 8N head-batches ---
    for (int sc = 0; sc < 4; ++sc) {
      const size_t po = (size_t)sc * N * PLF;
      mm_kernel<0, 0, 0, 0, 0><<<dim3(4, 4, 8 * N), 256, 0, stream>>>(
          Qb + po, Kb + po, Sf, 128, 1024, 1024, 512,
          8, PLF, 128, 8, PLF, 128, 1, 262144, 0, 1.f / 32.f);
      softmax_kernel<<<N * 1024, 256, 0, stream>>>(Sf, Pb);
      mm_kernel<1, 0, 0, 0, 0><<<dim3(1, 4, 8 * N), 256, 0, stream>>>(
          Pb, Vb + po, Qb + po, 512, 512, 512, 1024,
          1, 262144, 0, 8, PLF, 65536, 8, PLF, 128, 1.f);
    }
    // --- o projection (accumulate into H) ---
    conv4c_kernel<4><<<GCc1, 256, 0, stream>>>(Qb, o_cw, o_cb, CT, 10);
    cvt_kernel<<<2048, 256, 0, stream>>>((const float4*)o_pw, (short8*)W8);
    mm_kernel<0, 1, 0, 0, 0><<<dim3(8, 4, nP), 256, 0, stream>>>(
        CT, W8, Hf, 1024, 1024, 1024, 1024,
        N, PLF, P4, N, W1, 0, N, PLF, P4, 1.f);
    // --- LN2 ---
    ln_kernel<<<nP * 128, 256, 0, stream>>>(Hf, n2g, n2b, XN);
    // --- ffn1 (+fused squared relu) ---
    conv4c_kernel<4><<<GCc1, 256, 0, stream>>>(XN, f1_cw, f1_cb, CT, 10);
    if (N >= 2) {
      cvt_kernel<<<8192, 256, 0, stream>>>((const float4*)f1_pw, (short8*)f1w);
      mm_kernel<1, 0, 1, 1, 0><<<dim3(32, 4, nP), 256, 0, stream>>>(
          CT, f1w, MID, 1024, 1024, 1024, 4096,
          N, PLF, P4, N, W4, 0, N, M1, 4 * M1, 1.f);
    } else {
      mm_kernel<1, 0, 1, 1, 1><<<dim3(32, 4, nP), 256, 0, stream>>>(
          CT, f1_pw, MID, 1024, 1024, 1024, 4096,
          N, PLF, P4, N, W4, 0, N, M1, 4 * M1, 1.f);
    }
    // --- ffn2 conv (F=4096) then pw accumulate into H ---
    conv4c_kernel<4><<<GCc4, 256, 0, stream>>>(MID, f2_cw, f2_cb, F2C, 12);
    if (N >= 2) {
      cvt_kernel<<<8192, 256, 0, stream>>>((const float4*)f2_pw, (short8*)f2w);
      mm_kernel<0, 1, 0, 0, 0><<<dim3(8, 4, nP), 256, 0, stream>>>(
          F2C, f2w, Hf, 4096, 4096, 4096, 1024,
          N, M1, 4 * M1, N, W4, 0, N, PLF, P4, 1.f);
    } else {
      mm_kernel<0, 1, 0, 0, 1><<<dim3(8, 4, nP), 256, 0, stream>>>(
          F2C, f2_pw, Hf, 4096, 4096, 4096, 1024,
          N, M1, 4 * M1, N, W4, 0, N, PLF, P4, 1.f);
    }
    // --- output transpose ---
    tout_kernel<<<dim3(16, 32, nP), 256, 0, stream>>>(Hf, out, b0);
  }
}

// Round 7
// 731.639 us; speedup vs baseline: 12.3814x; 1.0569x over previous
//
#include <hip/hip_runtime.h>

typedef __attribute__((ext_vector_type(8))) short short8;
typedef __attribute__((ext_vector_type(4))) float f32x4;
typedef unsigned int uint;
typedef unsigned short ushort;

#define PLF 524288   // 1024*512 elements per activation plane

__device__ __forceinline__ ushort f2bf(float f) {
  uint u = __float_as_uint(f);
  u += 0x7FFF + ((u >> 16) & 1);   // RNE
  return (ushort)(u >> 16);
}
__device__ __forceinline__ float bf2f(ushort h) {
  return __uint_as_float(((uint)h) << 16);
}
__device__ __forceinline__ int swzf(int r) { return ((r & 3) ^ ((r >> 2) & 3)); }

#define GLOAD16(gp, lp)                                          \
  __builtin_amdgcn_global_load_lds(                              \
      (const __attribute__((address_space(1))) void*)(gp),       \
      (__attribute__((address_space(3))) void*)(lp), 16, 0, 0)

// ---------------------------------------------------------------------------
// MFMA GEMM: C[m][n] = alpha * sum_k A[m][k] * B[n][k]  (both row-major-K)
// BN: 128 (2x2 waves, 64x64/wave) or 64 (4x1 waves, 32x64/wave).
// ---------------------------------------------------------------------------
template <int CDT, int BETA, int RELU2, int MFAST, int BCVT, int BN>
__global__ __launch_bounds__(256) void mm_kernel(
    const void* __restrict__ Av, const void* __restrict__ Bv, void* __restrict__ Cv,
    int K, int lda, int ldb, int ldc,
    int aDiv, long long aS1, long long aS2,
    int bDiv, long long bS1, long long bS2,
    int cDiv, long long cS1, long long cS2, float alpha)
{
  constexpr int LDSB = 8192 + BN * 64;
  constexpr int MI = (BN == 128) ? 4 : 2;
  __shared__ char lds[2 * LDSB];
  const int nx = gridDim.x, ny = gridDim.y;
  const int nwg = nx * ny * (int)gridDim.z;
  const int o = ((int)blockIdx.z * ny + blockIdx.y) * nx + blockIdx.x;
  const int qd = nwg >> 3, rm = nwg & 7, xcd = o & 7, rot = o >> 3;
  const int wflat = (xcd < rm ? xcd * (qd + 1) : rm * (qd + 1) + (xcd - rm) * qd) + rot;
  int bx, by, bz;
  if (MFAST) { by = wflat % ny; int t2 = wflat / ny; bx = t2 % nx; bz = t2 / nx; }
  else       { bx = wflat % nx; int t2 = wflat / nx; by = t2 % ny; bz = t2 / ny; }
  const int tid = threadIdx.x;
  const long long aOff = (long long)(bz / aDiv) * aS1 + (long long)(bz % aDiv) * aS2;
  const long long bOff = (long long)(bz / bDiv) * bS1 + (long long)(bz % bDiv) * bS2;
  const long long cOff = (long long)(bz / cDiv) * cS1 + (long long)(bz % cDiv) * cS2;
  const int m0 = by * 128, n0 = bx * BN;
  const int lane = tid & 63, wid = tid >> 6;
  const int MOFF = (BN == 128) ? (wid >> 1) * 64 : wid * 32;
  const int NOFF = (BN == 128) ? (wid & 1) * 64 : 0;
  const int u = lane & 15, g = lane >> 4;
  const int sr0 = tid >> 2, sslot = tid & 3;
  const ushort* Ap = (const ushort*)Av + aOff;
  const ushort* Bp = (const ushort*)Bv + bOff;
  const float*  Bf = (const float*)Bv + bOff;

#define STAGE(buf, kt)                                                         \
  {                                                                            \
    _Pragma("unroll")                                                          \
    for (int half = 0; half < 2; ++half) {                                     \
      const int r = sr0 + 64 * half;                                           \
      const int ss = sslot ^ swzf(r);                                          \
      GLOAD16(Ap + (long long)(m0 + r) * lda + (kt) + ss * 8,                  \
              &lds[(buf) * LDSB] + wid * 1024 + half * 4096);                  \
    }                                                                          \
    _Pragma("unroll")                                                          \
    for (int bh = 0; bh < BN / 64; ++bh) {                                     \
      const int r = sr0 + 64 * bh;                                             \
      const int ss = sslot ^ swzf(r);                                          \
      if (BCVT == 0) {                                                         \
        GLOAD16(Bp + (long long)(n0 + r) * ldb + (kt) + ss * 8,                \
                &lds[(buf) * LDSB + 8192] + wid * 1024 + bh * 4096);           \
      } else {                                                                 \
        const float* srcB = Bf + (long long)(n0 + r) * ldb + (kt) + ss * 8;    \
        float4 x0 = *(const float4*)srcB;                                      \
        float4 x1 = *(const float4*)(srcB + 4);                                \
        short8 h;                                                              \
        h[0] = (short)f2bf(x0.x); h[1] = (short)f2bf(x0.y);                    \
        h[2] = (short)f2bf(x0.z); h[3] = (short)f2bf(x0.w);                    \
        h[4] = (short)f2bf(x1.x); h[5] = (short)f2bf(x1.y);                    \
        h[6] = (short)f2bf(x1.z); h[7] = (short)f2bf(x1.w);                    \
        *(short8*)(&lds[(buf) * LDSB + 8192] + r * 64 + sslot * 16) = h;       \
      }                                                                        \
    }                                                                          \
  }

  f32x4 acc[MI][4];
#pragma unroll
  for (int i = 0; i < MI; ++i)
#pragma unroll
    for (int j = 0; j < 4; ++j) acc[i][j] = (f32x4){0.f, 0.f, 0.f, 0.f};

  STAGE(0, 0);
  asm volatile("s_waitcnt vmcnt(0) lgkmcnt(0)" ::: "memory");
  __builtin_amdgcn_s_barrier();
  int cur = 0;
  for (int kt = 0; kt < K; kt += 32) {
    if (kt + 32 < K) STAGE(cur ^ 1, kt + 32);
    short8 af[MI], bfr[4];
#pragma unroll
    for (int mi = 0; mi < MI; ++mi) {
      const int r = MOFF + mi * 16 + u;
      af[mi] = *(const short8*)(&lds[cur * LDSB] + r * 64 + ((g ^ swzf(r)) * 16));
    }
#pragma unroll
    for (int ni = 0; ni < 4; ++ni) {
      const int r = NOFF + ni * 16 + u;
      bfr[ni] = *(const short8*)(&lds[cur * LDSB + 8192] + r * 64 + ((g ^ swzf(r)) * 16));
    }
#pragma unroll
    for (int mi = 0; mi < MI; ++mi)
#pragma unroll
      for (int ni = 0; ni < 4; ++ni)
        acc[mi][ni] = __builtin_amdgcn_mfma_f32_16x16x32_bf16(af[mi], bfr[ni], acc[mi][ni], 0, 0, 0);
    asm volatile("s_waitcnt vmcnt(0) lgkmcnt(0)" ::: "memory");
    __builtin_amdgcn_s_barrier();
    cur ^= 1;
  }
#undef STAGE

#pragma unroll
  for (int mi = 0; mi < MI; ++mi)
#pragma unroll
    for (int ni = 0; ni < 4; ++ni)
#pragma unroll
      for (int q = 0; q < 4; ++q) {
        const int row = m0 + MOFF + mi * 16 + g * 4 + q;
        const int col = n0 + NOFF + ni * 16 + u;
        float v = acc[mi][ni][q] * alpha;
        if (CDT == 0) {
          float* cp = (float*)Cv + cOff + (long long)row * ldc + col;
          if (BETA) v += *cp;
          *cp = v;
        } else {
          if (RELU2) { v = fmaxf(v, 0.f); v = v * v; }
          ((ushort*)Cv)[cOff + (long long)row * ldc + col] = f2bf(v);
        }
      }
}

// ---------------------------------------------------------------------------
// Fused flash attention. Block: 64 q-rows of one head-batch, 4 waves x 16 rows.
// Q,K planes [w][1024] (head cols h*128..); V^T plane [1024 f][512 w].
// O overwrites Q region. grid (8 q-tiles, nP*8 heads).
// ---------------------------------------------------------------------------
__global__ __launch_bounds__(256) void fattn_kernel(
    const ushort* __restrict__ Qg, const ushort* __restrict__ Kg,
    const ushort* __restrict__ Vg, ushort* __restrict__ Og)
{
  __shared__ char lds[73728];   // K 2x16KB | V 2x16KB @32768 | P 4x2KB @65536
  const int hb = blockIdx.y, pl = hb >> 3, h = hb & 7;
  const int q0 = blockIdx.x * 64;
  const int tid = threadIdx.x, lane = tid & 63, wv = tid >> 6;
  const int u = lane & 15, g = lane >> 4;
  const ushort* Qh = Qg + (size_t)pl * PLF + h * 128;
  const ushort* Kh = Kg + (size_t)pl * PLF + h * 128;
  const ushort* Vh = Vg + (size_t)pl * PLF + (size_t)(h * 128) * 512;
  ushort* Oh = Og + (size_t)pl * PLF + h * 128;

  short8 qf[4];
  const int qrow = q0 + wv * 16 + u;
#pragma unroll
  for (int dc = 0; dc < 4; ++dc)
    qf[dc] = *(const short8*)(Qh + (size_t)qrow * 1024 + dc * 32 + g * 8);

#define STAGE_KV(buf, kt)                                                     \
  {                                                                           \
    _Pragma("unroll")                                                         \
    for (int it = 0; it < 4; ++it) {                                          \
      const int off = tid * 16 + it * 4096;                                   \
      const int krow = off >> 8, kslot = (off >> 4) & 15;                     \
      GLOAD16(Kh + (size_t)((kt) * 64 + krow) * 1024 +                        \
                  ((kslot ^ ((krow & 7) << 1)) * 8),                          \
              &lds[(buf) * 16384] + off);                                     \
      const int vrow = off >> 7, vslot = (off >> 4) & 7;                      \
      GLOAD16(Vh + (size_t)vrow * 512 + (kt) * 64 + ((vslot ^ (vrow & 7)) * 8), \
              &lds[32768 + (buf) * 16384] + off);                             \
    }                                                                         \
  }

  f32x4 oacc[8];
#pragma unroll
  for (int i = 0; i < 8; ++i) oacc[i] = (f32x4){0.f, 0.f, 0.f, 0.f};
  float m_run = -3.0e38f, l_run = 0.f;

  STAGE_KV(0, 0);
  asm volatile("s_waitcnt vmcnt(0)" ::: "memory");
  __syncthreads();
  int cur = 0;
  for (int kt = 0; kt < 8; ++kt) {
    if (kt + 1 < 8) STAGE_KV(cur ^ 1, kt + 1);
    // S^T: rows k, cols q  (swapped operands)
    f32x4 sacc[4];
#pragma unroll
    for (int kn = 0; kn < 4; ++kn) sacc[kn] = (f32x4){0.f, 0.f, 0.f, 0.f};
#pragma unroll
    for (int kn = 0; kn < 4; ++kn) {
      const int r = kn * 16 + u;
      const char* kb = &lds[cur * 16384] + r * 256;
#pragma unroll
      for (int dc = 0; dc < 4; ++dc) {
        short8 kf = *(const short8*)(kb + (((dc * 4 + g) ^ ((u & 7) << 1)) * 16));
        sacc[kn] = __builtin_amdgcn_mfma_f32_16x16x32_bf16(kf, qf[dc], sacc[kn], 0, 0, 0);
      }
    }
    // online softmax; lane owns q=u, k = kt*64 + kn*16 + g*4 + r
    float pm = -3.0e38f;
#pragma unroll
    for (int kn = 0; kn < 4; ++kn)
#pragma unroll
      for (int r = 0; r < 4; ++r) {
        sacc[kn][r] *= 0.03125f;
        pm = fmaxf(pm, sacc[kn][r]);
      }
    pm = fmaxf(pm, __shfl_xor(pm, 16));
    pm = fmaxf(pm, __shfl_xor(pm, 32));
    const float m_new = fmaxf(m_run, pm);
    const float es = __expf(m_run - m_new);
    float psum = 0.f;
    uint pw[4][2];
#pragma unroll
    for (int kn = 0; kn < 4; ++kn) {
      float p0 = __expf(sacc[kn][0] - m_new);
      float p1 = __expf(sacc[kn][1] - m_new);
      float p2 = __expf(sacc[kn][2] - m_new);
      float p3 = __expf(sacc[kn][3] - m_new);
      psum += (p0 + p1) + (p2 + p3);
      pw[kn][0] = (uint)f2bf(p0) | ((uint)f2bf(p1) << 16);
      pw[kn][1] = (uint)f2bf(p2) | ((uint)f2bf(p3) << 16);
    }
    psum += __shfl_xor(psum, 16);
    psum += __shfl_xor(psum, 32);
    l_run = l_run * es + psum;
    m_run = m_new;
    // write P (wave-private, swizzled 16B slots)
    char* pb = &lds[65536 + wv * 2048] + u * 128 + (g & 1) * 8;
#pragma unroll
    for (int kn = 0; kn < 4; ++kn)
      *(uint2*)(pb + (((2 * kn + (g >> 1)) ^ (u & 7)) * 16)) =
          make_uint2(pw[kn][0], pw[kn][1]);
    // O rescale (O rows are g*4+r; es lives at lane u=row)
    float es_o[4];
#pragma unroll
    for (int r = 0; r < 4; ++r) es_o[r] = __shfl(es, g * 4 + r);
#pragma unroll
    for (int nd = 0; nd < 8; ++nd)
#pragma unroll
      for (int r = 0; r < 4; ++r) oacc[nd][r] *= es_o[r];
    // PV
    const char* prd = &lds[65536 + wv * 2048] + u * 128;
    short8 pf[2];
#pragma unroll
    for (int kc = 0; kc < 2; ++kc)
      pf[kc] = *(const short8*)(prd + (((kc * 4 + g) ^ (u & 7)) * 16));
#pragma unroll
    for (int nd = 0; nd < 8; ++nd) {
      const int vr = nd * 16 + u;
      const char* vb = &lds[32768 + cur * 16384] + vr * 128;
#pragma unroll
      for (int kc = 0; kc < 2; ++kc) {
        short8 vf = *(const short8*)(vb + (((kc * 4 + g) ^ (u & 7)) * 16));
        oacc[nd] = __builtin_amdgcn_mfma_f32_16x16x32_bf16(pf[kc], vf, oacc[nd], 0, 0, 0);
      }
    }
    asm volatile("s_waitcnt vmcnt(0)" ::: "memory");
    __syncthreads();
    cur ^= 1;
  }
#undef STAGE_KV
  const float inv_l = 1.f / l_run;
  float inv_o[4];
#pragma unroll
  for (int r = 0; r < 4; ++r) inv_o[r] = __shfl(inv_l, g * 4 + r);
#pragma unroll
  for (int nd = 0; nd < 8; ++nd)
#pragma unroll
    for (int r = 0; r < 4; ++r) {
      const int row = q0 + wv * 16 + g * 4 + r;
      Oh[(size_t)row * 1024 + nd * 16 + u] = f2bf(oacc[nd][r] * inv_o[r]);
    }
}

// ---------------- fp32 -> bf16 weight conversion (8 elem/thread) ------------
__global__ __launch_bounds__(256) void cvt_kernel(
    const float4* __restrict__ s, short8* __restrict__ d)
{
  const int i = blockIdx.x * 256 + threadIdx.x;
  const float4 a = s[2 * i], b = s[2 * i + 1];
  short8 h;
  h[0] = (short)f2bf(a.x); h[1] = (short)f2bf(a.y);
  h[2] = (short)f2bf(a.z); h[3] = (short)f2bf(a.w);
  h[4] = (short)f2bf(b.x); h[5] = (short)f2bf(b.y);
  h[6] = (short)f2bf(b.z); h[7] = (short)f2bf(b.w);
  d[i] = h;
}

// ---------------------------------------------------------------------------
// conv 3x3 SAME on [512 w][F f] planes; 8 f-outputs x 4 out-channels/thread.
// ---------------------------------------------------------------------------
template <int CIN>
__global__ __launch_bounds__(256) void conv4c_kernel(
    const ushort* __restrict__ in, const float* __restrict__ wt,
    const float* __restrict__ bias, ushort* __restrict__ outp, int log2F)
{
  const int idx = blockIdx.x * 256 + threadIdx.x;
  const int F8m = (1 << (log2F - 3)) - 1;
  const int f8 = idx & F8m;
  const int w = (idx >> (log2F - 3)) & 511;
  const int bb = idx >> (log2F + 6);
  const int f0 = f8 << 3;
  float acc[4][8];
#pragma unroll
  for (int co = 0; co < 4; ++co) {
    const float bv = bias[co];
#pragma unroll
    for (int j = 0; j < 8; ++j) acc[co][j] = bv;
  }
  const bool lok = f8 > 0, rok = f8 < F8m;
#pragma unroll
  for (int ci = 0; ci < CIN; ++ci) {
    const ushort* base = in + (((size_t)(bb * CIN + ci)) << (log2F + 9));
#pragma unroll
    for (int dxw = 0; dxw < 3; ++dxw) {
      const int w2 = w + dxw - 1;
      if (w2 < 0 || w2 > 511) continue;
      const ushort* rp = base + ((size_t)w2 << log2F) + f0;
      const short8 cen = *(const short8*)rp;
      float xv[10];
      xv[0] = lok ? bf2f(rp[-1]) : 0.f;
#pragma unroll
      for (int j = 0; j < 8; ++j) xv[j + 1] = bf2f((ushort)cen[j]);
      xv[9] = rok ? bf2f(rp[8]) : 0.f;
#pragma unroll
      for (int co = 0; co < 4; ++co) {
        const float* wp = wt + (co * CIN + ci) * 9;
        const float k0 = wp[dxw], k1 = wp[3 + dxw], k2 = wp[6 + dxw];
#pragma unroll
        for (int j = 0; j < 8; ++j)
          acc[co][j] += k0 * xv[j] + k1 * xv[j + 1] + k2 * xv[j + 2];
      }
    }
  }
#pragma unroll
  for (int co = 0; co < 4; ++co) {
    short8 o;
#pragma unroll
    for (int j = 0; j < 8; ++j) o[j] = (short)f2bf(acc[co][j]);
    *(short8*)(outp + (((size_t)(bb * 4 + co)) << (log2F + 9)) + ((size_t)w << log2F) + f0) = o;
  }
}

// ---------------- layernorm over f (rows of 1024), H fp32 -> XN bf16 --------
__global__ __launch_bounds__(256) void ln_kernel(
    const float* __restrict__ H, const float* __restrict__ gam,
    const float* __restrict__ bet, ushort* __restrict__ XN)
{
  const int wid = threadIdx.x >> 6, lane = threadIdx.x & 63;
  const int row = blockIdx.x * 4 + wid;
  const int c = (row >> 9) & 3;
  const float* xp = H + (size_t)row * 1024;
  float4 v[4];
  float s = 0.f, q = 0.f;
#pragma unroll
  for (int p = 0; p < 4; ++p) {
    v[p] = *(const float4*)(xp + p * 256 + lane * 4);
    s += v[p].x + v[p].y + v[p].z + v[p].w;
    q += v[p].x * v[p].x + v[p].y * v[p].y + v[p].z * v[p].z + v[p].w * v[p].w;
  }
#pragma unroll
  for (int o = 32; o > 0; o >>= 1) { s += __shfl_xor(s, o); q += __shfl_xor(q, o); }
  const float mu = s * (1.f / 1024.f);
  const float var = q * (1.f / 1024.f) - mu * mu;
  const float rs = rsqrtf(var + 1e-5f);
  ushort* op = XN + (size_t)row * 1024;
  const float* gp = gam + c * 1024;
  const float* bp = bet + c * 1024;
#pragma unroll
  for (int p = 0; p < 4; ++p) {
    const int f = p * 256 + lane * 4;
    float4 g4 = *(const float4*)(gp + f);
    float4 b4 = *(const float4*)(bp + f);
    ushort4 o4;
    o4.x = f2bf((v[p].x - mu) * rs * g4.x + b4.x);
    o4.y = f2bf((v[p].y - mu) * rs * g4.y + b4.y);
    o4.z = f2bf((v[p].z - mu) * rs * g4.z + b4.z);
    o4.w = f2bf((v[p].w - mu) * rs * g4.w + b4.w);
    *(ushort4*)(op + f) = o4;
  }
}

// ---------------- RoPE in-place on bf16 [w][f] planes (pairs adjacent) ------
__global__ __launch_bounds__(256) void rope_kernel(uint* __restrict__ B)
{
  const int idx = blockIdx.x * 256 + threadIdx.x;
  const int fp = idx & 511;
  const int w = (idx >> 9) & 511;
  const int pl = idx >> 18;
  const int j = fp & 63;
  const float inv = __expf(-(float)j * (9.210340371976184f / 64.f));
  float sn, cs;
  sincosf((float)w * inv, &sn, &cs);
  uint* p = B + ((size_t)pl << 18) + ((size_t)w << 9) + fp;
  const uint pr = *p;
  const float e = bf2f((ushort)(pr & 0xFFFF));
  const float o = bf2f((ushort)(pr >> 16));
  const float ne = e * cs - o * sn;
  const float no = o * cs + e * sn;
  *p = ((uint)f2bf(no) << 16) | (uint)f2bf(ne);
}

// ---- transpose-in: x fp32 [f][w] -> XT bf16 [w][f]; also copy x -> out -----
__global__ __launch_bounds__(256) void tin_kernel(
    const float* __restrict__ x, ushort* __restrict__ XT,
    float* __restrict__ outp, int planeOff)
{
  __shared__ float t[32][33];
  const int f0 = blockIdx.x * 32, w0 = blockIdx.y * 32;
  const int z = blockIdx.z;
  const int tx = threadIdx.x & 31, ty = threadIdx.x >> 5;
  const int gpl = planeOff + z;
  const int b = gpl >> 3, ch = gpl & 7;
  const float* src = x + (size_t)gpl * PLF;
  float* dst0 = outp + (size_t)(b * 12 + ch) * PLF;
#pragma unroll
  for (int r = 0; r < 32; r += 8) {
    const size_t off = (size_t)(f0 + r + ty) * 512 + w0 + tx;
    const float v = src[off];
    t[r + ty][tx] = v;
    dst0[off] = v;
  }
  __syncthreads();
  ushort* dst = XT + (size_t)z * PLF;
#pragma unroll
  for (int r = 0; r < 32; r += 8) dst[(size_t)(w0 + r + ty) * 1024 + f0 + tx] = f2bf(t[tx][r + ty]);
}

// ---------------- transpose-out: H fp32 [w][f] -> out[b][8+c][f][w] ---------
__global__ __launch_bounds__(256) void tout_kernel(
    const float* __restrict__ H, float* __restrict__ out, int b0)
{
  __shared__ float t[32][33];
  const int w0 = blockIdx.x * 32, f0 = blockIdx.y * 32;
  const int p = blockIdx.z;
  const int b = b0 + (p >> 2), c = p & 3;
  const int tx = threadIdx.x & 31, ty = threadIdx.x >> 5;
  const float* src = H + (size_t)p * PLF;
#pragma unroll
  for (int r = 0; r < 32; r += 8) t[r + ty][tx] = src[(size_t)(w0 + r + ty) * 1024 + f0 + tx];
  __syncthreads();
  float* dst = out + (size_t)(b * 12 + 8 + c) * PLF;
#pragma unroll
  for (int r = 0; r < 32; r += 8) dst[(size_t)(f0 + r + ty) * 512 + w0 + tx] = t[tx][r + ty];
}

// ---------------------------------------------------------------------------
extern "C" void kernel_launch(void* const* d_in, const int* in_sizes, int n_in,
                              void* d_out, int out_size, void* d_ws, size_t ws_size,
                              hipStream_t stream)
{
  const float* x        = (const float*)d_in[0];
  const float* embed_cw = (const float*)d_in[1];
  const float* embed_cb = (const float*)d_in[2];
  const float* embed_pw = (const float*)d_in[3];
  const float* n1g      = (const float*)d_in[4];
  const float* n1b      = (const float*)d_in[5];
  const float* q_cw     = (const float*)d_in[6];
  const float* q_cb     = (const float*)d_in[7];
  const float* q_pw     = (const float*)d_in[8];
  const float* k_cw     = (const float*)d_in[9];
  const float* k_cb     = (const float*)d_in[10];
  const float* k_pw     = (const float*)d_in[11];
  const float* v_cw     = (const float*)d_in[12];
  const float* v_cb     = (const float*)d_in[13];
  const float* v_pw     = (const float*)d_in[14];
  const float* o_cw     = (const float*)d_in[15];
  const float* o_cb     = (const float*)d_in[16];
  const float* o_pw     = (const float*)d_in[17];
  const float* n2g      = (const float*)d_in[18];
  const float* n2b      = (const float*)d_in[19];
  const float* f1_cw    = (const float*)d_in[20];
  const float* f1_cb    = (const float*)d_in[21];
  const float* f1_pw    = (const float*)d_in[22];
  const float* f2_cw    = (const float*)d_in[23];
  const float* f2_cb    = (const float*)d_in[24];
  const float* f2_pw    = (const float*)d_in[25];
  float* out = (float*)d_out;

  const size_t perB = 50331648ull;
  const int N = (ws_size >= 4 * perB) ? 4 : (ws_size >= 2 * perB) ? 2 : 1;
  const int nP = 4 * N;

  char* base = (char*)d_ws;
  float*  Hf = (float*)base;                                    // N*8388608 B
  ushort* XT = (ushort*)(base + (size_t)N * 8388608);           // N*8388608 B
  ushort* XN = (ushort*)((char*)XT + (size_t)N * 8388608);      // N*4194304 B
  ushort* Qb = (ushort*)((char*)XN + (size_t)N * 4194304);
  ushort* CT = (ushort*)((char*)Qb + (size_t)N * 4194304);
  ushort* Kb = (ushort*)((char*)CT + (size_t)N * 4194304);
  ushort* Vb = (ushort*)((char*)Kb + (size_t)N * 4194304);
  float*  Sf = (float*)((char*)Vb + (size_t)N * 4194304);       // N*8388608 B (scratch)
  ushort* Pb = (ushort*)((char*)Sf + (size_t)N * 8388608);      // N*4194304 B (scratch)
  ushort* MID = XT;                    // overlays XT+XN+Qb
  ushort* F2C = Kb;                    // overlays Kb+Vb+Sf
  ushort* W8  = (N == 1) ? (ushort*)Sf : Pb;   // bf16 weight scratch
  ushort* f1w = Kb;                    // 33.5MB span (N>=2 only)
  ushort* f2w = XT;                    // 33.5MB span (N>=2 only)

  const long long W1 = 1048576;
  const long long W4 = 4194304;
  const long long P4 = 4LL * PLF;
  const long long M1 = 2097152;
  const int GCc1 = N * 256;
  const int GCc4 = N * 1024;

  for (int b0 = 0; b0 < 4; b0 += N) {
    // --- input transpose + x copy to out ---
    tin_kernel<<<dim3(32, 16, 8 * N), 256, 0, stream>>>(x, XT, out, b0 * 8);
    // --- embed ---
    conv4c_kernel<8><<<GCc1, 256, 0, stream>>>(XT, embed_cw, embed_cb, CT, 10);
    cvt_kernel<<<2048, 256, 0, stream>>>((const float4*)embed_pw, (short8*)W8);
    mm_kernel<0, 0, 0, 0, 0, 64><<<dim3(16, 4, nP), 256, 0, stream>>>(
        CT, W8, Hf, 1024, 1024, 1024, 1024,
        N, PLF, P4, N, W1, 0, N, PLF, P4, 1.f);
    // --- LN1 ---
    ln_kernel<<<nP * 128, 256, 0, stream>>>(Hf, n1g, n1b, XN);
    // --- q/k/v projections ---
    conv4c_kernel<4><<<GCc1, 256, 0, stream>>>(XN, q_cw, q_cb, CT, 10);
    cvt_kernel<<<2048, 256, 0, stream>>>((const float4*)q_pw, (short8*)W8);
    mm_kernel<1, 0, 0, 0, 0, 64><<<dim3(16, 4, nP), 256, 0, stream>>>(
        CT, W8, Qb, 1024, 1024, 1024, 1024,
        N, PLF, P4, N, W1, 0, N, PLF, P4, 1.f);
    conv4c_kernel<4><<<GCc1, 256, 0, stream>>>(XN, k_cw, k_cb, CT, 10);
    cvt_kernel<<<2048, 256, 0, stream>>>((const float4*)k_pw, (short8*)W8);
    mm_kernel<1, 0, 0, 0, 0, 64><<<dim3(16, 4, nP), 256, 0, stream>>>(
        CT, W8, Kb, 1024, 1024, 1024, 1024,
        N, PLF, P4, N, W1, 0, N, PLF, P4, 1.f);
    conv4c_kernel<4><<<GCc1, 256, 0, stream>>>(XN, v_cw, v_cb, CT, 10);
    cvt_kernel<<<2048, 256, 0, stream>>>((const float4*)v_pw, (short8*)W8);
    mm_kernel<1, 0, 0, 0, 0, 64><<<dim3(8, 8, nP), 256, 0, stream>>>(
        W8, CT, Vb, 1024, 1024, 1024, 512,
        N, W1, 0, N, PLF, P4, N, PLF, P4, 1.f);        // V stored [f][w]
    // --- RoPE ---
    rope_kernel<<<nP * 1024, 256, 0, stream>>>((uint*)Qb);
    rope_kernel<<<nP * 1024, 256, 0, stream>>>((uint*)Kb);
    // --- fused flash attention (O overwrites Q) ---
    fattn_kernel<<<dim3(8, nP * 8), 256, 0, stream>>>(Qb, Kb, Vb, Qb);
    // --- o projection (accumulate into H) ---
    conv4c_kernel<4><<<GCc1, 256, 0, stream>>>(Qb, o_cw, o_cb, CT, 10);
    cvt_kernel<<<2048, 256, 0, stream>>>((const float4*)o_pw, (short8*)W8);
    mm_kernel<0, 1, 0, 0, 0, 64><<<dim3(16, 4, nP), 256, 0, stream>>>(
        CT, W8, Hf, 1024, 1024, 1024, 1024,
        N, PLF, P4, N, W1, 0, N, PLF, P4, 1.f);
    // --- LN2 ---
    ln_kernel<<<nP * 128, 256, 0, stream>>>(Hf, n2g, n2b, XN);
    // --- ffn1 (+fused squared relu) ---
    conv4c_kernel<4><<<GCc1, 256, 0, stream>>>(XN, f1_cw, f1_cb, CT, 10);
    if (N >= 2) {
      cvt_kernel<<<8192, 256, 0, stream>>>((const float4*)f1_pw, (short8*)f1w);
      mm_kernel<1, 0, 1, 1, 0, 128><<<dim3(32, 4, nP), 256, 0, stream>>>(
          CT, f1w, MID, 1024, 1024, 1024, 4096,
          N, PLF, P4, N, W4, 0, N, M1, 4 * M1, 1.f);
    } else {
      mm_kernel<1, 0, 1, 1, 1, 128><<<dim3(32, 4, nP), 256, 0, stream>>>(
          CT, f1_pw, MID, 1024, 1024, 1024, 4096,
          N, PLF, P4, N, W4, 0, N, M1, 4 * M1, 1.f);
    }
    // --- ffn2 conv (F=4096) then pw accumulate into H ---
    conv4c_kernel<4><<<GCc4, 256, 0, stream>>>(MID, f2_cw, f2_cb, F2C, 12);
    if (N >= 2) {
      cvt_kernel<<<8192, 256, 0, stream>>>((const float4*)f2_pw, (short8*)f2w);
      mm_kernel<0, 1, 0, 0, 0, 64><<<dim3(16, 4, nP), 256, 0, stream>>>(
          F2C, f2w, Hf, 4096, 4096, 4096, 1024,
          N, M1, 4 * M1, N, W4, 0, N, PLF, P4, 1.f);
    } else {
      mm_kernel<0, 1, 0, 0, 1, 128><<<dim3(8, 4, nP), 256, 0, stream>>>(
          F2C, f2_pw, Hf, 4096, 4096, 4096, 1024,
          N, M1, 4 * M1, N, W4, 0, N, PLF, P4, 1.f);
    }
    // --- output transpose ---
    tout_kernel<<<dim3(16, 32, nP), 256, 0, stream>>>(Hf, out, b0);
  }
}

// Round 8
// 674.107 us; speedup vs baseline: 13.4381x; 1.0853x over previous
//
#include <hip/hip_runtime.h>

typedef __attribute__((ext_vector_type(8))) short short8;
typedef __attribute__((ext_vector_type(4))) float f32x4;
typedef unsigned int uint;
typedef unsigned short ushort;

#define PLF 524288   // 1024*512 elements per activation plane

__device__ __forceinline__ ushort f2bf(float f) {
  uint u = __float_as_uint(f);
  u += 0x7FFF + ((u >> 16) & 1);   // RNE
  return (ushort)(u >> 16);
}
__device__ __forceinline__ float bf2f(ushort h) {
  return __uint_as_float(((uint)h) << 16);
}
__device__ __forceinline__ int swzf(int r) { return ((r & 3) ^ ((r >> 2) & 3)); }

#define GLOAD16(gp, lp)                                          \
  __builtin_amdgcn_global_load_lds(                              \
      (const __attribute__((address_space(1))) void*)(gp),       \
      (__attribute__((address_space(3))) void*)(lp), 16, 0, 0)

// ---------------------------------------------------------------------------
// MFMA GEMM: C[m][n] = alpha * sum_k A[m][k] * B[n][k]  (both row-major-K)
// Per-z offsets: off = (z/Div)*S1 + (z%Mod)*S2 (element units).
// ROPE: apply rotary embedding in epilogue (row = position, col = feature).
// ---------------------------------------------------------------------------
template <int CDT, int BETA, int RELU2, int MFAST, int BCVT, int ROPE>
__global__ __launch_bounds__(256) void mm_kernel(
    const void* __restrict__ Av, const void* __restrict__ Bv, void* __restrict__ Cv,
    int K, int lda, int ldb, int ldc,
    int aDiv, int aMod, long long aS1, long long aS2,
    int bDiv, int bMod, long long bS1, long long bS2,
    int cDiv, int cMod, long long cS1, long long cS2, float alpha)
{
  __shared__ char lds[32768];   // 2 bufs x (A 8KB | B 8KB)
  const int nx = gridDim.x, ny = gridDim.y;
  const int nwg = nx * ny * (int)gridDim.z;
  const int o = ((int)blockIdx.z * ny + blockIdx.y) * nx + blockIdx.x;
  const int qd = nwg >> 3, rm = nwg & 7, xcd = o & 7, rot = o >> 3;
  const int wflat = (xcd < rm ? xcd * (qd + 1) : rm * (qd + 1) + (xcd - rm) * qd) + rot;
  int bx, by, bz;
  if (MFAST) { by = wflat % ny; int t2 = wflat / ny; bx = t2 % nx; bz = t2 / nx; }
  else       { bx = wflat % nx; int t2 = wflat / nx; by = t2 % ny; bz = t2 / ny; }
  const int tid = threadIdx.x;
  const long long aOff = (long long)(bz / aDiv) * aS1 + (long long)(bz % aMod) * aS2;
  const long long bOff = (long long)(bz / bDiv) * bS1 + (long long)(bz % bMod) * bS2;
  const long long cOff = (long long)(bz / cDiv) * cS1 + (long long)(bz % cMod) * cS2;
  const int m0 = by * 128, n0 = bx * 128;
  const int lane = tid & 63, wid = tid >> 6;
  const int MOFF = (wid >> 1) * 64, NOFF = (wid & 1) * 64;
  const int u = lane & 15, g = lane >> 4;
  const int sr0 = tid >> 2, sslot = tid & 3;
  const ushort* Ap = (const ushort*)Av + aOff;
  const ushort* Bp = (const ushort*)Bv + bOff;
  const float*  Bf = (const float*)Bv + bOff;

#define STAGE(buf, kt)                                                         \
  {                                                                            \
    _Pragma("unroll")                                                          \
    for (int half = 0; half < 2; ++half) {                                     \
      const int r = sr0 + 64 * half;                                           \
      const int ss = sslot ^ swzf(r);                                          \
      GLOAD16(Ap + (long long)(m0 + r) * lda + (kt) + ss * 8,                  \
              &lds[(buf) * 16384] + wid * 1024 + half * 4096);                 \
      if (BCVT == 0) {                                                         \
        GLOAD16(Bp + (long long)(n0 + r) * ldb + (kt) + ss * 8,                \
                &lds[(buf) * 16384 + 8192] + wid * 1024 + half * 4096);        \
      } else {                                                                 \
        const float* srcB = Bf + (long long)(n0 + r) * ldb + (kt) + ss * 8;    \
        float4 x0 = *(const float4*)srcB;                                      \
        float4 x1 = *(const float4*)(srcB + 4);                                \
        short8 h;                                                              \
        h[0] = (short)f2bf(x0.x); h[1] = (short)f2bf(x0.y);                    \
        h[2] = (short)f2bf(x0.z); h[3] = (short)f2bf(x0.w);                    \
        h[4] = (short)f2bf(x1.x); h[5] = (short)f2bf(x1.y);                    \
        h[6] = (short)f2bf(x1.z); h[7] = (short)f2bf(x1.w);                    \
        *(short8*)(&lds[(buf) * 16384 + 8192] + r * 64 + sslot * 16) = h;      \
      }                                                                        \
    }                                                                          \
  }

  f32x4 acc[4][4];
#pragma unroll
  for (int i = 0; i < 4; ++i)
#pragma unroll
    for (int j = 0; j < 4; ++j) acc[i][j] = (f32x4){0.f, 0.f, 0.f, 0.f};

  STAGE(0, 0);
  asm volatile("s_waitcnt vmcnt(0) lgkmcnt(0)" ::: "memory");
  __builtin_amdgcn_s_barrier();
  int cur = 0;
  for (int kt = 0; kt < K; kt += 32) {
    if (kt + 32 < K) STAGE(cur ^ 1, kt + 32);
    short8 af[4], bfr[4];
#pragma unroll
    for (int mi = 0; mi < 4; ++mi) {
      const int r = MOFF + mi * 16 + u;
      af[mi] = *(const short8*)(&lds[cur * 16384] + r * 64 + ((g ^ swzf(r)) * 16));
    }
#pragma unroll
    for (int ni = 0; ni < 4; ++ni) {
      const int r = NOFF + ni * 16 + u;
      bfr[ni] = *(const short8*)(&lds[cur * 16384 + 8192] + r * 64 + ((g ^ swzf(r)) * 16));
    }
#pragma unroll
    for (int mi = 0; mi < 4; ++mi)
#pragma unroll
      for (int ni = 0; ni < 4; ++ni)
        acc[mi][ni] = __builtin_amdgcn_mfma_f32_16x16x32_bf16(af[mi], bfr[ni], acc[mi][ni], 0, 0, 0);
    asm volatile("s_waitcnt vmcnt(0) lgkmcnt(0)" ::: "memory");
    __builtin_amdgcn_s_barrier();
    cur ^= 1;
  }
#undef STAGE

#pragma unroll
  for (int mi = 0; mi < 4; ++mi)
#pragma unroll
    for (int ni = 0; ni < 4; ++ni)
#pragma unroll
      for (int q = 0; q < 4; ++q) {
        const int row = m0 + MOFF + mi * 16 + g * 4 + q;
        const int col = n0 + NOFF + ni * 16 + u;
        float v = acc[mi][ni][q] * alpha;
        if (CDT == 0) {
          float* cp = (float*)Cv + cOff + (long long)row * ldc + col;
          if (BETA) v += *cp;
          *cp = v;
        } else {
          if (ROPE) {
            const int j = (col & 127) >> 1;
            const float infr = __expf((float)j * (-9.210340371976184f / 64.f));
            float sn, cs;
            __sincosf((float)row * infr, &sn, &cs);
            const float part = __shfl_xor(v, 1);
            v = (col & 1) ? fmaf(part, sn, v * cs) : fmaf(-part, sn, v * cs);
          }
          if (RELU2) { v = fmaxf(v, 0.f); v = v * v; }
          ((ushort*)Cv)[cOff + (long long)row * ldc + col] = f2bf(v);
        }
      }
}

// ---------------------------------------------------------------------------
// Fused flash attention (unchanged from round 7, verified).
// ---------------------------------------------------------------------------
__global__ __launch_bounds__(256) void fattn_kernel(
    const ushort* __restrict__ Qg, const ushort* __restrict__ Kg,
    const ushort* __restrict__ Vg, ushort* __restrict__ Og)
{
  __shared__ char lds[73728];
  const int hb = blockIdx.y, pl = hb >> 3, h = hb & 7;
  const int q0 = blockIdx.x * 64;
  const int tid = threadIdx.x, lane = tid & 63, wv = tid >> 6;
  const int u = lane & 15, g = lane >> 4;
  const ushort* Qh = Qg + (size_t)pl * PLF + h * 128;
  const ushort* Kh = Kg + (size_t)pl * PLF + h * 128;
  const ushort* Vh = Vg + (size_t)pl * PLF + (size_t)(h * 128) * 512;
  ushort* Oh = Og + (size_t)pl * PLF + h * 128;

  short8 qf[4];
  const int qrow = q0 + wv * 16 + u;
#pragma unroll
  for (int dc = 0; dc < 4; ++dc)
    qf[dc] = *(const short8*)(Qh + (size_t)qrow * 1024 + dc * 32 + g * 8);

#define STAGE_KV(buf, kt)                                                     \
  {                                                                           \
    _Pragma("unroll")                                                         \
    for (int it = 0; it < 4; ++it) {                                          \
      const int off = tid * 16 + it * 4096;                                   \
      const int krow = off >> 8, kslot = (off >> 4) & 15;                     \
      GLOAD16(Kh + (size_t)((kt) * 64 + krow) * 1024 +                        \
                  ((kslot ^ ((krow & 7) << 1)) * 8),                          \
              &lds[(buf) * 16384] + off);                                     \
      const int vrow = off >> 7, vslot = (off >> 4) & 7;                      \
      GLOAD16(Vh + (size_t)vrow * 512 + (kt) * 64 + ((vslot ^ (vrow & 7)) * 8), \
              &lds[32768 + (buf) * 16384] + off);                             \
    }                                                                         \
  }

  f32x4 oacc[8];
#pragma unroll
  for (int i = 0; i < 8; ++i) oacc[i] = (f32x4){0.f, 0.f, 0.f, 0.f};
  float m_run = -3.0e38f, l_run = 0.f;

  STAGE_KV(0, 0);
  asm volatile("s_waitcnt vmcnt(0)" ::: "memory");
  __syncthreads();
  int cur = 0;
  for (int kt = 0; kt < 8; ++kt) {
    if (kt + 1 < 8) STAGE_KV(cur ^ 1, kt + 1);
    f32x4 sacc[4];
#pragma unroll
    for (int kn = 0; kn < 4; ++kn) sacc[kn] = (f32x4){0.f, 0.f, 0.f, 0.f};
#pragma unroll
    for (int kn = 0; kn < 4; ++kn) {
      const int r = kn * 16 + u;
      const char* kb = &lds[cur * 16384] + r * 256;
#pragma unroll
      for (int dc = 0; dc < 4; ++dc) {
        short8 kf = *(const short8*)(kb + (((dc * 4 + g) ^ ((u & 7) << 1)) * 16));
        sacc[kn] = __builtin_amdgcn_mfma_f32_16x16x32_bf16(kf, qf[dc], sacc[kn], 0, 0, 0);
      }
    }
    float pm = -3.0e38f;
#pragma unroll
    for (int kn = 0; kn < 4; ++kn)
#pragma unroll
      for (int r = 0; r < 4; ++r) {
        sacc[kn][r] *= 0.03125f;
        pm = fmaxf(pm, sacc[kn][r]);
      }
    pm = fmaxf(pm, __shfl_xor(pm, 16));
    pm = fmaxf(pm, __shfl_xor(pm, 32));
    const float m_new = fmaxf(m_run, pm);
    const float es = __expf(m_run - m_new);
    float psum = 0.f;
    uint pw[4][2];
#pragma unroll
    for (int kn = 0; kn < 4; ++kn) {
      float p0 = __expf(sacc[kn][0] - m_new);
      float p1 = __expf(sacc[kn][1] - m_new);
      float p2 = __expf(sacc[kn][2] - m_new);
      float p3 = __expf(sacc[kn][3] - m_new);
      psum += (p0 + p1) + (p2 + p3);
      pw[kn][0] = (uint)f2bf(p0) | ((uint)f2bf(p1) << 16);
      pw[kn][1] = (uint)f2bf(p2) | ((uint)f2bf(p3) << 16);
    }
    psum += __shfl_xor(psum, 16);
    psum += __shfl_xor(psum, 32);
    l_run = l_run * es + psum;
    m_run = m_new;
    char* pb = &lds[65536 + wv * 2048] + u * 128 + (g & 1) * 8;
#pragma unroll
    for (int kn = 0; kn < 4; ++kn)
      *(uint2*)(pb + (((2 * kn + (g >> 1)) ^ (u & 7)) * 16)) =
          make_uint2(pw[kn][0], pw[kn][1]);
    float es_o[4];
#pragma unroll
    for (int r = 0; r < 4; ++r) es_o[r] = __shfl(es, g * 4 + r);
#pragma unroll
    for (int nd = 0; nd < 8; ++nd)
#pragma unroll
      for (int r = 0; r < 4; ++r) oacc[nd][r] *= es_o[r];
    const char* prd = &lds[65536 + wv * 2048] + u * 128;
    short8 pf[2];
#pragma unroll
    for (int kc = 0; kc < 2; ++kc)
      pf[kc] = *(const short8*)(prd + (((kc * 4 + g) ^ (u & 7)) * 16));
#pragma unroll
    for (int nd = 0; nd < 8; ++nd) {
      const int vr = nd * 16 + u;
      const char* vb = &lds[32768 + cur * 16384] + vr * 128;
#pragma unroll
      for (int kc = 0; kc < 2; ++kc) {
        short8 vf = *(const short8*)(vb + (((kc * 4 + g) ^ (u & 7)) * 16));
        oacc[nd] = __builtin_amdgcn_mfma_f32_16x16x32_bf16(pf[kc], vf, oacc[nd], 0, 0, 0);
      }
    }
    asm volatile("s_waitcnt vmcnt(0)" ::: "memory");
    __syncthreads();
    cur ^= 1;
  }
#undef STAGE_KV
  const float inv_l = 1.f / l_run;
  float inv_o[4];
#pragma unroll
  for (int r = 0; r < 4; ++r) inv_o[r] = __shfl(inv_l, g * 4 + r);
#pragma unroll
  for (int nd = 0; nd < 8; ++nd)
#pragma unroll
    for (int r = 0; r < 4; ++r) {
      const int row = q0 + wv * 16 + g * 4 + r;
      Oh[(size_t)row * 1024 + nd * 16 + u] = f2bf(oacc[nd][r] * inv_o[r]);
    }
}

// ---------------- fp32 -> bf16 weight conversion (8 elem/thread) ------------
__global__ __launch_bounds__(256) void cvt_kernel(
    const float4* __restrict__ s, short8* __restrict__ d)
{
  const int i = blockIdx.x * 256 + threadIdx.x;
  const float4 a = s[2 * i], b = s[2 * i + 1];
  short8 h;
  h[0] = (short)f2bf(a.x); h[1] = (short)f2bf(a.y);
  h[2] = (short)f2bf(a.z); h[3] = (short)f2bf(a.w);
  h[4] = (short)f2bf(b.x); h[5] = (short)f2bf(b.y);
  h[6] = (short)f2bf(b.z); h[7] = (short)f2bf(b.w);
  d[i] = h;
}

// ---------------------------------------------------------------------------
// conv 3x3 SAME on [512 w][F f] planes; 8 f-outputs x 4 out-channels/thread.
// ---------------------------------------------------------------------------
template <int CIN>
__global__ __launch_bounds__(256) void conv4c_kernel(
    const ushort* __restrict__ in, const float* __restrict__ wt,
    const float* __restrict__ bias, ushort* __restrict__ outp, int log2F)
{
  const int idx = blockIdx.x * 256 + threadIdx.x;
  const int F8m = (1 << (log2F - 3)) - 1;
  const int f8 = idx & F8m;
  const int w = (idx >> (log2F - 3)) & 511;
  const int bb = idx >> (log2F + 6);
  const int f0 = f8 << 3;
  float acc[4][8];
#pragma unroll
  for (int co = 0; co < 4; ++co) {
    const float bv = bias[co];
#pragma unroll
    for (int j = 0; j < 8; ++j) acc[co][j] = bv;
  }
  const bool lok = f8 > 0, rok = f8 < F8m;
#pragma unroll
  for (int ci = 0; ci < CIN; ++ci) {
    const ushort* base = in + (((size_t)(bb * CIN + ci)) << (log2F + 9));
#pragma unroll
    for (int dxw = 0; dxw < 3; ++dxw) {
      const int w2 = w + dxw - 1;
      if (w2 < 0 || w2 > 511) continue;
      const ushort* rp = base + ((size_t)w2 << log2F) + f0;
      const short8 cen = *(const short8*)rp;
      float xv[10];
      xv[0] = lok ? bf2f(rp[-1]) : 0.f;
#pragma unroll
      for (int j = 0; j < 8; ++j) xv[j + 1] = bf2f((ushort)cen[j]);
      xv[9] = rok ? bf2f(rp[8]) : 0.f;
#pragma unroll
      for (int co = 0; co < 4; ++co) {
        const float* wp = wt + (co * CIN + ci) * 9;
        const float k0 = wp[dxw], k1 = wp[3 + dxw], k2 = wp[6 + dxw];
#pragma unroll
        for (int j = 0; j < 8; ++j)
          acc[co][j] += k0 * xv[j] + k1 * xv[j + 1] + k2 * xv[j + 2];
      }
    }
  }
#pragma unroll
  for (int co = 0; co < 4; ++co) {
    short8 o;
#pragma unroll
    for (int j = 0; j < 8; ++j) o[j] = (short)f2bf(acc[co][j]);
    *(short8*)(outp + (((size_t)(bb * 4 + co)) << (log2F + 9)) + ((size_t)w << log2F) + f0) = o;
  }
}

// ---------------------------------------------------------------------------
// q/k/v merged conv: reads XN once, computes 12 output channels (3 proj x 4c).
// Output chunks [q][k][v], chunk stride nPl*PLF. F=1024 fixed.
// ---------------------------------------------------------------------------
__global__ __launch_bounds__(256) void conv12c_kernel(
    const ushort* __restrict__ in,
    const float* __restrict__ wq, const float* __restrict__ wk, const float* __restrict__ wv,
    const float* __restrict__ bq, const float* __restrict__ bk, const float* __restrict__ bv,
    ushort* __restrict__ outp, int nPl)
{
  const int idx = blockIdx.x * 256 + threadIdx.x;
  const int f8 = idx & 127;
  const int w = (idx >> 7) & 511;
  const int bb = idx >> 16;
  const int f0 = f8 << 3;
  const float* wsel[3] = {wq, wk, wv};
  float acc[12][8];
#pragma unroll
  for (int co = 0; co < 4; ++co) {
    const float b0 = bq[co], b1 = bk[co], b2 = bv[co];
#pragma unroll
    for (int j = 0; j < 8; ++j) {
      acc[co][j] = b0; acc[4 + co][j] = b1; acc[8 + co][j] = b2;
    }
  }
  const bool lok = f8 > 0, rok = f8 < 127;
#pragma unroll
  for (int ci = 0; ci < 4; ++ci) {
    const ushort* base = in + (((size_t)(bb * 4 + ci)) << 19);
#pragma unroll
    for (int dxw = 0; dxw < 3; ++dxw) {
      const int w2 = w + dxw - 1;
      if (w2 < 0 || w2 > 511) continue;
      const ushort* rp = base + ((size_t)w2 << 10) + f0;
      const short8 cen = *(const short8*)rp;
      float xv[10];
      xv[0] = lok ? bf2f(rp[-1]) : 0.f;
#pragma unroll
      for (int j = 0; j < 8; ++j) xv[j + 1] = bf2f((ushort)cen[j]);
      xv[9] = rok ? bf2f(rp[8]) : 0.f;
#pragma unroll
      for (int pj = 0; pj < 3; ++pj)
#pragma unroll
        for (int co = 0; co < 4; ++co) {
          const float* wp = wsel[pj] + (co * 4 + ci) * 9;
          const float k0 = wp[dxw], k1 = wp[3 + dxw], k2 = wp[6 + dxw];
#pragma unroll
          for (int j = 0; j < 8; ++j)
            acc[pj * 4 + co][j] += k0 * xv[j] + k1 * xv[j + 1] + k2 * xv[j + 2];
        }
    }
  }
#pragma unroll
  for (int pj = 0; pj < 3; ++pj)
#pragma unroll
    for (int co = 0; co < 4; ++co) {
      short8 o;
#pragma unroll
      for (int j = 0; j < 8; ++j) o[j] = (short)f2bf(acc[pj * 4 + co][j]);
      *(short8*)(outp + (((size_t)(pj * nPl + bb * 4 + co)) << 19) +
                 ((size_t)w << 10) + f0) = o;
    }
}

// ---------------- layernorm over f (rows of 1024), H fp32 -> XN bf16 --------
__global__ __launch_bounds__(256) void ln_kernel(
    const float* __restrict__ H, const float* __restrict__ gam,
    const float* __restrict__ bet, ushort* __restrict__ XN)
{
  const int wid = threadIdx.x >> 6, lane = threadIdx.x & 63;
  const int row = blockIdx.x * 4 + wid;
  const int c = (row >> 9) & 3;
  const float* xp = H + (size_t)row * 1024;
  float4 v[4];
  float s = 0.f, q = 0.f;
#pragma unroll
  for (int p = 0; p < 4; ++p) {
    v[p] = *(const float4*)(xp + p * 256 + lane * 4);
    s += v[p].x + v[p].y + v[p].z + v[p].w;
    q += v[p].x * v[p].x + v[p].y * v[p].y + v[p].z * v[p].z + v[p].w * v[p].w;
  }
#pragma unroll
  for (int o = 32; o > 0; o >>= 1) { s += __shfl_xor(s, o); q += __shfl_xor(q, o); }
  const float mu = s * (1.f / 1024.f);
  const float var = q * (1.f / 1024.f) - mu * mu;
  const float rs = rsqrtf(var + 1e-5f);
  ushort* op = XN + (size_t)row * 1024;
  const float* gp = gam + c * 1024;
  const float* bp = bet + c * 1024;
#pragma unroll
  for (int p = 0; p < 4; ++p) {
    const int f = p * 256 + lane * 4;
    float4 g4 = *(const float4*)(gp + f);
    float4 b4 = *(const float4*)(bp + f);
    ushort4 o4;
    o4.x = f2bf((v[p].x - mu) * rs * g4.x + b4.x);
    o4.y = f2bf((v[p].y - mu) * rs * g4.y + b4.y);
    o4.z = f2bf((v[p].z - mu) * rs * g4.z + b4.z);
    o4.w = f2bf((v[p].w - mu) * rs * g4.w + b4.w);
    *(ushort4*)(op + f) = o4;
  }
}

// ---- transpose-in: x fp32 [f][w] -> XT bf16 [w][f]; also copy x -> out -----
__global__ __launch_bounds__(256) void tin_kernel(
    const float* __restrict__ x, ushort* __restrict__ XT,
    float* __restrict__ outp, int planeOff)
{
  __shared__ float t[32][33];
  const int f0 = blockIdx.x * 32, w0 = blockIdx.y * 32;
  const int z = blockIdx.z;
  const int tx = threadIdx.x & 31, ty = threadIdx.x >> 5;
  const int gpl = planeOff + z;
  const int b = gpl >> 3, ch = gpl & 7;
  const float* src = x + (size_t)gpl * PLF;
  float* dst0 = outp + (size_t)(b * 12 + ch) * PLF;
#pragma unroll
  for (int r = 0; r < 32; r += 8) {
    const size_t off = (size_t)(f0 + r + ty) * 512 + w0 + tx;
    const float v = src[off];
    t[r + ty][tx] = v;
    dst0[off] = v;
  }
  __syncthreads();
  ushort* dst = XT + (size_t)z * PLF;
#pragma unroll
  for (int r = 0; r < 32; r += 8) dst[(size_t)(w0 + r + ty) * 1024 + f0 + tx] = f2bf(t[tx][r + ty]);
}

// ---------------- transpose-out: H fp32 [w][f] -> out[b][8+c][f][w] ---------
__global__ __launch_bounds__(256) void tout_kernel(
    const float* __restrict__ H, float* __restrict__ out, int b0)
{
  __shared__ float t[32][33];
  const int w0 = blockIdx.x * 32, f0 = blockIdx.y * 32;
  const int p = blockIdx.z;
  const int b = b0 + (p >> 2), c = p & 3;
  const int tx = threadIdx.x & 31, ty = threadIdx.x >> 5;
  const float* src = H + (size_t)p * PLF;
#pragma unroll
  for (int r = 0; r < 32; r += 8) t[r + ty][tx] = src[(size_t)(w0 + r + ty) * 1024 + f0 + tx];
  __syncthreads();
  float* dst = out + (size_t)(b * 12 + 8 + c) * PLF;
#pragma unroll
  for (int r = 0; r < 32; r += 8) dst[(size_t)(f0 + r + ty) * 512 + w0 + tx] = t[tx][r + ty];
}

// ---------------------------------------------------------------------------
extern "C" void kernel_launch(void* const* d_in, const int* in_sizes, int n_in,
                              void* d_out, int out_size, void* d_ws, size_t ws_size,
                              hipStream_t stream)
{
  const float* x        = (const float*)d_in[0];
  const float* embed_cw = (const float*)d_in[1];
  const float* embed_cb = (const float*)d_in[2];
  const float* embed_pw = (const float*)d_in[3];
  const float* n1g      = (const float*)d_in[4];
  const float* n1b      = (const float*)d_in[5];
  const float* q_cw     = (const float*)d_in[6];
  const float* q_cb     = (const float*)d_in[7];
  const float* q_pw     = (const float*)d_in[8];
  const float* k_cw     = (const float*)d_in[9];
  const float* k_cb     = (const float*)d_in[10];
  const float* k_pw     = (const float*)d_in[11];
  const float* v_cw     = (const float*)d_in[12];
  const float* v_cb     = (const float*)d_in[13];
  const float* v_pw     = (const float*)d_in[14];
  const float* o_cw     = (const float*)d_in[15];
  const float* o_cb     = (const float*)d_in[16];
  const float* o_pw     = (const float*)d_in[17];
  const float* n2g      = (const float*)d_in[18];
  const float* n2b      = (const float*)d_in[19];
  const float* f1_cw    = (const float*)d_in[20];
  const float* f1_cb    = (const float*)d_in[21];
  const float* f1_pw    = (const float*)d_in[22];
  const float* f2_cw    = (const float*)d_in[23];
  const float* f2_cb    = (const float*)d_in[24];
  const float* f2_pw    = (const float*)d_in[25];
  float* out = (float*)d_out;

  const size_t perB = 50331648ull;
  const int N = (ws_size >= 4 * perB) ? 4 : (ws_size >= 2 * perB) ? 2 : 1;
  const int nP = 4 * N;

  // layout: Hf | XT | XN | Qb | Kb | CT | Vb | SfPb
  char* base = (char*)d_ws;
  float*  Hf = (float*)base;                                    // N*8388608 B
  ushort* XT = (ushort*)(base + (size_t)N * 8388608);           // N*8388608 B
  ushort* XN = (ushort*)((char*)XT + (size_t)N * 8388608);      // N*4194304 B
  ushort* Qb = (ushort*)((char*)XN + (size_t)N * 4194304);
  ushort* Kb = (ushort*)((char*)Qb + (size_t)N * 4194304);      // adjacent to Qb!
  ushort* CT = (ushort*)((char*)Kb + (size_t)N * 4194304);
  ushort* Vb = (ushort*)((char*)CT + (size_t)N * 4194304);
  ushort* SfPb = (ushort*)((char*)Vb + (size_t)N * 4194304);    // N*12582912 B
  ushort* CT3 = SfPb;                  // q/k/v conv outputs, 3*nP planes
  ushort* W8  = SfPb;                  // 8.4MB bf16 weight slot (embed/o/v)
  ushort* WQK = XT;                    // 16.8MB qk weights (N>=2)
  ushort* MID = XT;                    // ffn1 out (XT..Qb span)
  ushort* f1w = Vb;                    // ffn1 weight (Vb..SfPb span, N>=2)
  ushort* F2C = Vb;                    // ffn2 conv out (Vb..SfPb span)
  ushort* f2w = XT;                    // ffn2 weight (XT..Qb span, N>=2)

  const long long W1 = 1048576;
  const long long W4 = 4194304;
  const long long M1 = 2097152;
  const long long CH3 = (long long)nP * PLF;   // CT3 chunk stride
  const int GCc1 = N * 256;
  const int GCc4 = N * 1024;

  for (int b0 = 0; b0 < 4; b0 += N) {
    // --- input transpose + x copy to out ---
    tin_kernel<<<dim3(32, 16, 8 * N), 256, 0, stream>>>(x, XT, out, b0 * 8);
    // --- embed ---
    conv4c_kernel<8><<<GCc1, 256, 0, stream>>>(XT, embed_cw, embed_cb, CT, 10);
    cvt_kernel<<<2048, 256, 0, stream>>>((const float4*)embed_pw, (short8*)W8);
    mm_kernel<0, 0, 0, 0, 0, 0><<<dim3(8, 4, nP), 256, 0, stream>>>(
        CT, W8, Hf, 1024, 1024, 1024, 1024,
        1, 1, PLF, 0, 4, 4, 0, W1, 1, 1, PLF, 0, 1.f);
    // --- LN1 ---
    ln_kernel<<<nP * 128, 256, 0, stream>>>(Hf, n1g, n1b, XN);
    // --- merged q/k/v conv ---
    conv12c_kernel<<<GCc1, 256, 0, stream>>>(XN, q_cw, k_cw, v_cw,
                                             q_cb, k_cb, v_cb, CT3, nP);
    // --- q+k projection (RoPE fused into epilogue) ---
    if (N >= 2) {
      cvt_kernel<<<2048, 256, 0, stream>>>((const float4*)q_pw, (short8*)WQK);
      cvt_kernel<<<2048, 256, 0, stream>>>((const float4*)k_pw, (short8*)(WQK) + 524288);
      mm_kernel<1, 0, 0, 0, 0, 1><<<dim3(8, 4, 2 * nP), 256, 0, stream>>>(
          CT3, WQK, Qb, 1024, 1024, 1024, 1024,
          1, 1, PLF, 0, nP, 4, 4 * W1, W1, 1, 1, PLF, 0, 1.f);
    } else {
      mm_kernel<1, 0, 0, 0, 1, 1><<<dim3(8, 4, nP), 256, 0, stream>>>(
          CT3, q_pw, Qb, 1024, 1024, 1024, 1024,
          1, 1, PLF, 0, 4, 4, 0, W1, 1, 1, PLF, 0, 1.f);
      mm_kernel<1, 0, 0, 0, 1, 1><<<dim3(8, 4, nP), 256, 0, stream>>>(
          CT3 + CH3, k_pw, Kb, 1024, 1024, 1024, 1024,
          1, 1, PLF, 0, 4, 4, 0, W1, 1, 1, PLF, 0, 1.f);
    }
    // --- v projection (V stored [f][w]); W8 clobbers CT3 chunk0 (dead) ---
    cvt_kernel<<<2048, 256, 0, stream>>>((const float4*)v_pw, (short8*)W8);
    mm_kernel<1, 0, 0, 0, 0, 0><<<dim3(4, 8, nP), 256, 0, stream>>>(
        W8, CT3 + 2 * CH3, Vb, 1024, 1024, 1024, 512,
        4, 4, 0, W1, 1, 1, PLF, 0, 1, 1, PLF, 0, 1.f);
    // --- fused flash attention (O overwrites Q) ---
    fattn_kernel<<<dim3(8, nP * 8), 256, 0, stream>>>(Qb, Kb, Vb, Qb);
    // --- o projection (accumulate into H) ---
    conv4c_kernel<4><<<GCc1, 256, 0, stream>>>(Qb, o_cw, o_cb, CT, 10);
    cvt_kernel<<<2048, 256, 0, stream>>>((const float4*)o_pw, (short8*)W8);
    mm_kernel<0, 1, 0, 0, 0, 0><<<dim3(8, 4, nP), 256, 0, stream>>>(
        CT, W8, Hf, 1024, 1024, 1024, 1024,
        1, 1, PLF, 0, 4, 4, 0, W1, 1, 1, PLF, 0, 1.f);
    // --- LN2 ---
    ln_kernel<<<nP * 128, 256, 0, stream>>>(Hf, n2g, n2b, XN);
    // --- ffn1 (+fused squared relu) ---
    conv4c_kernel<4><<<GCc1, 256, 0, stream>>>(XN, f1_cw, f1_cb, CT, 10);
    if (N >= 2) {
      cvt_kernel<<<8192, 256, 0, stream>>>((const float4*)f1_pw, (short8*)f1w);
      mm_kernel<1, 0, 1, 1, 0, 0><<<dim3(32, 4, nP), 256, 0, stream>>>(
          CT, f1w, MID, 1024, 1024, 1024, 4096,
          1, 1, PLF, 0, 4, 4, 0, W4, 1, 1, M1, 0, 1.f);
    } else {
      mm_kernel<1, 0, 1, 1, 1, 0><<<dim3(32, 4, nP), 256, 0, stream>>>(
          CT, f1_pw, MID, 1024, 1024, 1024, 4096,
          1, 1, PLF, 0, 4, 4, 0, W4, 1, 1, M1, 0, 1.f);
    }
    // --- ffn2 conv (F=4096) then pw accumulate into H ---
    conv4c_kernel<4><<<GCc4, 256, 0, stream>>>(MID, f2_cw, f2_cb, F2C, 12);
    if (N >= 2) {
      cvt_kernel<<<8192, 256, 0, stream>>>((const float4*)f2_pw, (short8*)f2w);
      mm_kernel<0, 1, 0, 0, 0, 0><<<dim3(8, 4, nP), 256, 0, stream>>>(
          F2C, f2w, Hf, 4096, 4096, 4096, 1024,
          1, 1, M1, 0, 4, 4, 0, W4, 1, 1, PLF, 0, 1.f);
    } else {
      mm_kernel<0, 1, 0, 0, 1, 0><<<dim3(8, 4, nP), 256, 0, stream>>>(
          F2C, f2_pw, Hf, 4096, 4096, 4096, 1024,
          1, 1, M1, 0, 4, 4, 0, W4, 1, 1, PLF, 0, 1.f);
    }
    // --- output transpose ---
    tout_kernel<<<dim3(16, 32, nP), 256, 0, stream>>>(Hf, out, b0);
  }
}

// Round 9
// 651.115 us; speedup vs baseline: 13.9127x; 1.0353x over previous
//
#include <hip/hip_runtime.h>

typedef __attribute__((ext_vector_type(8))) short short8;
typedef __attribute__((ext_vector_type(4))) float f32x4;
typedef unsigned int uint;
typedef unsigned short ushort;

#define PLF 524288   // 1024*512 elements per activation plane

__device__ __forceinline__ ushort f2bf(float f) {
  uint u = __float_as_uint(f);
  u += 0x7FFF + ((u >> 16) & 1);   // RNE
  return (ushort)(u >> 16);
}
__device__ __forceinline__ float bf2f(ushort h) {
  return __uint_as_float(((uint)h) << 16);
}
__device__ __forceinline__ int swzf(int r) { return ((r & 3) ^ ((r >> 2) & 3)); }

#define GLOAD16(gp, lp)                                          \
  __builtin_amdgcn_global_load_lds(                              \
      (const __attribute__((address_space(1))) void*)(gp),       \
      (__attribute__((address_space(3))) void*)(lp), 16, 0, 0)

// ---------------------------------------------------------------------------
// MFMA GEMM: C[m][n] = alpha * sum_k A[m][k] * B[n][k]  (both row-major-K)
// 3-buffer LDS pipeline with counted vmcnt (BCVT=0): stage t+2 while computing
// t; wait only tile-t's 4 loads per thread (vmcnt(4)); never drain mid-loop.
// Per-z offsets: off = (z/Div)*S1 + (z%Mod)*S2 (element units).
// ROPE: apply rotary embedding in epilogue (row = position, col = feature).
// ---------------------------------------------------------------------------
template <int CDT, int BETA, int RELU2, int MFAST, int BCVT, int ROPE>
__global__ __launch_bounds__(256) void mm_kernel(
    const void* __restrict__ Av, const void* __restrict__ Bv, void* __restrict__ Cv,
    int K, int lda, int ldb, int ldc,
    int aDiv, int aMod, long long aS1, long long aS2,
    int bDiv, int bMod, long long bS1, long long bS2,
    int cDiv, int cMod, long long cS1, long long cS2, float alpha)
{
  __shared__ char lds[49152];   // 3 bufs x (A 8KB | B 8KB)
  const int nx = gridDim.x, ny = gridDim.y;
  const int nwg = nx * ny * (int)gridDim.z;
  const int o = ((int)blockIdx.z * ny + blockIdx.y) * nx + blockIdx.x;
  const int qd = nwg >> 3, rm = nwg & 7, xcd = o & 7, rot = o >> 3;
  const int wflat = (xcd < rm ? xcd * (qd + 1) : rm * (qd + 1) + (xcd - rm) * qd) + rot;
  int bx, by, bz;
  if (MFAST) { by = wflat % ny; int t2 = wflat / ny; bx = t2 % nx; bz = t2 / nx; }
  else       { bx = wflat % nx; int t2 = wflat / nx; by = t2 % ny; bz = t2 / ny; }
  const int tid = threadIdx.x;
  const long long aOff = (long long)(bz / aDiv) * aS1 + (long long)(bz % aMod) * aS2;
  const long long bOff = (long long)(bz / bDiv) * bS1 + (long long)(bz % bMod) * bS2;
  const long long cOff = (long long)(bz / cDiv) * cS1 + (long long)(bz % cMod) * cS2;
  const int m0 = by * 128, n0 = bx * 128;
  const int lane = tid & 63, wid = tid >> 6;
  const int MOFF = (wid >> 1) * 64, NOFF = (wid & 1) * 64;
  const int u = lane & 15, g = lane >> 4;
  const int sr0 = tid >> 2, sslot = tid & 3;
  const ushort* Ap = (const ushort*)Av + aOff;
  const ushort* Bp = (const ushort*)Bv + bOff;
  const float*  Bf = (const float*)Bv + bOff;

#define STAGE(buf, kt)                                                         \
  {                                                                            \
    _Pragma("unroll")                                                          \
    for (int half = 0; half < 2; ++half) {                                     \
      const int r = sr0 + 64 * half;                                           \
      const int ss = sslot ^ swzf(r);                                          \
      GLOAD16(Ap + (long long)(m0 + r) * lda + (kt) + ss * 8,                  \
              &lds[(buf) * 16384] + wid * 1024 + half * 4096);                 \
      if (BCVT == 0) {                                                         \
        GLOAD16(Bp + (long long)(n0 + r) * ldb + (kt) + ss * 8,                \
                &lds[(buf) * 16384 + 8192] + wid * 1024 + half * 4096);        \
      } else {                                                                 \
        const float* srcB = Bf + (long long)(n0 + r) * ldb + (kt) + ss * 8;    \
        float4 x0 = *(const float4*)srcB;                                      \
        float4 x1 = *(const float4*)(srcB + 4);                                \
        short8 h;                                                              \
        h[0] = (short)f2bf(x0.x); h[1] = (short)f2bf(x0.y);                    \
        h[2] = (short)f2bf(x0.z); h[3] = (short)f2bf(x0.w);                    \
        h[4] = (short)f2bf(x1.x); h[5] = (short)f2bf(x1.y);                    \
        h[6] = (short)f2bf(x1.z); h[7] = (short)f2bf(x1.w);                    \
        *(short8*)(&lds[(buf) * 16384 + 8192] + r * 64 + sslot * 16) = h;      \
      }                                                                        \
    }                                                                          \
  }

  f32x4 acc[4][4];
#pragma unroll
  for (int i = 0; i < 4; ++i)
#pragma unroll
    for (int j = 0; j < 4; ++j) acc[i][j] = (f32x4){0.f, 0.f, 0.f, 0.f};

  const int T = K >> 5;
  STAGE(0, 0);
  if (T > 1) STAGE(1, 32);
  int rb = 0, sb = 2;
  for (int t = 0; t < T; ++t) {
    if (BCVT == 0) {
      if (t + 1 < T) { asm volatile("s_waitcnt vmcnt(4)" ::: "memory"); }
      else           { asm volatile("s_waitcnt vmcnt(0)" ::: "memory"); }
    } else {
      asm volatile("s_waitcnt vmcnt(0) lgkmcnt(0)" ::: "memory");
    }
    __builtin_amdgcn_s_barrier();
    __builtin_amdgcn_sched_barrier(0);
    asm volatile("" ::: "memory");
    if (t + 2 < T) STAGE(sb, (t + 2) * 32);
    const char* Abuf = &lds[rb * 16384];
    const char* Bbuf = &lds[rb * 16384 + 8192];
    short8 af[4], bfr[4];
#pragma unroll
    for (int mi = 0; mi < 4; ++mi) {
      const int r = MOFF + mi * 16 + u;
      af[mi] = *(const short8*)(Abuf + r * 64 + ((g ^ swzf(r)) * 16));
    }
#pragma unroll
    for (int ni = 0; ni < 4; ++ni) {
      const int r = NOFF + ni * 16 + u;
      bfr[ni] = *(const short8*)(Bbuf + r * 64 + ((g ^ swzf(r)) * 16));
    }
#pragma unroll
    for (int mi = 0; mi < 4; ++mi)
#pragma unroll
      for (int ni = 0; ni < 4; ++ni)
        acc[mi][ni] = __builtin_amdgcn_mfma_f32_16x16x32_bf16(af[mi], bfr[ni], acc[mi][ni], 0, 0, 0);
    rb = (rb == 2) ? 0 : rb + 1;
    sb = (sb == 2) ? 0 : sb + 1;
  }
#undef STAGE

#pragma unroll
  for (int mi = 0; mi < 4; ++mi)
#pragma unroll
    for (int ni = 0; ni < 4; ++ni)
#pragma unroll
      for (int q = 0; q < 4; ++q) {
        const int row = m0 + MOFF + mi * 16 + g * 4 + q;
        const int col = n0 + NOFF + ni * 16 + u;
        float v = acc[mi][ni][q] * alpha;
        if (CDT == 0) {
          float* cp = (float*)Cv + cOff + (long long)row * ldc + col;
          if (BETA) v += *cp;
          *cp = v;
        } else {
          if (ROPE) {
            const int j = (col & 127) >> 1;
            const float infr = __expf((float)j * (-9.210340371976184f / 64.f));
            float sn, cs;
            __sincosf((float)row * infr, &sn, &cs);
            const float part = __shfl_xor(v, 1);
            v = (col & 1) ? fmaf(part, sn, v * cs) : fmaf(-part, sn, v * cs);
          }
          if (RELU2) { v = fmaxf(v, 0.f); v = v * v; }
          ((ushort*)Cv)[cOff + (long long)row * ldc + col] = f2bf(v);
        }
      }
}

// ---------------------------------------------------------------------------
// Fused flash attention (unchanged, verified).
// ---------------------------------------------------------------------------
__global__ __launch_bounds__(256) void fattn_kernel(
    const ushort* __restrict__ Qg, const ushort* __restrict__ Kg,
    const ushort* __restrict__ Vg, ushort* __restrict__ Og)
{
  __shared__ char lds[73728];
  const int hb = blockIdx.y, pl = hb >> 3, h = hb & 7;
  const int q0 = blockIdx.x * 64;
  const int tid = threadIdx.x, lane = tid & 63, wv = tid >> 6;
  const int u = lane & 15, g = lane >> 4;
  const ushort* Qh = Qg + (size_t)pl * PLF + h * 128;
  const ushort* Kh = Kg + (size_t)pl * PLF + h * 128;
  const ushort* Vh = Vg + (size_t)pl * PLF + (size_t)(h * 128) * 512;
  ushort* Oh = Og + (size_t)pl * PLF + h * 128;

  short8 qf[4];
  const int qrow = q0 + wv * 16 + u;
#pragma unroll
  for (int dc = 0; dc < 4; ++dc)
    qf[dc] = *(const short8*)(Qh + (size_t)qrow * 1024 + dc * 32 + g * 8);

#define STAGE_KV(buf, kt)                                                     \
  {                                                                           \
    _Pragma("unroll")                                                         \
    for (int it = 0; it < 4; ++it) {                                          \
      const int off = tid * 16 + it * 4096;                                   \
      const int krow = off >> 8, kslot = (off >> 4) & 15;                     \
      GLOAD16(Kh + (size_t)((kt) * 64 + krow) * 1024 +                        \
                  ((kslot ^ ((krow & 7) << 1)) * 8),                          \
              &lds[(buf) * 16384] + off);                                     \
      const int vrow = off >> 7, vslot = (off >> 4) & 7;                      \
      GLOAD16(Vh + (size_t)vrow * 512 + (kt) * 64 + ((vslot ^ (vrow & 7)) * 8), \
              &lds[32768 + (buf) * 16384] + off);                             \
    }                                                                         \
  }

  f32x4 oacc[8];
#pragma unroll
  for (int i = 0; i < 8; ++i) oacc[i] = (f32x4){0.f, 0.f, 0.f, 0.f};
  float m_run = -3.0e38f, l_run = 0.f;

  STAGE_KV(0, 0);
  asm volatile("s_waitcnt vmcnt(0)" ::: "memory");
  __syncthreads();
  int cur = 0;
  for (int kt = 0; kt < 8; ++kt) {
    if (kt + 1 < 8) STAGE_KV(cur ^ 1, kt + 1);
    f32x4 sacc[4];
#pragma unroll
    for (int kn = 0; kn < 4; ++kn) sacc[kn] = (f32x4){0.f, 0.f, 0.f, 0.f};
#pragma unroll
    for (int kn = 0; kn < 4; ++kn) {
      const int r = kn * 16 + u;
      const char* kb = &lds[cur * 16384] + r * 256;
#pragma unroll
      for (int dc = 0; dc < 4; ++dc) {
        short8 kf = *(const short8*)(kb + (((dc * 4 + g) ^ ((u & 7) << 1)) * 16));
        sacc[kn] = __builtin_amdgcn_mfma_f32_16x16x32_bf16(kf, qf[dc], sacc[kn], 0, 0, 0);
      }
    }
    float pm = -3.0e38f;
#pragma unroll
    for (int kn = 0; kn < 4; ++kn)
#pragma unroll
      for (int r = 0; r < 4; ++r) {
        sacc[kn][r] *= 0.03125f;
        pm = fmaxf(pm, sacc[kn][r]);
      }
    pm = fmaxf(pm, __shfl_xor(pm, 16));
    pm = fmaxf(pm, __shfl_xor(pm, 32));
    const float m_new = fmaxf(m_run, pm);
    const float es = __expf(m_run - m_new);
    float psum = 0.f;
    uint pw[4][2];
#pragma unroll
    for (int kn = 0; kn < 4; ++kn) {
      float p0 = __expf(sacc[kn][0] - m_new);
      float p1 = __expf(sacc[kn][1] - m_new);
      float p2 = __expf(sacc[kn][2] - m_new);
      float p3 = __expf(sacc[kn][3] - m_new);
      psum += (p0 + p1) + (p2 + p3);
      pw[kn][0] = (uint)f2bf(p0) | ((uint)f2bf(p1) << 16);
      pw[kn][1] = (uint)f2bf(p2) | ((uint)f2bf(p3) << 16);
    }
    psum += __shfl_xor(psum, 16);
    psum += __shfl_xor(psum, 32);
    l_run = l_run * es + psum;
    m_run = m_new;
    char* pb = &lds[65536 + wv * 2048] + u * 128 + (g & 1) * 8;
#pragma unroll
    for (int kn = 0; kn < 4; ++kn)
      *(uint2*)(pb + (((2 * kn + (g >> 1)) ^ (u & 7)) * 16)) =
          make_uint2(pw[kn][0], pw[kn][1]);
    float es_o[4];
#pragma unroll
    for (int r = 0; r < 4; ++r) es_o[r] = __shfl(es, g * 4 + r);
#pragma unroll
    for (int nd = 0; nd < 8; ++nd)
#pragma unroll
      for (int r = 0; r < 4; ++r) oacc[nd][r] *= es_o[r];
    const char* prd = &lds[65536 + wv * 2048] + u * 128;
    short8 pf[2];
#pragma unroll
    for (int kc = 0; kc < 2; ++kc)
      pf[kc] = *(const short8*)(prd + (((kc * 4 + g) ^ (u & 7)) * 16));
#pragma unroll
    for (int nd = 0; nd < 8; ++nd) {
      const int vr = nd * 16 + u;
      const char* vb = &lds[32768 + cur * 16384] + vr * 128;
#pragma unroll
      for (int kc = 0; kc < 2; ++kc) {
        short8 vf = *(const short8*)(vb + (((kc * 4 + g) ^ (u & 7)) * 16));
        oacc[nd] = __builtin_amdgcn_mfma_f32_16x16x32_bf16(pf[kc], vf, oacc[nd], 0, 0, 0);
      }
    }
    asm volatile("s_waitcnt vmcnt(0)" ::: "memory");
    __syncthreads();
    cur ^= 1;
  }
#undef STAGE_KV
  const float inv_l = 1.f / l_run;
  float inv_o[4];
#pragma unroll
  for (int r = 0; r < 4; ++r) inv_o[r] = __shfl(inv_l, g * 4 + r);
#pragma unroll
  for (int nd = 0; nd < 8; ++nd)
#pragma unroll
    for (int r = 0; r < 4; ++r) {
      const int row = q0 + wv * 16 + g * 4 + r;
      Oh[(size_t)row * 1024 + nd * 16 + u] = f2bf(oacc[nd][r] * inv_o[r]);
    }
}

// ---------------- fp32 -> bf16 weight conversion (8 elem/thread) ------------
__global__ __launch_bounds__(256) void cvt_kernel(
    const float4* __restrict__ s, short8* __restrict__ d)
{
  const int i = blockIdx.x * 256 + threadIdx.x;
  const float4 a = s[2 * i], b = s[2 * i + 1];
  short8 h;
  h[0] = (short)f2bf(a.x); h[1] = (short)f2bf(a.y);
  h[2] = (short)f2bf(a.z); h[3] = (short)f2bf(a.w);
  h[4] = (short)f2bf(b.x); h[5] = (short)f2bf(b.y);
  h[6] = (short)f2bf(b.z); h[7] = (short)f2bf(b.w);
  d[i] = h;
}

// ---------------------------------------------------------------------------
// conv 3x3 SAME on [512 w][F f] planes; 8 f-outputs x 4 out-channels/thread.
// ---------------------------------------------------------------------------
template <int CIN>
__global__ __launch_bounds__(256) void conv4c_kernel(
    const ushort* __restrict__ in, const float* __restrict__ wt,
    const float* __restrict__ bias, ushort* __restrict__ outp, int log2F)
{
  const int idx = blockIdx.x * 256 + threadIdx.x;
  const int F8m = (1 << (log2F - 3)) - 1;
  const int f8 = idx & F8m;
  const int w = (idx >> (log2F - 3)) & 511;
  const int bb = idx >> (log2F + 6);
  const int f0 = f8 << 3;
  float acc[4][8];
#pragma unroll
  for (int co = 0; co < 4; ++co) {
    const float bv = bias[co];
#pragma unroll
    for (int j = 0; j < 8; ++j) acc[co][j] = bv;
  }
  const bool lok = f8 > 0, rok = f8 < F8m;
#pragma unroll
  for (int ci = 0; ci < CIN; ++ci) {
    const ushort* base = in + (((size_t)(bb * CIN + ci)) << (log2F + 9));
#pragma unroll
    for (int dxw = 0; dxw < 3; ++dxw) {
      const int w2 = w + dxw - 1;
      if (w2 < 0 || w2 > 511) continue;
      const ushort* rp = base + ((size_t)w2 << log2F) + f0;
      const short8 cen = *(const short8*)rp;
      float xv[10];
      xv[0] = lok ? bf2f(rp[-1]) : 0.f;
#pragma unroll
      for (int j = 0; j < 8; ++j) xv[j + 1] = bf2f((ushort)cen[j]);
      xv[9] = rok ? bf2f(rp[8]) : 0.f;
#pragma unroll
      for (int co = 0; co < 4; ++co) {
        const float* wp = wt + (co * CIN + ci) * 9;
        const float k0 = wp[dxw], k1 = wp[3 + dxw], k2 = wp[6 + dxw];
#pragma unroll
        for (int j = 0; j < 8; ++j)
          acc[co][j] += k0 * xv[j] + k1 * xv[j + 1] + k2 * xv[j + 2];
      }
    }
  }
#pragma unroll
  for (int co = 0; co < 4; ++co) {
    short8 o;
#pragma unroll
    for (int j = 0; j < 8; ++j) o[j] = (short)f2bf(acc[co][j]);
    *(short8*)(outp + (((size_t)(bb * 4 + co)) << (log2F + 9)) + ((size_t)w << log2F) + f0) = o;
  }
}

// ---------------------------------------------------------------------------
// q/k/v merged conv: reads XN once, computes 12 output channels (3 proj x 4c).
// ---------------------------------------------------------------------------
__global__ __launch_bounds__(256) void conv12c_kernel(
    const ushort* __restrict__ in,
    const float* __restrict__ wq, const float* __restrict__ wk, const float* __restrict__ wv,
    const float* __restrict__ bq, const float* __restrict__ bk, const float* __restrict__ bv,
    ushort* __restrict__ outp, int nPl)
{
  const int idx = blockIdx.x * 256 + threadIdx.x;
  const int f8 = idx & 127;
  const int w = (idx >> 7) & 511;
  const int bb = idx >> 16;
  const int f0 = f8 << 3;
  const float* wsel[3] = {wq, wk, wv};
  float acc[12][8];
#pragma unroll
  for (int co = 0; co < 4; ++co) {
    const float b0 = bq[co], b1 = bk[co], b2 = bv[co];
#pragma unroll
    for (int j = 0; j < 8; ++j) {
      acc[co][j] = b0; acc[4 + co][j] = b1; acc[8 + co][j] = b2;
    }
  }
  const bool lok = f8 > 0, rok = f8 < 127;
#pragma unroll
  for (int ci = 0; ci < 4; ++ci) {
    const ushort* base = in + (((size_t)(bb * 4 + ci)) << 19);
#pragma unroll
    for (int dxw = 0; dxw < 3; ++dxw) {
      const int w2 = w + dxw - 1;
      if (w2 < 0 || w2 > 511) continue;
      const ushort* rp = base + ((size_t)w2 << 10) + f0;
      const short8 cen = *(const short8*)rp;
      float xv[10];
      xv[0] = lok ? bf2f(rp[-1]) : 0.f;
#pragma unroll
      for (int j = 0; j < 8; ++j) xv[j + 1] = bf2f((ushort)cen[j]);
      xv[9] = rok ? bf2f(rp[8]) : 0.f;
#pragma unroll
      for (int pj = 0; pj < 3; ++pj)
#pragma unroll
        for (int co = 0; co < 4; ++co) {
          const float* wp = wsel[pj] + (co * 4 + ci) * 9;
          const float k0 = wp[dxw], k1 = wp[3 + dxw], k2 = wp[6 + dxw];
#pragma unroll
          for (int j = 0; j < 8; ++j)
            acc[pj * 4 + co][j] += k0 * xv[j] + k1 * xv[j + 1] + k2 * xv[j + 2];
        }
    }
  }
#pragma unroll
  for (int pj = 0; pj < 3; ++pj)
#pragma unroll
    for (int co = 0; co < 4; ++co) {
      short8 o;
#pragma unroll
      for (int j = 0; j < 8; ++j) o[j] = (short)f2bf(acc[pj * 4 + co][j]);
      *(short8*)(outp + (((size_t)(pj * nPl + bb * 4 + co)) << 19) +
                 ((size_t)w << 10) + f0) = o;
    }
}

// ---------------- layernorm over f (rows of 1024), H fp32 -> XN bf16 --------
__global__ __launch_bounds__(256) void ln_kernel(
    const float* __restrict__ H, const float* __restrict__ gam,
    const float* __restrict__ bet, ushort* __restrict__ XN)
{
  const int wid = threadIdx.x >> 6, lane = threadIdx.x & 63;
  const int row = blockIdx.x * 4 + wid;
  const int c = (row >> 9) & 3;
  const float* xp = H + (size_t)row * 1024;
  float4 v[4];
  float s = 0.f, q = 0.f;
#pragma unroll
  for (int p = 0; p < 4; ++p) {
    v[p] = *(const float4*)(xp + p * 256 + lane * 4);
    s += v[p].x + v[p].y + v[p].z + v[p].w;
    q += v[p].x * v[p].x + v[p].y * v[p].y + v[p].z * v[p].z + v[p].w * v[p].w;
  }
#pragma unroll
  for (int o = 32; o > 0; o >>= 1) { s += __shfl_xor(s, o); q += __shfl_xor(q, o); }
  const float mu = s * (1.f / 1024.f);
  const float var = q * (1.f / 1024.f) - mu * mu;
  const float rs = rsqrtf(var + 1e-5f);
  ushort* op = XN + (size_t)row * 1024;
  const float* gp = gam + c * 1024;
  const float* bp = bet + c * 1024;
#pragma unroll
  for (int p = 0; p < 4; ++p) {
    const int f = p * 256 + lane * 4;
    float4 g4 = *(const float4*)(gp + f);
    float4 b4 = *(const float4*)(bp + f);
    ushort4 o4;
    o4.x = f2bf((v[p].x - mu) * rs * g4.x + b4.x);
    o4.y = f2bf((v[p].y - mu) * rs * g4.y + b4.y);
    o4.z = f2bf((v[p].z - mu) * rs * g4.z + b4.z);
    o4.w = f2bf((v[p].w - mu) * rs * g4.w + b4.w);
    *(ushort4*)(op + f) = o4;
  }
}

// ---- transpose-in: x fp32 [f][w] -> XT bf16 [w][f]; also copy x -> out -----
__global__ __launch_bounds__(256) void tin_kernel(
    const float* __restrict__ x, ushort* __restrict__ XT,
    float* __restrict__ outp, int planeOff)
{
  __shared__ float t[32][33];
  const int f0 = blockIdx.x * 32, w0 = blockIdx.y * 32;
  const int z = blockIdx.z;
  const int tx = threadIdx.x & 31, ty = threadIdx.x >> 5;
  const int gpl = planeOff + z;
  const int b = gpl >> 3, ch = gpl & 7;
  const float* src = x + (size_t)gpl * PLF;
  float* dst0 = outp + (size_t)(b * 12 + ch) * PLF;
#pragma unroll
  for (int r = 0; r < 32; r += 8) {
    const size_t off = (size_t)(f0 + r + ty) * 512 + w0 + tx;
    const float v = src[off];
    t[r + ty][tx] = v;
    dst0[off] = v;
  }
  __syncthreads();
  ushort* dst = XT + (size_t)z * PLF;
#pragma unroll
  for (int r = 0; r < 32; r += 8) dst[(size_t)(w0 + r + ty) * 1024 + f0 + tx] = f2bf(t[tx][r + ty]);
}

// ---------------- transpose-out: H fp32 [w][f] -> out[b][8+c][f][w] ---------
__global__ __launch_bounds__(256) void tout_kernel(
    const float* __restrict__ H, float* __restrict__ out, int b0)
{
  __shared__ float t[32][33];
  const int w0 = blockIdx.x * 32, f0 = blockIdx.y * 32;
  const int p = blockIdx.z;
  const int b = b0 + (p >> 2), c = p & 3;
  const int tx = threadIdx.x & 31, ty = threadIdx.x >> 5;
  const float* src = H + (size_t)p * PLF;
#pragma unroll
  for (int r = 0; r < 32; r += 8) t[r + ty][tx] = src[(size_t)(w0 + r + ty) * 1024 + f0 + tx];
  __syncthreads();
  float* dst = out + (size_t)(b * 12 + 8 + c) * PLF;
#pragma unroll
  for (int r = 0; r < 32; r += 8) dst[(size_t)(f0 + r + ty) * 512 + w0 + tx] = t[tx][r + ty];
}

// ---------------------------------------------------------------------------
extern "C" void kernel_launch(void* const* d_in, const int* in_sizes, int n_in,
                              void* d_out, int out_size, void* d_ws, size_t ws_size,
                              hipStream_t stream)
{
  const float* x        = (const float*)d_in[0];
  const float* embed_cw = (const float*)d_in[1];
  const float* embed_cb = (const float*)d_in[2];
  const float* embed_pw = (const float*)d_in[3];
  const float* n1g      = (const float*)d_in[4];
  const float* n1b      = (const float*)d_in[5];
  const float* q_cw     = (const float*)d_in[6];
  const float* q_cb     = (const float*)d_in[7];
  const float* q_pw     = (const float*)d_in[8];
  const float* k_cw     = (const float*)d_in[9];
  const float* k_cb     = (const float*)d_in[10];
  const float* k_pw     = (const float*)d_in[11];
  const float* v_cw     = (const float*)d_in[12];
  const float* v_cb     = (const float*)d_in[13];
  const float* v_pw     = (const float*)d_in[14];
  const float* o_cw     = (const float*)d_in[15];
  const float* o_cb     = (const float*)d_in[16];
  const float* o_pw     = (const float*)d_in[17];
  const float* n2g      = (const float*)d_in[18];
  const float* n2b      = (const float*)d_in[19];
  const float* f1_cw    = (const float*)d_in[20];
  const float* f1_cb    = (const float*)d_in[21];
  const float* f1_pw    = (const float*)d_in[22];
  const float* f2_cw    = (const float*)d_in[23];
  const float* f2_cb    = (const float*)d_in[24];
  const float* f2_pw    = (const float*)d_in[25];
  float* out = (float*)d_out;

  const size_t perB = 50331648ull;
  const int N = (ws_size >= 4 * perB) ? 4 : (ws_size >= 2 * perB) ? 2 : 1;
  const int nP = 4 * N;

  // layout: Hf | XT | XN | Qb | Kb | CT | Vb | SfPb
  char* base = (char*)d_ws;
  float*  Hf = (float*)base;                                    // N*8388608 B
  ushort* XT = (ushort*)(base + (size_t)N * 8388608);           // N*8388608 B
  ushort* XN = (ushort*)((char*)XT + (size_t)N * 8388608);      // N*4194304 B
  ushort* Qb = (ushort*)((char*)XN + (size_t)N * 4194304);
  ushort* Kb = (ushort*)((char*)Qb + (size_t)N * 4194304);      // adjacent to Qb!
  ushort* CT = (ushort*)((char*)Kb + (size_t)N * 4194304);
  ushort* Vb = (ushort*)((char*)CT + (size_t)N * 4194304);
  ushort* SfPb = (ushort*)((char*)Vb + (size_t)N * 4194304);    // N*12582912 B
  ushort* CT3 = SfPb;                  // q/k/v conv outputs, 3*nP planes
  ushort* W8  = SfPb;                  // 8.4MB bf16 weight slot (embed/o/v)
  ushort* WQK = XT;                    // 16.8MB qk weights (N>=2)
  ushort* MID = XT;                    // ffn1 out (XT..Qb span)
  ushort* f1w = Vb;                    // ffn1 weight (Vb..SfPb span, N>=2)
  ushort* F2C = Vb;                    // ffn2 conv out (Vb..SfPb span)
  ushort* f2w = XT;                    // ffn2 weight (XT..Qb span, N>=2)

  const long long W1 = 1048576;
  const long long W4 = 4194304;
  const long long M1 = 2097152;
  const long long CH3 = (long long)nP * PLF;   // CT3 chunk stride
  const int GCc1 = N * 256;
  const int GCc4 = N * 1024;

  for (int b0 = 0; b0 < 4; b0 += N) {
    // --- input transpose + x copy to out ---
    tin_kernel<<<dim3(32, 16, 8 * N), 256, 0, stream>>>(x, XT, out, b0 * 8);
    // --- embed ---
    conv4c_kernel<8><<<GCc1, 256, 0, stream>>>(XT, embed_cw, embed_cb, CT, 10);
    cvt_kernel<<<2048, 256, 0, stream>>>((const float4*)embed_pw, (short8*)W8);
    mm_kernel<0, 0, 0, 0, 0, 0><<<dim3(8, 4, nP), 256, 0, stream>>>(
        CT, W8, Hf, 1024, 1024, 1024, 1024,
        1, 1, PLF, 0, 4, 4, 0, W1, 1, 1, PLF, 0, 1.f);
    // --- LN1 ---
    ln_kernel<<<nP * 128, 256, 0, stream>>>(Hf, n1g, n1b, XN);
    // --- merged q/k/v conv ---
    conv12c_kernel<<<GCc1, 256, 0, stream>>>(XN, q_cw, k_cw, v_cw,
                                             q_cb, k_cb, v_cb, CT3, nP);
    // --- q+k projection (RoPE fused into epilogue) ---
    if (N >= 2) {
      cvt_kernel<<<2048, 256, 0, stream>>>((const float4*)q_pw, (short8*)WQK);
      cvt_kernel<<<2048, 256, 0, stream>>>((const float4*)k_pw, (short8*)(WQK) + 524288);
      mm_kernel<1, 0, 0, 0, 0, 1><<<dim3(8, 4, 2 * nP), 256, 0, stream>>>(
          CT3, WQK, Qb, 1024, 1024, 1024, 1024,
          1, 1, PLF, 0, nP, 4, 4 * W1, W1, 1, 1, PLF, 0, 1.f);
    } else {
      mm_kernel<1, 0, 0, 0, 1, 1><<<dim3(8, 4, nP), 256, 0, stream>>>(
          CT3, q_pw, Qb, 1024, 1024, 1024, 1024,
          1, 1, PLF, 0, 4, 4, 0, W1, 1, 1, PLF, 0, 1.f);
      mm_kernel<1, 0, 0, 0, 1, 1><<<dim3(8, 4, nP), 256, 0, stream>>>(
          CT3 + CH3, k_pw, Kb, 1024, 1024, 1024, 1024,
          1, 1, PLF, 0, 4, 4, 0, W1, 1, 1, PLF, 0, 1.f);
    }
    // --- v projection (V stored [f][w]); W8 clobbers CT3 chunk0 (dead) ---
    cvt_kernel<<<2048, 256, 0, stream>>>((const float4*)v_pw, (short8*)W8);
    mm_kernel<1, 0, 0, 0, 0, 0><<<dim3(4, 8, nP), 256, 0, stream>>>(
        W8, CT3 + 2 * CH3, Vb, 1024, 1024, 1024, 512,
        4, 4, 0, W1, 1, 1, PLF, 0, 1, 1, PLF, 0, 1.f);
    // --- fused flash attention (O overwrites Q) ---
    fattn_kernel<<<dim3(8, nP * 8), 256, 0, stream>>>(Qb, Kb, Vb, Qb);
    // --- o projection (accumulate into H) ---
    conv4c_kernel<4><<<GCc1, 256, 0, stream>>>(Qb, o_cw, o_cb, CT, 10);
    cvt_kernel<<<2048, 256, 0, stream>>>((const float4*)o_pw, (short8*)W8);
    mm_kernel<0, 1, 0, 0, 0, 0><<<dim3(8, 4, nP), 256, 0, stream>>>(
        CT, W8, Hf, 1024, 1024, 1024, 1024,
        1, 1, PLF, 0, 4, 4, 0, W1, 1, 1, PLF, 0, 1.f);
    // --- LN2 ---
    ln_kernel<<<nP * 128, 256, 0, stream>>>(Hf, n2g, n2b, XN);
    // --- ffn1 (+fused squared relu) ---
    conv4c_kernel<4><<<GCc1, 256, 0, stream>>>(XN, f1_cw, f1_cb, CT, 10);
    if (N >= 2) {
      cvt_kernel<<<8192, 256, 0, stream>>>((const float4*)f1_pw, (short8*)f1w);
      mm_kernel<1, 0, 1, 1, 0, 0><<<dim3(32, 4, nP), 256, 0, stream>>>(
          CT, f1w, MID, 1024, 1024, 1024, 4096,
          1, 1, PLF, 0, 4, 4, 0, W4, 1, 1, M1, 0, 1.f);
    } else {
      mm_kernel<1, 0, 1, 1, 1, 0><<<dim3(32, 4, nP), 256, 0, stream>>>(
          CT, f1_pw, MID, 1024, 1024, 1024, 4096,
          1, 1, PLF, 0, 4, 4, 0, W4, 1, 1, M1, 0, 1.f);
    }
    // --- ffn2 conv (F=4096) then pw accumulate into H ---
    conv4c_kernel<4><<<GCc4, 256, 0, stream>>>(MID, f2_cw, f2_cb, F2C, 12);
    if (N >= 2) {
      cvt_kernel<<<8192, 256, 0, stream>>>((const float4*)f2_pw, (short8*)f2w);
      mm_kernel<0, 1, 0, 0, 0, 0><<<dim3(8, 4, nP), 256, 0, stream>>>(
          F2C, f2w, Hf, 4096, 4096, 4096, 1024,
          1, 1, M1, 0, 4, 4, 0, W4, 1, 1, PLF, 0, 1.f);
    } else {
      mm_kernel<0, 1, 0, 0, 1, 0><<<dim3(8, 4, nP), 256, 0, stream>>>(
          F2C, f2_pw, Hf, 4096, 4096, 4096, 1024,
          1, 1, M1, 0, 4, 4, 0, W4, 1, 1, PLF, 0, 1.f);
    }
    // --- output transpose ---
    tout_kernel<<<dim3(16, 32, nP), 256, 0, stream>>>(Hf, out, b0);
  }
}